// Round 10
// baseline (618.469 us; speedup 1.0000x reference)
//
#include <hip/hip_runtime.h>
#include <math.h>

#define N_NODES 25000
#define N_EDGES 400000
#define HID 128
#define EDGE_F 16
#define ADY 64
#define INNER 160
#define MSG_F 273
#define HEADS 8

// element offsets inside d_out (h2 | coords | res2)
#define OUT_CRD (N_NODES * HID)
#define OUT_RES (N_NODES * (HID + 3))

// ws byte offsets (16-aligned)
#define FLAG_OFF 0
#define BAR_OFF  16                     // grid-barrier counter (zeroed by memset)
#define DEN_OFF  256                    // f32 [25000][8]   = 800000
#define CACC_OFF 800256                 // f32 [25000][3]   = 300000
#define HAGG_OFF 1100256                // f32 [25000][128] = 12800000
#define CNT_OFF  13900256               // int [25000] histogram
#define CUR_OFF  14000256               // int [25000] scan/cursor
#define MEMSET_BYTES 14000256           // zero flag..cnt (cursor/perm overwritten)
#define PERM_OFF 14100256               // int [400000] dst-sorted edge ids
#define BSUM_OFF 15700256               // int [256] per-block bin sums
#define BBASE_OFF 15701280              // int [256] per-block exclusive bases
#define HBF_OFF  15702304               // h as bf16: 6.4 MB
#define YBF_OFF  22102304               // y as bf16: 3.2 MB
#define BIAS_OFF 25302304               // 6 bias tensors, bf16
#define BW_OFF   25304608               // blocked (fragment-linear) weights

// per-wave LDS slice (u16 units):
//   [0,512)     kc chunk (GEMM1 kstep 8: radial + edge feats, frag-linear)
//   [512,3072)  sM (GEMM2 input sM1, then aliased as GEMM3 input sM2)
//   [0,2336)    scr bf16 [16][SCR_STRIDE] (epilogue, aliases kc+sM)
// slice = 3072 u16 = 6144 B -> 24576 B/block.
#define WSLICE 3072
#define SM_OFF 512
#define SCR_STRIDE 146

typedef unsigned short u16;
typedef unsigned int u32;
typedef unsigned long long u64;
typedef __attribute__((ext_vector_type(8))) short short8;
typedef __attribute__((ext_vector_type(4))) float f32x4;

__device__ __forceinline__ float bf2f(u16 v) {
    union { u32 u; float f; } x; x.u = ((u32)v) << 16; return x.f;
}
__device__ __forceinline__ u16 f2bf(float f) {
    union { float ff; u32 u; } x; x.ff = f;
    u32 u = x.u;
    u32 rounding = 0x7FFFu + ((u >> 16) & 1u);
    u += rounding;
    return (u16)(u >> 16);
}
// HW packed bf16 convert: one instruction for 2 floats (guide T12, m240).
__device__ __forceinline__ u32 cvt_pk(float lo, float hi) {
    u32 r;
    asm("v_cvt_pk_bf16_f32 %0, %1, %2" : "=v"(r) : "v"(lo), "v"(hi));
    return r;
}
__device__ __forceinline__ float silu(float z) {
    z = fminf(fmaxf(z, -30000.f), 30000.f);
    return z / (1.0f + __expf(-z));
}

template<bool F32> __device__ __forceinline__ float ldg1(const void* p, size_t i) {
    if (F32) return ((const float*)p)[i];
    return bf2f(((const u16*)p)[i]);
}
template<bool F32> __device__ __forceinline__ void stg1(void* p, size_t i, float v) {
    if (F32) ((float*)p)[i] = v;
    else     ((u16*)p)[i] = f2bf(v);
}
__device__ __forceinline__ float ldany(const void* p, size_t i, bool f32) {
    return f32 ? ((const float*)p)[i] : bf2f(((const u16*)p)[i]);
}
// wave-level LDS fence (all LDS regions are wave-private)
__device__ __forceinline__ void wave_lds_fence() {
    __builtin_amdgcn_wave_barrier();
    __builtin_amdgcn_s_waitcnt(0xc07f);   // lgkmcnt(0) only
    __builtin_amdgcn_wave_barrier();
}

// A-fragment address for 16x16x32 bf16 (K-major frag-linear LDS layout)
__device__ __forceinline__ int a_addr(int k, int lr) {
    return ((k >> 5) << 9) + (((((k & 31) >> 3) << 4) | lr) << 3) + (k & 7);
}

// grid-wide barrier: 256 co-resident blocks (grid==256 <= 256 CUs).
// device-scope atomic arrive + spin; __threadfence drains prior writes.
__device__ __forceinline__ void grid_bar(int* bar, int target) {
    __threadfence();
    __syncthreads();
    if (threadIdx.x == 0) {
        __hip_atomic_fetch_add(bar, 1, __ATOMIC_ACQ_REL, __HIP_MEMORY_SCOPE_AGENT);
        while (__hip_atomic_load(bar, __ATOMIC_ACQUIRE, __HIP_MEMORY_SCOPE_AGENT) < target)
            __builtin_amdgcn_s_sleep(8);
    }
    __syncthreads();
}

// ---------------------------------------------------------------------------
// Fused preprocessing: dtype detect + cvt + fragment-linear blockw + dst hist
// + (R9) counting-sort scan + scatter, all in ONE kernel via grid barriers.
// Removes 2 kernel launches + their serial drain gaps.
// ---------------------------------------------------------------------------
struct CvtArgs {
    const void* src[8];
    u64 dstoff[8];
    int n[8];
};
struct BwArgs {
    const void* We1; const void* We2; const void* Wv; const void* Wa;
    const void* Wc;  const void* Wo;  const void* Wn1; const void* Wn2;
    const void* Wf1; const void* Wf2;
    u64 b1, b2, b3, b4, b5, b6, b7, b8;
};

__global__ __launch_bounds__(256)
void preproc_kernel(const void* hsrc, int* flag, char* ws, CvtArgs args, BwArgs bwa,
                    const int* __restrict__ dstp, int* __restrict__ cnt,
                    int* __restrict__ cursor, int* __restrict__ perm,
                    int* __restrict__ bar, int* __restrict__ bsum,
                    int* __restrict__ bbase)
{
    __shared__ float red[256];
    __shared__ int sflag;
    __shared__ int sscan[128];
    __shared__ int s2a[256];
    const int t = threadIdx.x;
    const int b = blockIdx.x;
    {
        const u16* p = (const u16*)hsrc;
        float mx = 0.f;
        for (int i = 0; i < 8; i++) {
            int idx = (t * 8 + i) * 97;
            float v = fabsf(bf2f(p[idx * 2]));
            mx = fmaxf(mx, v);
        }
        red[t] = mx;
        __syncthreads();
        for (int s = 128; s > 0; s >>= 1) {
            if (t < s) red[t] = fmaxf(red[t], red[t + s]);
            __syncthreads();
        }
        if (t == 0) {
            sflag = (red[0] > 1e10f || red[0] == 0.f) ? 1 : 0;
            if (b == 0) flag[0] = sflag;
        }
        __syncthreads();
    }
    const bool f32 = (sflag != 0);
    const int g = b * 256 + t;
    const int stride = gridDim.x * 256;

    // ---- dst histogram for counting sort ----
    for (int i = g; i < N_EDGES; i += stride)
        atomicAdd(&cnt[dstp[i]], 1);

    // ---- cvt: biases + h + y ----
    for (int ten = 0; ten < 8; ten++) {
        const void* s = args.src[ten];
        u16* d = (u16*)(ws + args.dstoff[ten]);
        const int n = args.n[ten];
        if (f32) {
            const float* sf = (const float*)s;
            for (int i = g; i < n; i += stride) d[i] = f2bf(sf[i]);
        } else {
            const u16* su = (const u16*)s;
            for (int i = g; i < n; i += stride) d[i] = su[i];
        }
    }

    // ---- fragment-linear blocked weights ----
    u16* b1 = (u16*)(ws + bwa.b1);
    u16* b2 = (u16*)(ws + bwa.b2);
    u16* b3 = (u16*)(ws + bwa.b3);
    u16* b4 = (u16*)(ws + bwa.b4);
    u16* b5 = (u16*)(ws + bwa.b5);
    u16* b6 = (u16*)(ws + bwa.b6);
    u16* b7 = (u16*)(ws + bwa.b7);
    u16* b8 = (u16*)(ws + bwa.b8);
    // We1P: [5c][2ks][10nt] tiles, K=320 logical (k==273 -> dup row 256)
    for (int i = g; i < 5*2*10*512; i += stride) {
        int tt = i >> 9, r = i & 511, l = r >> 3, j = r & 7;
        int c = tt / 20, ks = (tt / 10) % 2, nt = tt % 10;
        int k = c*64 + ks*32 + (l >> 4)*8 + j;
        int n = nt*16 + (l & 15);
        float v = 0.f;
        if (k < MSG_F)      v = ldany(bwa.We1, (size_t)k*INNER + n, f32);
        else if (k == 273)  v = ldany(bwa.We1, (size_t)256*INNER + n, f32);
        b1[i] = f2bf(v);
    }
    // We2P: [5 k5][10 nt], K=160
    for (int i = g; i < 5*10*512; i += stride) {
        int tt = i >> 9, r = i & 511, l = r >> 3, j = r & 7;
        int k5 = tt / 10, nt = tt % 10;
        int k = k5*32 + (l >> 4)*8 + j;
        int n = nt*16 + (l & 15);
        b2[i] = f2bf(ldany(bwa.We2, (size_t)k*INNER + n, f32));
    }
    // W3P: [5 k5][9 nt], K=160; n<128 Wv | n<136 Wa | n==136 Wc | else 0
    for (int i = g; i < 5*9*512; i += stride) {
        int tt = i >> 9, r = i & 511, l = r >> 3, j = r & 7;
        int k5 = tt / 9, nt = tt % 9;
        int k = k5*32 + (l >> 4)*8 + j;
        int n = nt*16 + (l & 15);
        float v = 0.f;
        if (n < 128)       v = ldany(bwa.Wv, (size_t)k*HID + n, f32);
        else if (n < 136)  v = ldany(bwa.Wa, (size_t)k*HEADS + (n-128), f32);
        else if (n == 136) v = ldany(bwa.Wc, (size_t)k, f32);
        b3[i] = f2bf(v);
    }
    // WoP: [4 cks][8 nt], K=128
    for (int i = g; i < 4*8*512; i += stride) {
        int tt = i >> 9, r = i & 511, l = r >> 3, j = r & 7;
        int cks = tt / 8, nt = tt % 8;
        int k = cks*32 + (l >> 4)*8 + j;
        int n = nt*16 + (l & 15);
        b4[i] = f2bf(ldany(bwa.Wo, (size_t)k*HID + n, f32));
    }
    // Wn1P: [4 cks][10 nt], K=128
    for (int i = g; i < 4*10*512; i += stride) {
        int tt = i >> 9, r = i & 511, l = r >> 3, j = r & 7;
        int cks = tt / 10, nt = tt % 10;
        int k = cks*32 + (l >> 4)*8 + j;
        int n = nt*16 + (l & 15);
        b5[i] = f2bf(ldany(bwa.Wn1, (size_t)k*INNER + n, f32));
    }
    // Wn2P: [5 k5][8 nt], K=160
    for (int i = g; i < 5*8*512; i += stride) {
        int tt = i >> 9, r = i & 511, l = r >> 3, j = r & 7;
        int k5 = tt / 8, nt = tt % 8;
        int k = k5*32 + (l >> 4)*8 + j;
        int n = nt*16 + (l & 15);
        b6[i] = f2bf(ldany(bwa.Wn2, (size_t)k*HID + n, f32));
    }
    // Wf1P / Wf2P: [2 ks][16 nt], K=64
    for (int i = g; i < 2*16*512; i += stride) {
        int tt = i >> 9, r = i & 511, l = r >> 3, j = r & 7;
        int ks = tt / 16, nt = tt % 16;
        int k = ks*32 + (l >> 4)*8 + j;
        int n = nt*16 + (l & 15);
        b7[i] = f2bf(ldany(bwa.Wf1, (size_t)k*256 + n, f32));
        b8[i] = f2bf(ldany(bwa.Wf2, (size_t)k*256 + n, f32));
    }

    // ==== counting sort: scan + scatter, fused via grid barriers ====
    grid_bar(bar, 256);                       // histogram complete

    // phase 2a: block b (b<250) scans its 100 bins in LDS
    int myv = 0;
    if (b < 250) {
        if (t < 128) {
            int bin = b*100 + t;
            myv = (t < 100)
                ? __hip_atomic_load(&cnt[bin], __ATOMIC_RELAXED, __HIP_MEMORY_SCOPE_AGENT)
                : 0;
            sscan[t] = myv;
        }
        __syncthreads();
        for (int off = 1; off < 128; off <<= 1) {
            int x = (t < 128 && t >= off) ? sscan[t - off] : 0;
            __syncthreads();
            if (t < 128) sscan[t] += x;
            __syncthreads();
        }
        if (t == 127)
            __hip_atomic_store(&bsum[b], sscan[127], __ATOMIC_RELEASE, __HIP_MEMORY_SCOPE_AGENT);
    } else {
        if (t == 0)
            __hip_atomic_store(&bsum[b], 0, __ATOMIC_RELEASE, __HIP_MEMORY_SCOPE_AGENT);
    }
    grid_bar(bar, 512);                       // all bsum written

    // phase 2b: block 0 scans 256 block sums -> exclusive bases
    if (b == 0) {
        int v2 = __hip_atomic_load(&bsum[t], __ATOMIC_RELAXED, __HIP_MEMORY_SCOPE_AGENT);
        s2a[t] = v2;
        __syncthreads();
        for (int off = 1; off < 256; off <<= 1) {
            int x = (t >= off) ? s2a[t - off] : 0;
            __syncthreads();
            s2a[t] += x;
            __syncthreads();
        }
        __hip_atomic_store(&bbase[t], s2a[t] - v2, __ATOMIC_RELEASE, __HIP_MEMORY_SCOPE_AGENT);
    }
    grid_bar(bar, 768);                       // bbase ready

    // phase 2c: write cursors (exclusive prefix per bin)
    if (b < 250 && t < 100) {
        int base = __hip_atomic_load(&bbase[b], __ATOMIC_RELAXED, __HIP_MEMORY_SCOPE_AGENT);
        __hip_atomic_store(&cursor[b*100 + t], base + sscan[t] - myv,
                           __ATOMIC_RELEASE, __HIP_MEMORY_SCOPE_AGENT);
    }
    grid_bar(bar, 1024);                      // all cursors ready

    // phase 3: scatter
    for (int i = g; i < N_EDGES; i += stride) {
        int pos = atomicAdd(&cursor[dstp[i]], 1);
        perm[pos] = i;
    }
}

// ---------------------------------------------------------------------------
// Barrier-free MFMA edge kernel, dst-sorted, 6144 B LDS/wave.
// R9: staging runs FIRST (its ~20 temporaries die), THEN the 8-fragment afr
// batch is issued -- peak live regs ~107 < 128, clearing R7/R8's scratch
// spill (one short8/lane = 25.6 MB of HBM round trips). cvt_pk throughout.
// ---------------------------------------------------------------------------
template<bool F32>   // applies to coords / a only
__device__ __forceinline__ void edge_body(
    const u16* __restrict__ hbf, const void* coords, const void* a,
    const int* __restrict__ src, const int* __restrict__ dst,
    const int* __restrict__ perm,
    const u16* __restrict__ We1P, const u16* __restrict__ We2P,
    const u16* __restrict__ W3P,
    const u16* __restrict__ cbe1, const u16* __restrict__ cbe2,
    float* __restrict__ den, float* __restrict__ hagg, float* __restrict__ cacc,
    u16* sPool)
{
    const int t   = threadIdx.x;
    const int w   = t >> 6;
    const int l   = t & 63;
    const int col = l & 15;
    const int q   = l >> 4;
    const int e0  = blockIdx.x * 64;
    const int l8  = l << 3;

    u16* sW = sPool + w * WSLICE;

    // per-lane edge for A-gathers: edge index = col (row of the MFMA A tile)
    const int ge2 = perm[e0 + w*16 + col];
    const int s2 = src[ge2];
    const int d2 = dst[ge2];

    // ---- staging lanes FIRST: coords/radial/a -> kc chunk + metadata regs ----
    const int er = l >> 2;          // edge row 0..15 (4 lanes per edge)
    const int p  = l & 3;
    const int ge = perm[e0 + w*16 + er];
    float dx = 0.f, dy = 0.f, dz = 0.f, invf = 0.f, r2 = 0.f;
    if (p < 2) {
        int s_ = src[ge], d_ = dst[ge];
        dx = ldg1<F32>(coords, (size_t)s_*3+0) - ldg1<F32>(coords, (size_t)d_*3+0);
        dy = ldg1<F32>(coords, (size_t)s_*3+1) - ldg1<F32>(coords, (size_t)d_*3+1);
        dz = ldg1<F32>(coords, (size_t)s_*3+2) - ldg1<F32>(coords, (size_t)d_*3+2);
        r2 = dx*dx + dy*dy + dz*dz;
        invf = 1.0f / (sqrtf(r2 + 1e-5f) + 1.0f);
        __align__(16) u16 tmp[16];
        #pragma unroll
        for (int j = 0; j < 16; j++) tmp[j] = 0;
        if (p == 0) {
            tmp[0] = f2bf(r2);                               // k=256 radial hi
            for (int j = 0; j < 15; j++)
                tmp[1+j] = f2bf(ldg1<F32>(a, (size_t)ge*EDGE_F + j));
        } else {
            tmp[0] = f2bf(ldg1<F32>(a, (size_t)ge*EDGE_F + 15));
            tmp[1] = f2bf(r2 - bf2f(f2bf(r2)));              // k=273 radial lo
        }
        // local frag-linear addr within the 32-wide kc tile
        *(uint4*)(sW + (32*p + er)*8)      = ((uint4*)tmp)[0];
        *(uint4*)(sW + (32*p + 16 + er)*8) = ((uint4*)tmp)[1];
    }

    // ---- NOW batch-load ALL 8 A-fragments (staging temporaries are dead) ----
    short8 afr[8];
    {
        const u16* hs = hbf + (size_t)s2*HID + q*8;
        const u16* hd = hbf + (size_t)d2*HID + q*8;
        #pragma unroll
        for (int kk = 0; kk < 4; kk++) {
            afr[kk]     = *(const short8*)(hs + (kk << 5));
            afr[4 + kk] = *(const short8*)(hd + (kk << 5));
        }
    }
    wave_lds_fence();                                   // F1: kc staged

    // ---- GEMM1: K=288 (8 register ksteps + 1 LDS kstep) ----
    f32x4 acc1[10];
    #pragma unroll
    for (int nt = 0; nt < 10; nt++) {
        float v = bf2f(cbe1[nt*16 + col]);
        acc1[nt] = (f32x4){v, v, v, v};
    }
    #pragma unroll
    for (int kk = 0; kk < 8; kk++) {
        const u16* B1 = We1P + ((kk*10) << 9) + l8;
        #pragma unroll
        for (int nt = 0; nt < 10; nt++) {
            short8 b = *(const short8*)(B1 + (nt << 9));
            acc1[nt] = __builtin_amdgcn_mfma_f32_16x16x32_bf16(afr[kk], b, acc1[nt], 0, 0, 0);
        }
    }
    {   // kstep 8: radial + edge features from LDS
        short8 af = *(const short8*)(sW + l8);
        const u16* B1 = We1P + ((8*10) << 9) + l8;
        #pragma unroll
        for (int nt = 0; nt < 10; nt++) {
            short8 b = *(const short8*)(B1 + (nt << 9));
            acc1[nt] = __builtin_amdgcn_mfma_f32_16x16x32_bf16(af, b, acc1[nt], 0, 0, 0);
        }
    }
    // kc reads done; sM1 writes go to disjoint region [512,3072) -> no fence.
    // Paired u32 transpose write via cvt_pk: lane pair (col, col^1) = adjacent k.
    const bool lo = (col & 1) == 0;
    const int cb16 = col & ~1;
    #pragma unroll
    for (int nt = 0; nt < 10; nt++) {
        float m0 = silu(acc1[nt][0]);
        float m1 = silu(acc1[nt][1]);
        float m2 = silu(acc1[nt][2]);
        float m3 = silu(acc1[nt][3]);
        float p0 = __shfl_xor(m0, 1);
        float p1 = __shfl_xor(m1, 1);
        float p2 = __shfl_xor(m2, 1);
        float p3 = __shfl_xor(m3, 1);
        int k0 = nt*16 + cb16;
        if (lo) {
            *(u32*)(sW + SM_OFF + a_addr(k0, q*4+0)) = cvt_pk(m0, p0);
            *(u32*)(sW + SM_OFF + a_addr(k0, q*4+1)) = cvt_pk(m1, p1);
        } else {
            *(u32*)(sW + SM_OFF + a_addr(k0, q*4+2)) = cvt_pk(p2, m2);
            *(u32*)(sW + SM_OFF + a_addr(k0, q*4+3)) = cvt_pk(p3, m3);
        }
    }
    wave_lds_fence();                                   // F2: sM1 ready

    // ---- GEMM2: K=160 ----
    f32x4 acc2[10];
    #pragma unroll
    for (int nt = 0; nt < 10; nt++) {
        float v = bf2f(cbe2[nt*16 + col]);
        acc2[nt] = (f32x4){v, v, v, v};
    }
    #pragma unroll
    for (int k5 = 0; k5 < 5; k5++) {
        short8 af = *(const short8*)(sW + SM_OFF + (k5 << 9) + l8);
        const u16* B2 = We2P + ((k5*10) << 9) + l8;
        #pragma unroll
        for (int nt = 0; nt < 10; nt++) {
            short8 b = *(const short8*)(B2 + (nt << 9));
            acc2[nt] = __builtin_amdgcn_mfma_f32_16x16x32_bf16(af, b, acc2[nt], 0, 0, 0);
        }
    }
    wave_lds_fence();                                   // F3: sM1 reads done (WAR)
    #pragma unroll
    for (int nt = 0; nt < 10; nt++) {
        float m0 = silu(acc2[nt][0]);
        float m1 = silu(acc2[nt][1]);
        float m2 = silu(acc2[nt][2]);
        float m3 = silu(acc2[nt][3]);
        float p0 = __shfl_xor(m0, 1);
        float p1 = __shfl_xor(m1, 1);
        float p2 = __shfl_xor(m2, 1);
        float p3 = __shfl_xor(m3, 1);
        int k0 = nt*16 + cb16;
        if (lo) {
            *(u32*)(sW + SM_OFF + a_addr(k0, q*4+0)) = cvt_pk(m0, p0);
            *(u32*)(sW + SM_OFF + a_addr(k0, q*4+1)) = cvt_pk(m1, p1);
        } else {
            *(u32*)(sW + SM_OFF + a_addr(k0, q*4+2)) = cvt_pk(p2, m2);
            *(u32*)(sW + SM_OFF + a_addr(k0, q*4+3)) = cvt_pk(p3, m3);
        }
    }
    wave_lds_fence();                                   // F4: sM2 ready

    // ---- GEMM3: N=144, K=160 ----
    f32x4 acc3[9];
    #pragma unroll
    for (int nt = 0; nt < 9; nt++) acc3[nt] = (f32x4){0.f, 0.f, 0.f, 0.f};
    #pragma unroll
    for (int k5 = 0; k5 < 5; k5++) {
        short8 af = *(const short8*)(sW + SM_OFF + (k5 << 9) + l8);
        const u16* B3 = W3P + ((k5*9) << 9) + l8;
        #pragma unroll
        for (int nt = 0; nt < 9; nt++) {
            short8 b = *(const short8*)(B3 + (nt << 9));
            acc3[nt] = __builtin_amdgcn_mfma_f32_16x16x32_bf16(af, b, acc3[nt], 0, 0, 0);
        }
    }
    wave_lds_fence();                                   // F5: sM2 reads done (WAR vs scr)

    // ---- epilogue: bf16 scr transpose + segmented reduction over dst runs ----
    int dsts[16];
    #pragma unroll
    for (int row = 0; row < 16; row++) dsts[row] = __shfl(d2, row);
    float dxv[4], dyv[4], dzv[4], ivv[4];
    #pragma unroll
    for (int rr = 0; rr < 4; rr++) {
        int sl = (q*4 + rr) << 2;
        dxv[rr] = __shfl(dx, sl); dyv[rr] = __shfl(dy, sl);
        dzv[rr] = __shfl(dz, sl); ivv[rr] = __shfl(invf, sl);
    }

    {
        float exv[4] = {0.f, 0.f, 0.f, 0.f};
        if (col < 8) {
            #pragma unroll
            for (int rr = 0; rr < 4; rr++)
                exv[rr] = __expf(fminf(fmaxf(acc3[8][rr], -30.f), 30.f));
        }
        #pragma unroll
        for (int nt = 0; nt < 8; nt++) {
            float ex0 = __shfl(exv[0], q*16 + nt);
            float ex1 = __shfl(exv[1], q*16 + nt);
            float ex2 = __shfl(exv[2], q*16 + nt);
            float ex3 = __shfl(exv[3], q*16 + nt);
            float v0 = acc3[nt][0] * ex0;
            float v1 = acc3[nt][1] * ex1;
            float v2 = acc3[nt][2] * ex2;
            float v3 = acc3[nt][3] * ex3;
            float p0 = __shfl_xor(v0, 1);
            float p1 = __shfl_xor(v1, 1);
            float p2 = __shfl_xor(v2, 1);
            float p3 = __shfl_xor(v3, 1);
            // even cols write rows q*4+{0,1}; odd cols rows q*4+{2,3}; packed u32
            int cb = nt*16 + cb16;
            int rowA = q*4 + (lo ? 0 : 2);
            u32 wA = lo ? cvt_pk(v0, p0) : cvt_pk(p2, v2);
            u32 wB = lo ? cvt_pk(v1, p1) : cvt_pk(p3, v3);
            *(u32*)(&sW[rowA*SCR_STRIDE + cb])       = wA;
            *(u32*)(&sW[(rowA+1)*SCR_STRIDE + cb])   = wB;
        }
        if (col < 8) {
            #pragma unroll
            for (int rr = 0; rr < 4; rr++)
                sW[(q*4 + rr)*SCR_STRIDE + 128 + col] = f2bf(exv[rr]);
        }
        if (col == 8) {
            #pragma unroll
            for (int rr = 0; rr < 4; rr++) {
                float lc = fminf(fmaxf(acc3[8][rr], -1e6f), 1e6f) * ivv[rr];
                sW[(q*4 + rr)*SCR_STRIDE + 136] = f2bf(lc * dxv[rr]);
                sW[(q*4 + rr)*SCR_STRIDE + 137] = f2bf(lc * dyv[rr]);
                sW[(q*4 + rr)*SCR_STRIDE + 138] = f2bf(lc * dzv[rr]);
            }
        }
    }
    wave_lds_fence();                                   // F6: scr ready

    #pragma unroll
    for (int pass = 0; pass < 3; pass++) {
        int c = pass*64 + l;
        bool act = c < 139;
        float accu = 0.f;
        int prevd = dsts[0];
        #pragma unroll
        for (int row = 0; row < 16; row++) {
            int d = dsts[row];
            if (d != prevd) {
                if (act) {
                    if (c < 128)      atomicAdd(&hagg[(size_t)prevd*HID + c], accu);
                    else if (c < 136) atomicAdd(&den[(size_t)prevd*8 + (c-128)], accu);
                    else              atomicAdd(&cacc[(size_t)prevd*3 + (c-136)], accu);
                }
                accu = 0.f; prevd = d;
            }
            if (act) accu += bf2f(sW[row*SCR_STRIDE + c]);
        }
        if (act) {
            if (c < 128)      atomicAdd(&hagg[(size_t)prevd*HID + c], accu);
            else if (c < 136) atomicAdd(&den[(size_t)prevd*8 + (c-128)], accu);
            else              atomicAdd(&cacc[(size_t)prevd*3 + (c-136)], accu);
        }
    }
}

__global__ __launch_bounds__(256, 4)
void edge_kernel(const int* __restrict__ flag,
                 const u16* __restrict__ hbf, const void* coords, const void* a,
                 const int* __restrict__ src, const int* __restrict__ dst,
                 const int* __restrict__ perm,
                 const u16* __restrict__ We1P, const u16* __restrict__ We2P,
                 const u16* __restrict__ W3P,
                 const u16* __restrict__ cbe1, const u16* __restrict__ cbe2,
                 float* __restrict__ den, float* __restrict__ hagg,
                 float* __restrict__ cacc)
{
    __shared__ __align__(16) u16 sPool[4 * WSLICE];   // 24576 B
    if (*flag)
        edge_body<true>(hbf, coords, a, src, dst, perm, We1P, We2P, W3P,
                        cbe1, cbe2, den, hagg, cacc, sPool);
    else
        edge_body<false>(hbf, coords, a, src, dst, perm, We1P, We2P, W3P,
                         cbe1, cbe2, den, hagg, cacc, sPool);
}

// ---------------------------------------------------------------------------
// Barrier-free fused MFMA node kernel, fragment-linear B reads. (f32 den/hagg)
// ---------------------------------------------------------------------------
template<bool F32>   // applies to res / coords / out
__device__ __forceinline__ void node_body(
    const u16* __restrict__ hbf, const void* res, const void* coords,
    const u16* __restrict__ ybf,
    const float* __restrict__ den, const float* __restrict__ hagg,
    const float* __restrict__ cacc,
    const u16* __restrict__ WoP, const u16* __restrict__ Wn1P,
    const u16* __restrict__ Wn2P, const u16* __restrict__ Wf1P,
    const u16* __restrict__ Wf2P,
    const u16* __restrict__ cbn1, const u16* __restrict__ cbn2,
    const u16* __restrict__ cbf1, const u16* __restrict__ cbf2,
    void* out, u16* sScr)
{
    const int t = threadIdx.x;
    const int w = t >> 6, l = t & 63, col = l & 15, q = l >> 4;
    const int nodew = blockIdx.x * 64 + w * 16;
    const int mynode = nodew + col;
    const bool okA = mynode < N_NODES;
    const int l8 = l << 3;
    const bool lo = (col & 1) == 0;
    const int cb16 = col & ~1;
    u16* sc = sScr + w * 16 * 168;

    int gm[4]; bool okC[4];
    #pragma unroll
    for (int r = 0; r < 4; r++) { gm[r] = nodew + q*4 + r; okC[r] = gm[r] < N_NODES; }

    f32x4 aF2[8];
    #pragma unroll
    for (int nt = 0; nt < 8; nt++) aF2[nt] = (f32x4){0.f,0.f,0.f,0.f};
    #pragma unroll
    for (int c = 0; c < 2; c++) {
        #pragma unroll
        for (int ks = 0; ks < 2; ks++) {
            const int kbase = c*64 + ks*32 + q*8;
            union { u32 w[4]; short8 v; } u;
            if (okA) {
                float dd = den[(size_t)mynode*8 + (kbase >> 4)];
                float inv = dd > 0.f ? 1.f/dd : 0.f;
                const float4* gp = (const float4*)(hagg + (size_t)mynode*HID + kbase);
                float4 v0 = gp[0], v1 = gp[1];
                u.w[0] = cvt_pk(v0.x*inv, v0.y*inv);
                u.w[1] = cvt_pk(v0.z*inv, v0.w*inv);
                u.w[2] = cvt_pk(v1.x*inv, v1.y*inv);
                u.w[3] = cvt_pk(v1.z*inv, v1.w*inv);
            } else {
                #pragma unroll
                for (int j = 0; j < 4; j++) u.w[j] = 0;
            }
            const u16* B = WoP + (((c*2 + ks)*8) << 9) + l8;
            #pragma unroll
            for (int nt = 0; nt < 8; nt++) {
                short8 b = *(const short8*)(B + (nt << 9));
                aF2[nt] = __builtin_amdgcn_mfma_f32_16x16x32_bf16(u.v, b, aF2[nt], 0, 0, 0);
            }
        }
    }

    f32x4 aFl[16];
    #pragma unroll
    for (int nt = 0; nt < 16; nt++) {
        float v = bf2f(cbf1[nt*16 + col]);
        aFl[nt] = (f32x4){v,v,v,v};
    }
    #pragma unroll
    for (int ks = 0; ks < 2; ks++) {
        short8 af;
        if (okA) af = *(const short8*)(ybf + (size_t)mynode*ADY + ks*32 + q*8);
        else { union { u16 s[8]; short8 v; } z; for (int j=0;j<8;j++) z.s[j]=0; af = z.v; }
        const u16* B = Wf1P + ((ks*16) << 9) + l8;
        #pragma unroll
        for (int nt = 0; nt < 16; nt++) {
            short8 b = *(const short8*)(B + (nt << 9));
            aFl[nt] = __builtin_amdgcn_mfma_f32_16x16x32_bf16(af, b, aFl[nt], 0, 0, 0);
        }
    }

    float h1c[8][4], r1c[8][4];
    {
        float xv[8][4], s[4], ss[4];
        #pragma unroll
        for (int r = 0; r < 4; r++) { s[r] = 0.f; ss[r] = 0.f; }
        #pragma unroll
        for (int nt = 0; nt < 8; nt++)
            #pragma unroll
            for (int r = 0; r < 4; r++) {
                float hv = okC[r] ? bf2f(hbf[(size_t)gm[r]*HID + nt*16 + col]) : 0.f;
                float x = hv + aF2[nt][r];
                xv[nt][r] = x; s[r] += x; ss[r] += x*x;
            }
        #pragma unroll
        for (int r = 0; r < 4; r++)
            for (int off = 1; off <= 8; off <<= 1) {
                s[r]  += __shfl_xor(s[r], off);
                ss[r] += __shfl_xor(ss[r], off);
            }
        #pragma unroll
        for (int r = 0; r < 4; r++) {
            float mu = s[r] * (1.f/128.f);
            float var = ss[r] * (1.f/128.f) - mu*mu;
            float rs = rsqrtf(fmaxf(var, 0.f) + 1e-5f);
            #pragma unroll
            for (int nt = 0; nt < 8; nt++) {
                float h1 = (xv[nt][r]-mu)*rs*(1.f+aFl[nt][r]) + aFl[nt+8][r];
                h1c[nt][r] = h1;
                float rv = okC[r] ? ldg1<F32>(res, (size_t)gm[r]*HID + nt*16 + col) : 0.f;
                r1c[nt][r] = rv + aF2[nt][r];
            }
        }
        // paired-u32 transpose write of h1 into sc
        #pragma unroll
        for (int nt = 0; nt < 8; nt++) {
            float p0 = __shfl_xor(h1c[nt][0], 1);
            float p1 = __shfl_xor(h1c[nt][1], 1);
            float p2 = __shfl_xor(h1c[nt][2], 1);
            float p3 = __shfl_xor(h1c[nt][3], 1);
            int cb = nt*16 + cb16;
            if (lo) {
                *(u32*)(&sc[(q*4 + 0)*168 + cb]) = cvt_pk(h1c[nt][0], p0);
                *(u32*)(&sc[(q*4 + 1)*168 + cb]) = cvt_pk(h1c[nt][1], p1);
            } else {
                *(u32*)(&sc[(q*4 + 2)*168 + cb]) = cvt_pk(p2, h1c[nt][2]);
                *(u32*)(&sc[(q*4 + 3)*168 + cb]) = cvt_pk(p3, h1c[nt][3]);
            }
        }
    }
    wave_lds_fence();

    f32x4 aT[10];
    #pragma unroll
    for (int nt = 0; nt < 10; nt++) {
        float v = bf2f(cbn1[nt*16 + col]);
        aT[nt] = (f32x4){v,v,v,v};
    }
    #pragma unroll
    for (int c = 0; c < 2; c++) {
        #pragma unroll
        for (int ks = 0; ks < 2; ks++) {
            short8 af = *(const short8*)(sc + col*168 + c*64 + ks*32 + q*8);
            const u16* B = Wn1P + (((c*2 + ks)*10) << 9) + l8;
            #pragma unroll
            for (int nt = 0; nt < 10; nt++) {
                short8 b = *(const short8*)(B + (nt << 9));
                aT[nt] = __builtin_amdgcn_mfma_f32_16x16x32_bf16(af, b, aT[nt], 0, 0, 0);
            }
        }
    }
    wave_lds_fence();
    #pragma unroll
    for (int nt = 0; nt < 10; nt++) {
        float m0 = silu(aT[nt][0]);
        float m1 = silu(aT[nt][1]);
        float m2 = silu(aT[nt][2]);
        float m3 = silu(aT[nt][3]);
        float p0 = __shfl_xor(m0, 1);
        float p1 = __shfl_xor(m1, 1);
        float p2 = __shfl_xor(m2, 1);
        float p3 = __shfl_xor(m3, 1);
        int cb = nt*16 + cb16;
        if (lo) {
            *(u32*)(&sc[(q*4 + 0)*168 + cb]) = cvt_pk(m0, p0);
            *(u32*)(&sc[(q*4 + 1)*168 + cb]) = cvt_pk(m1, p1);
        } else {
            *(u32*)(&sc[(q*4 + 2)*168 + cb]) = cvt_pk(p2, m2);
            *(u32*)(&sc[(q*4 + 3)*168 + cb]) = cvt_pk(p3, m3);
        }
    }
    wave_lds_fence();

    f32x4 aF3[8];
    #pragma unroll
    for (int nt = 0; nt < 8; nt++) {
        float v = bf2f(cbn2[nt*16 + col]);
        aF3[nt] = (f32x4){v,v,v,v};
    }
    #pragma unroll
    for (int k5 = 0; k5 < 5; k5++) {
        short8 af = *(const short8*)(sc + col*168 + k5*32 + q*8);
        const u16* B = Wn2P + ((k5*8) << 9) + l8;
        #pragma unroll
        for (int nt = 0; nt < 8; nt++) {
            short8 b = *(const short8*)(B + (nt << 9));
            aF3[nt] = __builtin_amdgcn_mfma_f32_16x16x32_bf16(af, b, aF3[nt], 0, 0, 0);
        }
    }

    #pragma unroll
    for (int nt = 0; nt < 16; nt++) {
        float v = bf2f(cbf2[nt*16 + col]);
        aFl[nt] = (f32x4){v,v,v,v};
    }
    #pragma unroll
    for (int ks = 0; ks < 2; ks++) {
        short8 af;
        if (okA) af = *(const short8*)(ybf + (size_t)mynode*ADY + ks*32 + q*8);
        else { union { u16 s[8]; short8 v; } z; for (int j=0;j<8;j++) z.s[j]=0; af = z.v; }
        const u16* B = Wf2P + ((ks*16) << 9) + l8;
        #pragma unroll
        for (int nt = 0; nt < 16; nt++) {
            short8 b = *(const short8*)(B + (nt << 9));
            aFl[nt] = __builtin_amdgcn_mfma_f32_16x16x32_bf16(af, b, aFl[nt], 0, 0, 0);
        }
    }

    {
        float xv[8][4], s[4], ss[4];
        #pragma unroll
        for (int r = 0; r < 4; r++) { s[r] = 0.f; ss[r] = 0.f; }
        #pragma unroll
        for (int nt = 0; nt < 8; nt++)
            #pragma unroll
            for (int r = 0; r < 4; r++) {
                float x = h1c[nt][r] + aF3[nt][r];
                xv[nt][r] = x; s[r] += x; ss[r] += x*x;
            }
        #pragma unroll
        for (int r = 0; r < 4; r++)
            for (int off = 1; off <= 8; off <<= 1) {
                s[r]  += __shfl_xor(s[r], off);
                ss[r] += __shfl_xor(ss[r], off);
            }
        #pragma unroll
        for (int r = 0; r < 4; r++) {
            float mu = s[r] * (1.f/128.f);
            float var = ss[r] * (1.f/128.f) - mu*mu;
            float rs = rsqrtf(fmaxf(var, 0.f) + 1e-5f);
            if (okC[r]) {
                #pragma unroll
                for (int nt = 0; nt < 8; nt++) {
                    int n = nt*16 + col;
                    float h2 = (xv[nt][r]-mu)*rs*(1.f+aFl[nt][r]) + aFl[nt+8][r];
                    stg1<F32>(out, (size_t)gm[r]*HID + n, h2);
                    stg1<F32>(out, (size_t)OUT_RES + (size_t)gm[r]*HID + n,
                              r1c[nt][r] + aF3[nt][r]);
                }
            }
        }
    }

    if (q == 0 && okA) {
        #pragma unroll
        for (int j = 0; j < 3; j++)
            stg1<F32>(out, (size_t)OUT_CRD + (size_t)mynode*3 + j,
                      ldg1<F32>(coords, (size_t)mynode*3 + j) + cacc[(size_t)mynode*3 + j]);
    }
}

__global__ __launch_bounds__(256, 2)
void node_kernel(const int* __restrict__ flag,
                 const u16* __restrict__ hbf, const void* res, const void* coords,
                 const u16* __restrict__ ybf,
                 const float* __restrict__ den, const float* __restrict__ hagg,
                 const float* __restrict__ cacc,
                 const u16* __restrict__ WoP, const u16* __restrict__ Wn1P,
                 const u16* __restrict__ Wn2P, const u16* __restrict__ Wf1P,
                 const u16* __restrict__ Wf2P,
                 const u16* __restrict__ cbn1, const u16* __restrict__ cbn2,
                 const u16* __restrict__ cbf1, const u16* __restrict__ cbf2,
                 void* out)
{
    __shared__ __align__(16) u16 sScr[4 * 16 * 168];
    if (*flag)
        node_body<true>(hbf, res, coords, ybf, den, hagg, cacc, WoP, Wn1P, Wn2P,
                        Wf1P, Wf2P, cbn1, cbn2, cbf1, cbf2, out, sScr);
    else
        node_body<false>(hbf, res, coords, ybf, den, hagg, cacc, WoP, Wn1P, Wn2P,
                         Wf1P, Wf2P, cbn1, cbn2, cbf1, cbf2, out, sScr);
}

// ---------------------------------------------------------------------------
extern "C" void kernel_launch(void* const* d_in, const int* in_sizes, int n_in,
                              void* d_out, int out_size, void* d_ws, size_t ws_size,
                              hipStream_t stream)
{
    const void* h      = d_in[0];
    const void* coords = d_in[1];
    const void* a      = d_in[2];
    const void* y      = d_in[3];
    const void* res    = d_in[4];
    const int* src     = (const int*)d_in[5];
    const int* dst     = (const int*)d_in[6];

    char* ws = (char*)d_ws;
    int*   flag   = (int*)(ws + FLAG_OFF);
    int*   bar    = (int*)(ws + BAR_OFF);
    float* den    = (float*)(ws + DEN_OFF);
    float* cacc   = (float*)(ws + CACC_OFF);
    float* hagg   = (float*)(ws + HAGG_OFF);
    int*   cnt    = (int*)(ws + CNT_OFF);
    int*   cursor = (int*)(ws + CUR_OFF);
    int*   perm   = (int*)(ws + PERM_OFF);
    int*   bsum   = (int*)(ws + BSUM_OFF);
    int*   bbase  = (int*)(ws + BBASE_OFF);
    u16*   hbf    = (u16*)(ws + HBF_OFF);
    u16*   ybf    = (u16*)(ws + YBF_OFF);

    // convert list: 6 biases + h + y
    CvtArgs args;
    const int cvtn[8]   = {160, 160, 160, 128, 256, 256, N_NODES*HID, N_NODES*ADY};
    const int cvtsrc[8] = {8, 10, 16, 18, 20, 22, 0, 3};
    u64 boff[8];
    u64 bo = BIAS_OFF;
    for (int i = 0; i < 6; i++) {
        boff[i] = bo;
        bo += ((u64)cvtn[i] * 2 + 15) & ~(u64)15;
    }
    boff[6] = HBF_OFF;
    boff[7] = YBF_OFF;
    for (int i = 0; i < 8; i++) {
        args.src[i] = d_in[cvtsrc[i]];
        args.dstoff[i] = boff[i];
        args.n[i] = cvtn[i];
    }
    const u16* cbe1 = (const u16*)(ws + boff[0]);
    const u16* cbe2 = (const u16*)(ws + boff[1]);
    const u16* cbn1 = (const u16*)(ws + boff[2]);
    const u16* cbn2 = (const u16*)(ws + boff[3]);
    const u16* cbf1 = (const u16*)(ws + boff[4]);
    const u16* cbf2 = (const u16*)(ws + boff[5]);

    // fragment-linear blocked weights
    BwArgs bwa;
    bwa.We1 = d_in[7];  bwa.We2 = d_in[9];  bwa.Wv = d_in[12]; bwa.Wa = d_in[13];
    bwa.Wc  = d_in[11]; bwa.Wo  = d_in[14]; bwa.Wn1 = d_in[15]; bwa.Wn2 = d_in[17];
    bwa.Wf1 = d_in[19]; bwa.Wf2 = d_in[21];
    bwa.b1 = BW_OFF;
    bwa.b2 = bwa.b1 + (u64)5*2*10*512*2;   // 102400 B
    bwa.b3 = bwa.b2 + (u64)5*10*512*2;     //  51200 B
    bwa.b4 = bwa.b3 + (u64)5*9*512*2;      //  46080 B
    bwa.b5 = bwa.b4 + (u64)4*8*512*2;      //  32768 B
    bwa.b6 = bwa.b5 + (u64)4*10*512*2;     //  40960 B
    bwa.b7 = bwa.b6 + (u64)5*8*512*2;      //  40960 B
    bwa.b8 = bwa.b7 + (u64)2*16*512*2;     //  32768 B
    const u16* We1P = (const u16*)(ws + bwa.b1);
    const u16* We2P = (const u16*)(ws + bwa.b2);
    const u16* W3P  = (const u16*)(ws + bwa.b3);
    const u16* WoP  = (const u16*)(ws + bwa.b4);
    const u16* Wn1P = (const u16*)(ws + bwa.b5);
    const u16* Wn2P = (const u16*)(ws + bwa.b6);
    const u16* Wf1P = (const u16*)(ws + bwa.b7);
    const u16* Wf2P = (const u16*)(ws + bwa.b8);

    hipMemsetAsync(d_ws, 0, MEMSET_BYTES, stream);

    // fused: detect + cvt + weights + histogram + scan + scatter
    preproc_kernel<<<256, 256, 0, stream>>>(h, flag, ws, args, bwa, dst, cnt,
                                            cursor, perm, bar, bsum, bbase);

    edge_kernel<<<N_EDGES/64, 256, 0, stream>>>(flag, hbf, coords, a, src, dst, perm,
                                                We1P, We2P, W3P, cbe1, cbe2,
                                                den, hagg, cacc);

    node_kernel<<<(N_NODES + 63)/64, 256, 0, stream>>>(
        flag, hbf, res, coords, ybf, den, hagg, cacc,
        WoP, Wn1P, Wn2P, Wf1P, Wf2P, cbn1, cbn2, cbf1, cbf2, d_out);
}

// Round 11
// 527.361 us; speedup vs baseline: 1.1728x; 1.1728x over previous
//
#include <hip/hip_runtime.h>
#include <math.h>

#define N_NODES 25000
#define N_EDGES 400000
#define HID 128
#define EDGE_F 16
#define ADY 64
#define INNER 160
#define MSG_F 273
#define HEADS 8

// element offsets inside d_out (h2 | coords | res2)
#define OUT_CRD (N_NODES * HID)
#define OUT_RES (N_NODES * (HID + 3))

// ws byte offsets (16-aligned)
#define FLAG_OFF 0
#define DEN_OFF  256                    // f32 [25000][8]   = 800000
#define CACC_OFF 800256                 // f32 [25000][3]   = 300000
#define HAGG_OFF 1100256                // f32 [25000][128] = 12800000
#define CNT_OFF  13900256               // int [25000] histogram
#define CUR_OFF  14000256               // int [25000] scan/cursor
#define PERM_OFF 14100256               // int [400000] dst-sorted edge ids
#define MEMSET_BYTES 14000256           // zero flag..cnt (cursor/perm overwritten)
#define HBF_OFF  15700256               // h as bf16: 6.4 MB
#define YBF_OFF  22100256               // y as bf16: 3.2 MB
#define BIAS_OFF 25300256               // 6 bias tensors, bf16
#define BW_OFF   25302560               // blocked (fragment-linear) weights

// per-wave LDS slice (u16 units):
//   [0,512)     kc chunk (GEMM1 kstep 8: radial + edge feats, frag-linear)
//   [512,3072)  sM (GEMM2 input sM1, then aliased as GEMM3 input sM2)
//   [0,2336)    scr bf16 [16][SCR_STRIDE] (epilogue, aliases kc+sM)
// slice = 3072 u16 = 6144 B -> 24576 B/block.
#define WSLICE 3072
#define SM_OFF 512
#define SCR_STRIDE 146

typedef unsigned short u16;
typedef unsigned int u32;
typedef unsigned long long u64;
typedef __attribute__((ext_vector_type(8))) short short8;
typedef __attribute__((ext_vector_type(4))) float f32x4;

__device__ __forceinline__ float bf2f(u16 v) {
    union { u32 u; float f; } x; x.u = ((u32)v) << 16; return x.f;
}
__device__ __forceinline__ u16 f2bf(float f) {
    union { float ff; u32 u; } x; x.ff = f;
    u32 u = x.u;
    u32 rounding = 0x7FFFu + ((u >> 16) & 1u);
    u += rounding;
    return (u16)(u >> 16);
}
// HW packed bf16 convert: one instruction for 2 floats (guide T12, m240).
__device__ __forceinline__ u32 cvt_pk(float lo, float hi) {
    u32 r;
    asm("v_cvt_pk_bf16_f32 %0, %1, %2" : "=v"(r) : "v"(lo), "v"(hi));
    return r;
}
__device__ __forceinline__ float silu(float z) {
    z = fminf(fmaxf(z, -30000.f), 30000.f);
    return z / (1.0f + __expf(-z));
}

template<bool F32> __device__ __forceinline__ float ldg1(const void* p, size_t i) {
    if (F32) return ((const float*)p)[i];
    return bf2f(((const u16*)p)[i]);
}
template<bool F32> __device__ __forceinline__ void stg1(void* p, size_t i, float v) {
    if (F32) ((float*)p)[i] = v;
    else     ((u16*)p)[i] = f2bf(v);
}
__device__ __forceinline__ float ldany(const void* p, size_t i, bool f32) {
    return f32 ? ((const float*)p)[i] : bf2f(((const u16*)p)[i]);
}
// wave-level LDS fence (all LDS regions are wave-private)
__device__ __forceinline__ void wave_lds_fence() {
    __builtin_amdgcn_wave_barrier();
    __builtin_amdgcn_s_waitcnt(0xc07f);   // lgkmcnt(0) only
    __builtin_amdgcn_wave_barrier();
}

// A-fragment address for 16x16x32 bf16 (K-major frag-linear LDS layout)
__device__ __forceinline__ int a_addr(int k, int lr) {
    return ((k >> 5) << 9) + (((((k & 31) >> 3) << 4) | lr) << 3) + (k & 7);
}

// ---------------------------------------------------------------------------
// Fused preprocessing: dtype detect + cvt + fragment-linear blockw + dst hist.
// (R11: reverted to R8's 3-kernel sort pipeline -- R10's grid-barrier fusion
// cost +125us from cross-XCD spin contention.)
// ---------------------------------------------------------------------------
struct CvtArgs {
    const void* src[8];
    u64 dstoff[8];
    int n[8];
};
struct BwArgs {
    const void* We1; const void* We2; const void* Wv; const void* Wa;
    const void* Wc;  const void* Wo;  const void* Wn1; const void* Wn2;
    const void* Wf1; const void* Wf2;
    u64 b1, b2, b3, b4, b5, b6, b7, b8;
};

__global__ __launch_bounds__(256)
void preproc_kernel(const void* hsrc, int* flag, char* ws, CvtArgs args, BwArgs bwa,
                    const int* __restrict__ dstp, int* __restrict__ cnt)
{
    __shared__ float red[256];
    __shared__ int sflag;
    const int t = threadIdx.x;
    {
        const u16* p = (const u16*)hsrc;
        float mx = 0.f;
        for (int i = 0; i < 8; i++) {
            int idx = (t * 8 + i) * 97;
            float v = fabsf(bf2f(p[idx * 2]));
            mx = fmaxf(mx, v);
        }
        red[t] = mx;
        __syncthreads();
        for (int s = 128; s > 0; s >>= 1) {
            if (t < s) red[t] = fmaxf(red[t], red[t + s]);
            __syncthreads();
        }
        if (t == 0) {
            sflag = (red[0] > 1e10f || red[0] == 0.f) ? 1 : 0;
            if (blockIdx.x == 0) flag[0] = sflag;
        }
        __syncthreads();
    }
    const bool f32 = (sflag != 0);
    const int g = blockIdx.x * 256 + t;
    const int stride = gridDim.x * 256;

    // ---- dst histogram for counting sort ----
    for (int i = g; i < N_EDGES; i += stride)
        atomicAdd(&cnt[dstp[i]], 1);

    // ---- cvt: biases + h + y ----
    for (int ten = 0; ten < 8; ten++) {
        const void* s = args.src[ten];
        u16* d = (u16*)(ws + args.dstoff[ten]);
        const int n = args.n[ten];
        if (f32) {
            const float* sf = (const float*)s;
            for (int i = g; i < n; i += stride) d[i] = f2bf(sf[i]);
        } else {
            const u16* su = (const u16*)s;
            for (int i = g; i < n; i += stride) d[i] = su[i];
        }
    }

    // ---- fragment-linear blocked weights ----
    u16* b1 = (u16*)(ws + bwa.b1);
    u16* b2 = (u16*)(ws + bwa.b2);
    u16* b3 = (u16*)(ws + bwa.b3);
    u16* b4 = (u16*)(ws + bwa.b4);
    u16* b5 = (u16*)(ws + bwa.b5);
    u16* b6 = (u16*)(ws + bwa.b6);
    u16* b7 = (u16*)(ws + bwa.b7);
    u16* b8 = (u16*)(ws + bwa.b8);
    // We1P: [5c][2ks][10nt] tiles, K=320 logical (k==273 -> dup row 256)
    for (int i = g; i < 5*2*10*512; i += stride) {
        int tt = i >> 9, r = i & 511, l = r >> 3, j = r & 7;
        int c = tt / 20, ks = (tt / 10) % 2, nt = tt % 10;
        int k = c*64 + ks*32 + (l >> 4)*8 + j;
        int n = nt*16 + (l & 15);
        float v = 0.f;
        if (k < MSG_F)      v = ldany(bwa.We1, (size_t)k*INNER + n, f32);
        else if (k == 273)  v = ldany(bwa.We1, (size_t)256*INNER + n, f32);
        b1[i] = f2bf(v);
    }
    // We2P: [5 k5][10 nt], K=160
    for (int i = g; i < 5*10*512; i += stride) {
        int tt = i >> 9, r = i & 511, l = r >> 3, j = r & 7;
        int k5 = tt / 10, nt = tt % 10;
        int k = k5*32 + (l >> 4)*8 + j;
        int n = nt*16 + (l & 15);
        b2[i] = f2bf(ldany(bwa.We2, (size_t)k*INNER + n, f32));
    }
    // W3P: [5 k5][9 nt], K=160; n<128 Wv | n<136 Wa | n==136 Wc | else 0
    for (int i = g; i < 5*9*512; i += stride) {
        int tt = i >> 9, r = i & 511, l = r >> 3, j = r & 7;
        int k5 = tt / 9, nt = tt % 9;
        int k = k5*32 + (l >> 4)*8 + j;
        int n = nt*16 + (l & 15);
        float v = 0.f;
        if (n < 128)       v = ldany(bwa.Wv, (size_t)k*HID + n, f32);
        else if (n < 136)  v = ldany(bwa.Wa, (size_t)k*HEADS + (n-128), f32);
        else if (n == 136) v = ldany(bwa.Wc, (size_t)k, f32);
        b3[i] = f2bf(v);
    }
    // WoP: [4 cks][8 nt], K=128
    for (int i = g; i < 4*8*512; i += stride) {
        int tt = i >> 9, r = i & 511, l = r >> 3, j = r & 7;
        int cks = tt / 8, nt = tt % 8;
        int k = cks*32 + (l >> 4)*8 + j;
        int n = nt*16 + (l & 15);
        b4[i] = f2bf(ldany(bwa.Wo, (size_t)k*HID + n, f32));
    }
    // Wn1P: [4 cks][10 nt], K=128
    for (int i = g; i < 4*10*512; i += stride) {
        int tt = i >> 9, r = i & 511, l = r >> 3, j = r & 7;
        int cks = tt / 10, nt = tt % 10;
        int k = cks*32 + (l >> 4)*8 + j;
        int n = nt*16 + (l & 15);
        b5[i] = f2bf(ldany(bwa.Wn1, (size_t)k*INNER + n, f32));
    }
    // Wn2P: [5 k5][8 nt], K=160
    for (int i = g; i < 5*8*512; i += stride) {
        int tt = i >> 9, r = i & 511, l = r >> 3, j = r & 7;
        int k5 = tt / 8, nt = tt % 8;
        int k = k5*32 + (l >> 4)*8 + j;
        int n = nt*16 + (l & 15);
        b6[i] = f2bf(ldany(bwa.Wn2, (size_t)k*HID + n, f32));
    }
    // Wf1P / Wf2P: [2 ks][16 nt], K=64
    for (int i = g; i < 2*16*512; i += stride) {
        int tt = i >> 9, r = i & 511, l = r >> 3, j = r & 7;
        int ks = tt / 16, nt = tt % 16;
        int k = ks*32 + (l >> 4)*8 + j;
        int n = nt*16 + (l & 15);
        b7[i] = f2bf(ldany(bwa.Wf1, (size_t)k*256 + n, f32));
        b8[i] = f2bf(ldany(bwa.Wf2, (size_t)k*256 + n, f32));
    }
}

// ---------------------------------------------------------------------------
// Counting-sort: exclusive scan of the 25000-bin histogram (single block).
// ---------------------------------------------------------------------------
__global__ __launch_bounds__(1024)
void scan_kernel(const int* __restrict__ cnt, int* __restrict__ cursor)
{
    __shared__ int ssum[1024];
    const int t = threadIdx.x;
    const int base = t * 25;
    int loc[25];
    int s = 0;
    #pragma unroll
    for (int j = 0; j < 25; j++) {
        int i = base + j;
        int v = (i < N_NODES) ? cnt[i] : 0;
        loc[j] = s; s += v;
    }
    ssum[t] = s;
    __syncthreads();
    for (int off = 1; off < 1024; off <<= 1) {
        int v = (t >= off) ? ssum[t - off] : 0;
        __syncthreads();
        ssum[t] += v;
        __syncthreads();
    }
    int offs = (t > 0) ? ssum[t - 1] : 0;
    #pragma unroll
    for (int j = 0; j < 25; j++) {
        int i = base + j;
        if (i < N_NODES) cursor[i] = offs + loc[j];
    }
}

__global__ __launch_bounds__(256)
void scatter_kernel(const int* __restrict__ dstp, int* __restrict__ cursor,
                    int* __restrict__ perm)
{
    int i = blockIdx.x * 256 + threadIdx.x;
    if (i < N_EDGES) {
        int pos = atomicAdd(&cursor[dstp[i]], 1);
        perm[pos] = i;
    }
}

// ---------------------------------------------------------------------------
// Barrier-free MFMA edge kernel, dst-sorted, 6144 B LDS/wave.
// R11: __launch_bounds__(256,3) -> ~170 unified regs/wave. The (256,4)
// 128-reg cap forced arch VGPRs to 64 (acc takes ~64 AGPR-side) and spilled
// one short8/lane (= 25+ MB HBM scratch round-trips, R7-R10). 12 waves/CU
// (vs 14-16) trades ~12% occupancy for zero spill.
// ---------------------------------------------------------------------------
template<bool F32>   // applies to coords / a only
__device__ __forceinline__ void edge_body(
    const u16* __restrict__ hbf, const void* coords, const void* a,
    const int* __restrict__ src, const int* __restrict__ dst,
    const int* __restrict__ perm,
    const u16* __restrict__ We1P, const u16* __restrict__ We2P,
    const u16* __restrict__ W3P,
    const u16* __restrict__ cbe1, const u16* __restrict__ cbe2,
    float* __restrict__ den, float* __restrict__ hagg, float* __restrict__ cacc,
    u16* sPool)
{
    const int t   = threadIdx.x;
    const int w   = t >> 6;
    const int l   = t & 63;
    const int col = l & 15;
    const int q   = l >> 4;
    const int e0  = blockIdx.x * 64;
    const int l8  = l << 3;

    u16* sW = sPool + w * WSLICE;

    // per-lane edge for A-gathers: edge index = col (row of the MFMA A tile)
    const int ge2 = perm[e0 + w*16 + col];
    const int s2 = src[ge2];
    const int d2 = dst[ge2];

    // ---- batch-load ALL 8 A-fragments into registers (one vmcnt window) ----
    short8 afr[8];
    {
        const u16* hs = hbf + (size_t)s2*HID + q*8;
        const u16* hd = hbf + (size_t)d2*HID + q*8;
        #pragma unroll
        for (int kk = 0; kk < 4; kk++) {
            afr[kk]     = *(const short8*)(hs + (kk << 5));
            afr[4 + kk] = *(const short8*)(hd + (kk << 5));
        }
    }

    // ---- staging lanes: coords/radial/a -> kc chunk + metadata regs ----
    const int er = l >> 2;          // edge row 0..15 (4 lanes per edge)
    const int p  = l & 3;
    const int ge = perm[e0 + w*16 + er];
    float dx = 0.f, dy = 0.f, dz = 0.f, invf = 0.f, r2 = 0.f;
    if (p < 2) {
        int s_ = src[ge], d_ = dst[ge];
        dx = ldg1<F32>(coords, (size_t)s_*3+0) - ldg1<F32>(coords, (size_t)d_*3+0);
        dy = ldg1<F32>(coords, (size_t)s_*3+1) - ldg1<F32>(coords, (size_t)d_*3+1);
        dz = ldg1<F32>(coords, (size_t)s_*3+2) - ldg1<F32>(coords, (size_t)d_*3+2);
        r2 = dx*dx + dy*dy + dz*dz;
        invf = 1.0f / (sqrtf(r2 + 1e-5f) + 1.0f);
        __align__(16) u16 tmp[16];
        #pragma unroll
        for (int j = 0; j < 16; j++) tmp[j] = 0;
        if (p == 0) {
            tmp[0] = f2bf(r2);                               // k=256 radial hi
            for (int j = 0; j < 15; j++)
                tmp[1+j] = f2bf(ldg1<F32>(a, (size_t)ge*EDGE_F + j));
        } else {
            tmp[0] = f2bf(ldg1<F32>(a, (size_t)ge*EDGE_F + 15));
            tmp[1] = f2bf(r2 - bf2f(f2bf(r2)));              // k=273 radial lo
        }
        // local frag-linear addr within the 32-wide kc tile
        *(uint4*)(sW + (32*p + er)*8)      = ((uint4*)tmp)[0];
        *(uint4*)(sW + (32*p + 16 + er)*8) = ((uint4*)tmp)[1];
    }
    wave_lds_fence();                                   // F1: kc staged

    // ---- GEMM1: K=288 (8 register ksteps + 1 LDS kstep) ----
    f32x4 acc1[10];
    #pragma unroll
    for (int nt = 0; nt < 10; nt++) {
        float v = bf2f(cbe1[nt*16 + col]);
        acc1[nt] = (f32x4){v, v, v, v};
    }
    #pragma unroll
    for (int kk = 0; kk < 8; kk++) {
        const u16* B1 = We1P + ((kk*10) << 9) + l8;
        #pragma unroll
        for (int nt = 0; nt < 10; nt++) {
            short8 b = *(const short8*)(B1 + (nt << 9));
            acc1[nt] = __builtin_amdgcn_mfma_f32_16x16x32_bf16(afr[kk], b, acc1[nt], 0, 0, 0);
        }
    }
    {   // kstep 8: radial + edge features from LDS
        short8 af = *(const short8*)(sW + l8);
        const u16* B1 = We1P + ((8*10) << 9) + l8;
        #pragma unroll
        for (int nt = 0; nt < 10; nt++) {
            short8 b = *(const short8*)(B1 + (nt << 9));
            acc1[nt] = __builtin_amdgcn_mfma_f32_16x16x32_bf16(af, b, acc1[nt], 0, 0, 0);
        }
    }
    // kc reads done; sM1 writes go to disjoint region [512,3072) -> no fence.
    // Paired u32 transpose write via cvt_pk: lane pair (col, col^1) = adjacent k.
    const bool lo = (col & 1) == 0;
    const int cb16 = col & ~1;
    #pragma unroll
    for (int nt = 0; nt < 10; nt++) {
        float m0 = silu(acc1[nt][0]);
        float m1 = silu(acc1[nt][1]);
        float m2 = silu(acc1[nt][2]);
        float m3 = silu(acc1[nt][3]);
        float p0 = __shfl_xor(m0, 1);
        float p1 = __shfl_xor(m1, 1);
        float p2 = __shfl_xor(m2, 1);
        float p3 = __shfl_xor(m3, 1);
        int k0 = nt*16 + cb16;
        if (lo) {
            *(u32*)(sW + SM_OFF + a_addr(k0, q*4+0)) = cvt_pk(m0, p0);
            *(u32*)(sW + SM_OFF + a_addr(k0, q*4+1)) = cvt_pk(m1, p1);
        } else {
            *(u32*)(sW + SM_OFF + a_addr(k0, q*4+2)) = cvt_pk(p2, m2);
            *(u32*)(sW + SM_OFF + a_addr(k0, q*4+3)) = cvt_pk(p3, m3);
        }
    }
    wave_lds_fence();                                   // F2: sM1 ready

    // ---- GEMM2: K=160 ----
    f32x4 acc2[10];
    #pragma unroll
    for (int nt = 0; nt < 10; nt++) {
        float v = bf2f(cbe2[nt*16 + col]);
        acc2[nt] = (f32x4){v, v, v, v};
    }
    #pragma unroll
    for (int k5 = 0; k5 < 5; k5++) {
        short8 af = *(const short8*)(sW + SM_OFF + (k5 << 9) + l8);
        const u16* B2 = We2P + ((k5*10) << 9) + l8;
        #pragma unroll
        for (int nt = 0; nt < 10; nt++) {
            short8 b = *(const short8*)(B2 + (nt << 9));
            acc2[nt] = __builtin_amdgcn_mfma_f32_16x16x32_bf16(af, b, acc2[nt], 0, 0, 0);
        }
    }
    wave_lds_fence();                                   // F3: sM1 reads done (WAR)
    #pragma unroll
    for (int nt = 0; nt < 10; nt++) {
        float m0 = silu(acc2[nt][0]);
        float m1 = silu(acc2[nt][1]);
        float m2 = silu(acc2[nt][2]);
        float m3 = silu(acc2[nt][3]);
        float p0 = __shfl_xor(m0, 1);
        float p1 = __shfl_xor(m1, 1);
        float p2 = __shfl_xor(m2, 1);
        float p3 = __shfl_xor(m3, 1);
        int k0 = nt*16 + cb16;
        if (lo) {
            *(u32*)(sW + SM_OFF + a_addr(k0, q*4+0)) = cvt_pk(m0, p0);
            *(u32*)(sW + SM_OFF + a_addr(k0, q*4+1)) = cvt_pk(m1, p1);
        } else {
            *(u32*)(sW + SM_OFF + a_addr(k0, q*4+2)) = cvt_pk(p2, m2);
            *(u32*)(sW + SM_OFF + a_addr(k0, q*4+3)) = cvt_pk(p3, m3);
        }
    }
    wave_lds_fence();                                   // F4: sM2 ready

    // ---- GEMM3: N=144, K=160 ----
    f32x4 acc3[9];
    #pragma unroll
    for (int nt = 0; nt < 9; nt++) acc3[nt] = (f32x4){0.f, 0.f, 0.f, 0.f};
    #pragma unroll
    for (int k5 = 0; k5 < 5; k5++) {
        short8 af = *(const short8*)(sW + SM_OFF + (k5 << 9) + l8);
        const u16* B3 = W3P + ((k5*9) << 9) + l8;
        #pragma unroll
        for (int nt = 0; nt < 9; nt++) {
            short8 b = *(const short8*)(B3 + (nt << 9));
            acc3[nt] = __builtin_amdgcn_mfma_f32_16x16x32_bf16(af, b, acc3[nt], 0, 0, 0);
        }
    }
    wave_lds_fence();                                   // F5: sM2 reads done (WAR vs scr)

    // ---- epilogue: bf16 scr transpose + segmented reduction over dst runs ----
    int dsts[16];
    #pragma unroll
    for (int row = 0; row < 16; row++) dsts[row] = __shfl(d2, row);
    float dxv[4], dyv[4], dzv[4], ivv[4];
    #pragma unroll
    for (int rr = 0; rr < 4; rr++) {
        int sl = (q*4 + rr) << 2;
        dxv[rr] = __shfl(dx, sl); dyv[rr] = __shfl(dy, sl);
        dzv[rr] = __shfl(dz, sl); ivv[rr] = __shfl(invf, sl);
    }

    {
        float exv[4] = {0.f, 0.f, 0.f, 0.f};
        if (col < 8) {
            #pragma unroll
            for (int rr = 0; rr < 4; rr++)
                exv[rr] = __expf(fminf(fmaxf(acc3[8][rr], -30.f), 30.f));
        }
        #pragma unroll
        for (int nt = 0; nt < 8; nt++) {
            float ex0 = __shfl(exv[0], q*16 + nt);
            float ex1 = __shfl(exv[1], q*16 + nt);
            float ex2 = __shfl(exv[2], q*16 + nt);
            float ex3 = __shfl(exv[3], q*16 + nt);
            float v0 = acc3[nt][0] * ex0;
            float v1 = acc3[nt][1] * ex1;
            float v2 = acc3[nt][2] * ex2;
            float v3 = acc3[nt][3] * ex3;
            float p0 = __shfl_xor(v0, 1);
            float p1 = __shfl_xor(v1, 1);
            float p2 = __shfl_xor(v2, 1);
            float p3 = __shfl_xor(v3, 1);
            // even cols write rows q*4+{0,1}; odd cols rows q*4+{2,3}; packed u32
            int cb = nt*16 + cb16;
            int rowA = q*4 + (lo ? 0 : 2);
            u32 wA = lo ? cvt_pk(v0, p0) : cvt_pk(p2, v2);
            u32 wB = lo ? cvt_pk(v1, p1) : cvt_pk(p3, v3);
            *(u32*)(&sW[rowA*SCR_STRIDE + cb])       = wA;
            *(u32*)(&sW[(rowA+1)*SCR_STRIDE + cb])   = wB;
        }
        if (col < 8) {
            #pragma unroll
            for (int rr = 0; rr < 4; rr++)
                sW[(q*4 + rr)*SCR_STRIDE + 128 + col] = f2bf(exv[rr]);
        }
        if (col == 8) {
            #pragma unroll
            for (int rr = 0; rr < 4; rr++) {
                float lc = fminf(fmaxf(acc3[8][rr], -1e6f), 1e6f) * ivv[rr];
                sW[(q*4 + rr)*SCR_STRIDE + 136] = f2bf(lc * dxv[rr]);
                sW[(q*4 + rr)*SCR_STRIDE + 137] = f2bf(lc * dyv[rr]);
                sW[(q*4 + rr)*SCR_STRIDE + 138] = f2bf(lc * dzv[rr]);
            }
        }
    }
    wave_lds_fence();                                   // F6: scr ready

    #pragma unroll
    for (int pass = 0; pass < 3; pass++) {
        int c = pass*64 + l;
        bool act = c < 139;
        float accu = 0.f;
        int prevd = dsts[0];
        #pragma unroll
        for (int row = 0; row < 16; row++) {
            int d = dsts[row];
            if (d != prevd) {
                if (act) {
                    if (c < 128)      atomicAdd(&hagg[(size_t)prevd*HID + c], accu);
                    else if (c < 136) atomicAdd(&den[(size_t)prevd*8 + (c-128)], accu);
                    else              atomicAdd(&cacc[(size_t)prevd*3 + (c-136)], accu);
                }
                accu = 0.f; prevd = d;
            }
            if (act) accu += bf2f(sW[row*SCR_STRIDE + c]);
        }
        if (act) {
            if (c < 128)      atomicAdd(&hagg[(size_t)prevd*HID + c], accu);
            else if (c < 136) atomicAdd(&den[(size_t)prevd*8 + (c-128)], accu);
            else              atomicAdd(&cacc[(size_t)prevd*3 + (c-136)], accu);
        }
    }
}

__global__ __launch_bounds__(256, 3)
void edge_kernel(const int* __restrict__ flag,
                 const u16* __restrict__ hbf, const void* coords, const void* a,
                 const int* __restrict__ src, const int* __restrict__ dst,
                 const int* __restrict__ perm,
                 const u16* __restrict__ We1P, const u16* __restrict__ We2P,
                 const u16* __restrict__ W3P,
                 const u16* __restrict__ cbe1, const u16* __restrict__ cbe2,
                 float* __restrict__ den, float* __restrict__ hagg,
                 float* __restrict__ cacc)
{
    __shared__ __align__(16) u16 sPool[4 * WSLICE];   // 24576 B
    if (*flag)
        edge_body<true>(hbf, coords, a, src, dst, perm, We1P, We2P, W3P,
                        cbe1, cbe2, den, hagg, cacc, sPool);
    else
        edge_body<false>(hbf, coords, a, src, dst, perm, We1P, We2P, W3P,
                         cbe1, cbe2, den, hagg, cacc, sPool);
}

// ---------------------------------------------------------------------------
// Barrier-free fused MFMA node kernel, fragment-linear B reads. (f32 den/hagg)
// ---------------------------------------------------------------------------
template<bool F32>   // applies to res / coords / out
__device__ __forceinline__ void node_body(
    const u16* __restrict__ hbf, const void* res, const void* coords,
    const u16* __restrict__ ybf,
    const float* __restrict__ den, const float* __restrict__ hagg,
    const float* __restrict__ cacc,
    const u16* __restrict__ WoP, const u16* __restrict__ Wn1P,
    const u16* __restrict__ Wn2P, const u16* __restrict__ Wf1P,
    const u16* __restrict__ Wf2P,
    const u16* __restrict__ cbn1, const u16* __restrict__ cbn2,
    const u16* __restrict__ cbf1, const u16* __restrict__ cbf2,
    void* out, u16* sScr)
{
    const int t = threadIdx.x;
    const int w = t >> 6, l = t & 63, col = l & 15, q = l >> 4;
    const int nodew = blockIdx.x * 64 + w * 16;
    const int mynode = nodew + col;
    const bool okA = mynode < N_NODES;
    const int l8 = l << 3;
    const bool lo = (col & 1) == 0;
    const int cb16 = col & ~1;
    u16* sc = sScr + w * 16 * 168;

    int gm[4]; bool okC[4];
    #pragma unroll
    for (int r = 0; r < 4; r++) { gm[r] = nodew + q*4 + r; okC[r] = gm[r] < N_NODES; }

    f32x4 aF2[8];
    #pragma unroll
    for (int nt = 0; nt < 8; nt++) aF2[nt] = (f32x4){0.f,0.f,0.f,0.f};
    #pragma unroll
    for (int c = 0; c < 2; c++) {
        #pragma unroll
        for (int ks = 0; ks < 2; ks++) {
            const int kbase = c*64 + ks*32 + q*8;
            union { u32 w[4]; short8 v; } u;
            if (okA) {
                float dd = den[(size_t)mynode*8 + (kbase >> 4)];
                float inv = dd > 0.f ? 1.f/dd : 0.f;
                const float4* gp = (const float4*)(hagg + (size_t)mynode*HID + kbase);
                float4 v0 = gp[0], v1 = gp[1];
                u.w[0] = cvt_pk(v0.x*inv, v0.y*inv);
                u.w[1] = cvt_pk(v0.z*inv, v0.w*inv);
                u.w[2] = cvt_pk(v1.x*inv, v1.y*inv);
                u.w[3] = cvt_pk(v1.z*inv, v1.w*inv);
            } else {
                #pragma unroll
                for (int j = 0; j < 4; j++) u.w[j] = 0;
            }
            const u16* B = WoP + (((c*2 + ks)*8) << 9) + l8;
            #pragma unroll
            for (int nt = 0; nt < 8; nt++) {
                short8 b = *(const short8*)(B + (nt << 9));
                aF2[nt] = __builtin_amdgcn_mfma_f32_16x16x32_bf16(u.v, b, aF2[nt], 0, 0, 0);
            }
        }
    }

    f32x4 aFl[16];
    #pragma unroll
    for (int nt = 0; nt < 16; nt++) {
        float v = bf2f(cbf1[nt*16 + col]);
        aFl[nt] = (f32x4){v,v,v,v};
    }
    #pragma unroll
    for (int ks = 0; ks < 2; ks++) {
        short8 af;
        if (okA) af = *(const short8*)(ybf + (size_t)mynode*ADY + ks*32 + q*8);
        else { union { u16 s[8]; short8 v; } z; for (int j=0;j<8;j++) z.s[j]=0; af = z.v; }
        const u16* B = Wf1P + ((ks*16) << 9) + l8;
        #pragma unroll
        for (int nt = 0; nt < 16; nt++) {
            short8 b = *(const short8*)(B + (nt << 9));
            aFl[nt] = __builtin_amdgcn_mfma_f32_16x16x32_bf16(af, b, aFl[nt], 0, 0, 0);
        }
    }

    float h1c[8][4], r1c[8][4];
    {
        float xv[8][4], s[4], ss[4];
        #pragma unroll
        for (int r = 0; r < 4; r++) { s[r] = 0.f; ss[r] = 0.f; }
        #pragma unroll
        for (int nt = 0; nt < 8; nt++)
            #pragma unroll
            for (int r = 0; r < 4; r++) {
                float hv = okC[r] ? bf2f(hbf[(size_t)gm[r]*HID + nt*16 + col]) : 0.f;
                float x = hv + aF2[nt][r];
                xv[nt][r] = x; s[r] += x; ss[r] += x*x;
            }
        #pragma unroll
        for (int r = 0; r < 4; r++)
            for (int off = 1; off <= 8; off <<= 1) {
                s[r]  += __shfl_xor(s[r], off);
                ss[r] += __shfl_xor(ss[r], off);
            }
        #pragma unroll
        for (int r = 0; r < 4; r++) {
            float mu = s[r] * (1.f/128.f);
            float var = ss[r] * (1.f/128.f) - mu*mu;
            float rs = rsqrtf(fmaxf(var, 0.f) + 1e-5f);
            #pragma unroll
            for (int nt = 0; nt < 8; nt++) {
                float h1 = (xv[nt][r]-mu)*rs*(1.f+aFl[nt][r]) + aFl[nt+8][r];
                h1c[nt][r] = h1;
                float rv = okC[r] ? ldg1<F32>(res, (size_t)gm[r]*HID + nt*16 + col) : 0.f;
                r1c[nt][r] = rv + aF2[nt][r];
            }
        }
        // paired-u32 transpose write of h1 into sc
        #pragma unroll
        for (int nt = 0; nt < 8; nt++) {
            float p0 = __shfl_xor(h1c[nt][0], 1);
            float p1 = __shfl_xor(h1c[nt][1], 1);
            float p2 = __shfl_xor(h1c[nt][2], 1);
            float p3 = __shfl_xor(h1c[nt][3], 1);
            int cb = nt*16 + cb16;
            if (lo) {
                *(u32*)(&sc[(q*4 + 0)*168 + cb]) = cvt_pk(h1c[nt][0], p0);
                *(u32*)(&sc[(q*4 + 1)*168 + cb]) = cvt_pk(h1c[nt][1], p1);
            } else {
                *(u32*)(&sc[(q*4 + 2)*168 + cb]) = cvt_pk(p2, h1c[nt][2]);
                *(u32*)(&sc[(q*4 + 3)*168 + cb]) = cvt_pk(p3, h1c[nt][3]);
            }
        }
    }
    wave_lds_fence();

    f32x4 aT[10];
    #pragma unroll
    for (int nt = 0; nt < 10; nt++) {
        float v = bf2f(cbn1[nt*16 + col]);
        aT[nt] = (f32x4){v,v,v,v};
    }
    #pragma unroll
    for (int c = 0; c < 2; c++) {
        #pragma unroll
        for (int ks = 0; ks < 2; ks++) {
            short8 af = *(const short8*)(sc + col*168 + c*64 + ks*32 + q*8);
            const u16* B = Wn1P + (((c*2 + ks)*10) << 9) + l8;
            #pragma unroll
            for (int nt = 0; nt < 10; nt++) {
                short8 b = *(const short8*)(B + (nt << 9));
                aT[nt] = __builtin_amdgcn_mfma_f32_16x16x32_bf16(af, b, aT[nt], 0, 0, 0);
            }
        }
    }
    wave_lds_fence();
    #pragma unroll
    for (int nt = 0; nt < 10; nt++) {
        float m0 = silu(aT[nt][0]);
        float m1 = silu(aT[nt][1]);
        float m2 = silu(aT[nt][2]);
        float m3 = silu(aT[nt][3]);
        float p0 = __shfl_xor(m0, 1);
        float p1 = __shfl_xor(m1, 1);
        float p2 = __shfl_xor(m2, 1);
        float p3 = __shfl_xor(m3, 1);
        int cb = nt*16 + cb16;
        if (lo) {
            *(u32*)(&sc[(q*4 + 0)*168 + cb]) = cvt_pk(m0, p0);
            *(u32*)(&sc[(q*4 + 1)*168 + cb]) = cvt_pk(m1, p1);
        } else {
            *(u32*)(&sc[(q*4 + 2)*168 + cb]) = cvt_pk(p2, m2);
            *(u32*)(&sc[(q*4 + 3)*168 + cb]) = cvt_pk(p3, m3);
        }
    }
    wave_lds_fence();

    f32x4 aF3[8];
    #pragma unroll
    for (int nt = 0; nt < 8; nt++) {
        float v = bf2f(cbn2[nt*16 + col]);
        aF3[nt] = (f32x4){v,v,v,v};
    }
    #pragma unroll
    for (int k5 = 0; k5 < 5; k5++) {
        short8 af = *(const short8*)(sc + col*168 + k5*32 + q*8);
        const u16* B = Wn2P + ((k5*8) << 9) + l8;
        #pragma unroll
        for (int nt = 0; nt < 8; nt++) {
            short8 b = *(const short8*)(B + (nt << 9));
            aF3[nt] = __builtin_amdgcn_mfma_f32_16x16x32_bf16(af, b, aF3[nt], 0, 0, 0);
        }
    }

    #pragma unroll
    for (int nt = 0; nt < 16; nt++) {
        float v = bf2f(cbf2[nt*16 + col]);
        aFl[nt] = (f32x4){v,v,v,v};
    }
    #pragma unroll
    for (int ks = 0; ks < 2; ks++) {
        short8 af;
        if (okA) af = *(const short8*)(ybf + (size_t)mynode*ADY + ks*32 + q*8);
        else { union { u16 s[8]; short8 v; } z; for (int j=0;j<8;j++) z.s[j]=0; af = z.v; }
        const u16* B = Wf2P + ((ks*16) << 9) + l8;
        #pragma unroll
        for (int nt = 0; nt < 16; nt++) {
            short8 b = *(const short8*)(B + (nt << 9));
            aFl[nt] = __builtin_amdgcn_mfma_f32_16x16x32_bf16(af, b, aFl[nt], 0, 0, 0);
        }
    }

    {
        float xv[8][4], s[4], ss[4];
        #pragma unroll
        for (int r = 0; r < 4; r++) { s[r] = 0.f; ss[r] = 0.f; }
        #pragma unroll
        for (int nt = 0; nt < 8; nt++)
            #pragma unroll
            for (int r = 0; r < 4; r++) {
                float x = h1c[nt][r] + aF3[nt][r];
                xv[nt][r] = x; s[r] += x; ss[r] += x*x;
            }
        #pragma unroll
        for (int r = 0; r < 4; r++)
            for (int off = 1; off <= 8; off <<= 1) {
                s[r]  += __shfl_xor(s[r], off);
                ss[r] += __shfl_xor(ss[r], off);
            }
        #pragma unroll
        for (int r = 0; r < 4; r++) {
            float mu = s[r] * (1.f/128.f);
            float var = ss[r] * (1.f/128.f) - mu*mu;
            float rs = rsqrtf(fmaxf(var, 0.f) + 1e-5f);
            if (okC[r]) {
                #pragma unroll
                for (int nt = 0; nt < 8; nt++) {
                    int n = nt*16 + col;
                    float h2 = (xv[nt][r]-mu)*rs*(1.f+aFl[nt][r]) + aFl[nt+8][r];
                    stg1<F32>(out, (size_t)gm[r]*HID + n, h2);
                    stg1<F32>(out, (size_t)OUT_RES + (size_t)gm[r]*HID + n,
                              r1c[nt][r] + aF3[nt][r]);
                }
            }
        }
    }

    if (q == 0 && okA) {
        #pragma unroll
        for (int j = 0; j < 3; j++)
            stg1<F32>(out, (size_t)OUT_CRD + (size_t)mynode*3 + j,
                      ldg1<F32>(coords, (size_t)mynode*3 + j) + cacc[(size_t)mynode*3 + j]);
    }
}

__global__ __launch_bounds__(256, 2)
void node_kernel(const int* __restrict__ flag,
                 const u16* __restrict__ hbf, const void* res, const void* coords,
                 const u16* __restrict__ ybf,
                 const float* __restrict__ den, const float* __restrict__ hagg,
                 const float* __restrict__ cacc,
                 const u16* __restrict__ WoP, const u16* __restrict__ Wn1P,
                 const u16* __restrict__ Wn2P, const u16* __restrict__ Wf1P,
                 const u16* __restrict__ Wf2P,
                 const u16* __restrict__ cbn1, const u16* __restrict__ cbn2,
                 const u16* __restrict__ cbf1, const u16* __restrict__ cbf2,
                 void* out)
{
    __shared__ __align__(16) u16 sScr[4 * 16 * 168];
    if (*flag)
        node_body<true>(hbf, res, coords, ybf, den, hagg, cacc, WoP, Wn1P, Wn2P,
                        Wf1P, Wf2P, cbn1, cbn2, cbf1, cbf2, out, sScr);
    else
        node_body<false>(hbf, res, coords, ybf, den, hagg, cacc, WoP, Wn1P, Wn2P,
                         Wf1P, Wf2P, cbn1, cbn2, cbf1, cbf2, out, sScr);
}

// ---------------------------------------------------------------------------
extern "C" void kernel_launch(void* const* d_in, const int* in_sizes, int n_in,
                              void* d_out, int out_size, void* d_ws, size_t ws_size,
                              hipStream_t stream)
{
    const void* h      = d_in[0];
    const void* coords = d_in[1];
    const void* a      = d_in[2];
    const void* y      = d_in[3];
    const void* res    = d_in[4];
    const int* src     = (const int*)d_in[5];
    const int* dst     = (const int*)d_in[6];

    char* ws = (char*)d_ws;
    int*   flag   = (int*)(ws + FLAG_OFF);
    float* den    = (float*)(ws + DEN_OFF);
    float* cacc   = (float*)(ws + CACC_OFF);
    float* hagg   = (float*)(ws + HAGG_OFF);
    int*   cnt    = (int*)(ws + CNT_OFF);
    int*   cursor = (int*)(ws + CUR_OFF);
    int*   perm   = (int*)(ws + PERM_OFF);
    u16*   hbf    = (u16*)(ws + HBF_OFF);
    u16*   ybf    = (u16*)(ws + YBF_OFF);

    // convert list: 6 biases + h + y
    CvtArgs args;
    const int cvtn[8]   = {160, 160, 160, 128, 256, 256, N_NODES*HID, N_NODES*ADY};
    const int cvtsrc[8] = {8, 10, 16, 18, 20, 22, 0, 3};
    u64 boff[8];
    u64 bo = BIAS_OFF;
    for (int i = 0; i < 6; i++) {
        boff[i] = bo;
        bo += ((u64)cvtn[i] * 2 + 15) & ~(u64)15;
    }
    boff[6] = HBF_OFF;
    boff[7] = YBF_OFF;
    for (int i = 0; i < 8; i++) {
        args.src[i] = d_in[cvtsrc[i]];
        args.dstoff[i] = boff[i];
        args.n[i] = cvtn[i];
    }
    const u16* cbe1 = (const u16*)(ws + boff[0]);
    const u16* cbe2 = (const u16*)(ws + boff[1]);
    const u16* cbn1 = (const u16*)(ws + boff[2]);
    const u16* cbn2 = (const u16*)(ws + boff[3]);
    const u16* cbf1 = (const u16*)(ws + boff[4]);
    const u16* cbf2 = (const u16*)(ws + boff[5]);

    // fragment-linear blocked weights
    BwArgs bwa;
    bwa.We1 = d_in[7];  bwa.We2 = d_in[9];  bwa.Wv = d_in[12]; bwa.Wa = d_in[13];
    bwa.Wc  = d_in[11]; bwa.Wo  = d_in[14]; bwa.Wn1 = d_in[15]; bwa.Wn2 = d_in[17];
    bwa.Wf1 = d_in[19]; bwa.Wf2 = d_in[21];
    bwa.b1 = BW_OFF;
    bwa.b2 = bwa.b1 + (u64)5*2*10*512*2;   // 102400 B
    bwa.b3 = bwa.b2 + (u64)5*10*512*2;     //  51200 B
    bwa.b4 = bwa.b3 + (u64)5*9*512*2;      //  46080 B
    bwa.b5 = bwa.b4 + (u64)4*8*512*2;      //  32768 B
    bwa.b6 = bwa.b5 + (u64)4*10*512*2;     //  40960 B
    bwa.b7 = bwa.b6 + (u64)5*8*512*2;      //  40960 B
    bwa.b8 = bwa.b7 + (u64)2*16*512*2;     //  32768 B
    const u16* We1P = (const u16*)(ws + bwa.b1);
    const u16* We2P = (const u16*)(ws + bwa.b2);
    const u16* W3P  = (const u16*)(ws + bwa.b3);
    const u16* WoP  = (const u16*)(ws + bwa.b4);
    const u16* Wn1P = (const u16*)(ws + bwa.b5);
    const u16* Wn2P = (const u16*)(ws + bwa.b6);
    const u16* Wf1P = (const u16*)(ws + bwa.b7);
    const u16* Wf2P = (const u16*)(ws + bwa.b8);

    hipMemsetAsync(d_ws, 0, MEMSET_BYTES, stream);

    preproc_kernel<<<256, 256, 0, stream>>>(h, flag, ws, args, bwa, dst, cnt);

    scan_kernel<<<1, 1024, 0, stream>>>(cnt, cursor);

    scatter_kernel<<<(N_EDGES + 255)/256, 256, 0, stream>>>(dst, cursor, perm);

    edge_kernel<<<N_EDGES/64, 256, 0, stream>>>(flag, hbf, coords, a, src, dst, perm,
                                                We1P, We2P, W3P, cbe1, cbe2,
                                                den, hagg, cacc);

    node_kernel<<<(N_NODES + 63)/64, 256, 0, stream>>>(
        flag, hbf, res, coords, ybf, den, hagg, cacc,
        WoP, Wn1P, Wn2P, Wf1P, Wf2P, cbn1, cbn2, cbf1, cbf2, d_out);
}

// Round 15
// 485.092 us; speedup vs baseline: 1.2750x; 1.0871x over previous
//
#include <hip/hip_runtime.h>
#include <math.h>

#define N_NODES 25000
#define N_EDGES 400000
#define HID 128
#define EDGE_F 16
#define ADY 64
#define INNER 160
#define MSG_F 273
#define HEADS 8

// element offsets inside d_out (h2 | coords | res2)
#define OUT_CRD (N_NODES * HID)
#define OUT_RES (N_NODES * (HID + 3))

// ws byte offsets (16-aligned)
#define FLAG_OFF 0
#define DEN_OFF  256                    // f32 [25000][8]   = 800000
#define CACC_OFF 800256                 // f32 [25000][3]   = 300000
#define HAGG_OFF 1100256                // f32 [25000][128] = 12800000
#define CNT_OFF  13900256               // int [25000] histogram
#define CUR_OFF  14000256               // int [25000] scan/cursor
#define PERM_OFF 14100256               // int [400000] dst-sorted edge ids
#define MEMSET_BYTES 14000256           // zero flag..cnt (cursor/perm overwritten)
#define HBF_OFF  15700256               // h as bf16: 6.4 MB
#define YBF_OFF  22100256               // y as bf16: 3.2 MB
#define BIAS_OFF 25300256               // 6 bias tensors, bf16
#define BW_OFF   25302560               // blocked (fragment-linear) weights

// per-wave LDS slice (u16 units), R12 = R4 structure:
//   sF  [0,4608)     9 frag-linear ksteps (h_src 4, h_dst 4, kc 1)
//   sM1 [0,2560)     GEMM2 input (aliases sF after GEMM1)
//   sM2 [2560,5120)  GEMM3 input (aliases sF tail, dead after GEMM1)
//   scr [0,2336)     bf16 [16][SCR_STRIDE] epilogue (aliases sM1)
// slice = 5120 u16 = 10240 B -> 40960 B/block -> 4 blocks/CU, no extra arrays.
#define WSLICE 5120
#define SM2_OFF 2560
#define SCR_STRIDE 146

typedef unsigned short u16;
typedef unsigned int u32;
typedef unsigned long long u64;
typedef __attribute__((ext_vector_type(8))) short short8;
typedef __attribute__((ext_vector_type(4))) float f32x4;

__device__ __forceinline__ float bf2f(u16 v) {
    union { u32 u; float f; } x; x.u = ((u32)v) << 16; return x.f;
}
__device__ __forceinline__ u16 f2bf(float f) {
    union { float ff; u32 u; } x; x.ff = f;
    u32 u = x.u;
    u32 rounding = 0x7FFFu + ((u >> 16) & 1u);
    u += rounding;
    return (u16)(u >> 16);
}
// HW packed bf16 convert: one instruction for 2 floats (guide T12, m240).
__device__ __forceinline__ u32 cvt_pk(float lo, float hi) {
    u32 r;
    asm("v_cvt_pk_bf16_f32 %0, %1, %2" : "=v"(r) : "v"(lo), "v"(hi));
    return r;
}
__device__ __forceinline__ float silu(float z) {
    z = fminf(fmaxf(z, -30000.f), 30000.f);
    return z / (1.0f + __expf(-z));
}

template<bool F32> __device__ __forceinline__ float ldg1(const void* p, size_t i) {
    if (F32) return ((const float*)p)[i];
    return bf2f(((const u16*)p)[i]);
}
template<bool F32> __device__ __forceinline__ void stg1(void* p, size_t i, float v) {
    if (F32) ((float*)p)[i] = v;
    else     ((u16*)p)[i] = f2bf(v);
}
__device__ __forceinline__ float ldany(const void* p, size_t i, bool f32) {
    return f32 ? ((const float*)p)[i] : bf2f(((const u16*)p)[i]);
}
// wave-level LDS fence (all LDS regions are wave-private)
__device__ __forceinline__ void wave_lds_fence() {
    __builtin_amdgcn_wave_barrier();
    __builtin_amdgcn_s_waitcnt(0xc07f);   // lgkmcnt(0) only
    __builtin_amdgcn_wave_barrier();
}

// A-fragment address for 16x16x32 bf16 (K-major frag-linear LDS layout)
__device__ __forceinline__ int a_addr(int k, int lr) {
    return ((k >> 5) << 9) + (((((k & 31) >> 3) << 4) | lr) << 3) + (k & 7);
}

// ---------------------------------------------------------------------------
// Fused preprocessing: dtype detect + cvt + fragment-linear blockw + dst hist.
// ---------------------------------------------------------------------------
struct CvtArgs {
    const void* src[8];
    u64 dstoff[8];
    int n[8];
};
struct BwArgs {
    const void* We1; const void* We2; const void* Wv; const void* Wa;
    const void* Wc;  const void* Wo;  const void* Wn1; const void* Wn2;
    const void* Wf1; const void* Wf2;
    u64 b1, b2, b3, b4, b5, b6, b7, b8;
};

__global__ __launch_bounds__(256)
void preproc_kernel(const void* hsrc, int* flag, char* ws, CvtArgs args, BwArgs bwa,
                    const int* __restrict__ dstp, int* __restrict__ cnt)
{
    __shared__ float red[256];
    __shared__ int sflag;
    const int t = threadIdx.x;
    {
        const u16* p = (const u16*)hsrc;
        float mx = 0.f;
        for (int i = 0; i < 8; i++) {
            int idx = (t * 8 + i) * 97;
            float v = fabsf(bf2f(p[idx * 2]));
            mx = fmaxf(mx, v);
        }
        red[t] = mx;
        __syncthreads();
        for (int s = 128; s > 0; s >>= 1) {
            if (t < s) red[t] = fmaxf(red[t], red[t + s]);
            __syncthreads();
        }
        if (t == 0) {
            sflag = (red[0] > 1e10f || red[0] == 0.f) ? 1 : 0;
            if (blockIdx.x == 0) flag[0] = sflag;
        }
        __syncthreads();
    }
    const bool f32 = (sflag != 0);
    const int g = blockIdx.x * 256 + t;
    const int stride = gridDim.x * 256;

    // ---- dst histogram for counting sort ----
    for (int i = g; i < N_EDGES; i += stride)
        atomicAdd(&cnt[dstp[i]], 1);

    // ---- cvt: biases + h + y ----
    for (int ten = 0; ten < 8; ten++) {
        const void* s = args.src[ten];
        u16* d = (u16*)(ws + args.dstoff[ten]);
        const int n = args.n[ten];
        if (f32) {
            const float* sf = (const float*)s;
            for (int i = g; i < n; i += stride) d[i] = f2bf(sf[i]);
        } else {
            const u16* su = (const u16*)s;
            for (int i = g; i < n; i += stride) d[i] = su[i];
        }
    }

    // ---- fragment-linear blocked weights ----
    u16* b1 = (u16*)(ws + bwa.b1);
    u16* b2 = (u16*)(ws + bwa.b2);
    u16* b3 = (u16*)(ws + bwa.b3);
    u16* b4 = (u16*)(ws + bwa.b4);
    u16* b5 = (u16*)(ws + bwa.b5);
    u16* b6 = (u16*)(ws + bwa.b6);
    u16* b7 = (u16*)(ws + bwa.b7);
    u16* b8 = (u16*)(ws + bwa.b8);
    // We1P: [5c][2ks][10nt] tiles, K=320 logical (k==273 -> dup row 256)
    for (int i = g; i < 5*2*10*512; i += stride) {
        int tt = i >> 9, r = i & 511, l = r >> 3, j = r & 7;
        int c = tt / 20, ks = (tt / 10) % 2, nt = tt % 10;
        int k = c*64 + ks*32 + (l >> 4)*8 + j;
        int n = nt*16 + (l & 15);
        float v = 0.f;
        if (k < MSG_F)      v = ldany(bwa.We1, (size_t)k*INNER + n, f32);
        else if (k == 273)  v = ldany(bwa.We1, (size_t)256*INNER + n, f32);
        b1[i] = f2bf(v);
    }
    // We2P: [5 k5][10 nt], K=160
    for (int i = g; i < 5*10*512; i += stride) {
        int tt = i >> 9, r = i & 511, l = r >> 3, j = r & 7;
        int k5 = tt / 10, nt = tt % 10;
        int k = k5*32 + (l >> 4)*8 + j;
        int n = nt*16 + (l & 15);
        b2[i] = f2bf(ldany(bwa.We2, (size_t)k*INNER + n, f32));
    }
    // W3P: [5 k5][9 nt], K=160; n<128 Wv | n<136 Wa | n==136 Wc | else 0
    for (int i = g; i < 5*9*512; i += stride) {
        int tt = i >> 9, r = i & 511, l = r >> 3, j = r & 7;
        int k5 = tt / 9, nt = tt % 9;
        int k = k5*32 + (l >> 4)*8 + j;
        int n = nt*16 + (l & 15);
        float v = 0.f;
        if (n < 128)       v = ldany(bwa.Wv, (size_t)k*HID + n, f32);
        else if (n < 136)  v = ldany(bwa.Wa, (size_t)k*HEADS + (n-128), f32);
        else if (n == 136) v = ldany(bwa.Wc, (size_t)k, f32);
        b3[i] = f2bf(v);
    }
    // WoP: [4 cks][8 nt], K=128
    for (int i = g; i < 4*8*512; i += stride) {
        int tt = i >> 9, r = i & 511, l = r >> 3, j = r & 7;
        int cks = tt / 8, nt = tt % 8;
        int k = cks*32 + (l >> 4)*8 + j;
        int n = nt*16 + (l & 15);
        b4[i] = f2bf(ldany(bwa.Wo, (size_t)k*HID + n, f32));
    }
    // Wn1P: [4 cks][10 nt], K=128
    for (int i = g; i < 4*10*512; i += stride) {
        int tt = i >> 9, r = i & 511, l = r >> 3, j = r & 7;
        int cks = tt / 10, nt = tt % 10;
        int k = cks*32 + (l >> 4)*8 + j;
        int n = nt*16 + (l & 15);
        b5[i] = f2bf(ldany(bwa.Wn1, (size_t)k*INNER + n, f32));
    }
    // Wn2P: [5 k5][8 nt], K=160
    for (int i = g; i < 5*8*512; i += stride) {
        int tt = i >> 9, r = i & 511, l = r >> 3, j = r & 7;
        int k5 = tt / 8, nt = tt % 8;
        int k = k5*32 + (l >> 4)*8 + j;
        int n = nt*16 + (l & 15);
        b6[i] = f2bf(ldany(bwa.Wn2, (size_t)k*HID + n, f32));
    }
    // Wf1P / Wf2P: [2 ks][16 nt], K=64
    for (int i = g; i < 2*16*512; i += stride) {
        int tt = i >> 9, r = i & 511, l = r >> 3, j = r & 7;
        int ks = tt / 16, nt = tt % 16;
        int k = ks*32 + (l >> 4)*8 + j;
        int n = nt*16 + (l & 15);
        b7[i] = f2bf(ldany(bwa.Wf1, (size_t)k*256 + n, f32));
        b8[i] = f2bf(ldany(bwa.Wf2, (size_t)k*256 + n, f32));
    }
}

// ---------------------------------------------------------------------------
// Counting-sort: exclusive scan of the 25000-bin histogram (single block).
// ---------------------------------------------------------------------------
__global__ __launch_bounds__(1024)
void scan_kernel(const int* __restrict__ cnt, int* __restrict__ cursor)
{
    __shared__ int ssum[1024];
    const int t = threadIdx.x;
    const int base = t * 25;
    int loc[25];
    int s = 0;
    #pragma unroll
    for (int j = 0; j < 25; j++) {
        int i = base + j;
        int v = (i < N_NODES) ? cnt[i] : 0;
        loc[j] = s; s += v;
    }
    ssum[t] = s;
    __syncthreads();
    for (int off = 1; off < 1024; off <<= 1) {
        int v = (t >= off) ? ssum[t - off] : 0;
        __syncthreads();
        ssum[t] += v;
        __syncthreads();
    }
    int offs = (t > 0) ? ssum[t - 1] : 0;
    #pragma unroll
    for (int j = 0; j < 25; j++) {
        int i = base + j;
        if (i < N_NODES) cursor[i] = offs + loc[j];
    }
}

__global__ __launch_bounds__(256)
void scatter_kernel(const int* __restrict__ dstp, int* __restrict__ cursor,
                    int* __restrict__ perm)
{
    int i = blockIdx.x * 256 + threadIdx.x;
    if (i < N_EDGES) {
        int pos = atomicAdd(&cursor[dstp[i]], 1);
        perm[pos] = i;
    }
}

// ---------------------------------------------------------------------------
// Barrier-free MFMA edge kernel, dst-sorted. R12 = R4's winning LDS-staged
// structure (VGPR ~60, true 4 blocks/CU, no spill, best measured 233us)
// + R8's cvt_pk paired-u32 transposes (halves ds_write count + VALU pack
// cost; R4 had 11M bank conflicts from scalar u16 writes) + bf16 scr +
// register/shfl metadata (no extra LDS arrays -> exactly 40960 B).
// ---------------------------------------------------------------------------
template<bool F32>   // applies to coords / a only
__device__ __forceinline__ void edge_body(
    const u16* __restrict__ hbf, const void* coords, const void* a,
    const int* __restrict__ src, const int* __restrict__ dst,
    const int* __restrict__ perm,
    const u16* __restrict__ We1P, const u16* __restrict__ We2P,
    const u16* __restrict__ W3P,
    const u16* __restrict__ cbe1, const u16* __restrict__ cbe2,
    float* __restrict__ den, float* __restrict__ hagg, float* __restrict__ cacc,
    u16* sPool)
{
    const int t   = threadIdx.x;
    const int w   = t >> 6;
    const int l   = t & 63;
    const int col = l & 15;
    const int q   = l >> 4;
    const int e0  = blockIdx.x * 64;
    const int l8  = l << 3;

    u16* sW = sPool + w * WSLICE;

    // ---- staging: 4 lanes per edge, h -> frag-linear LDS; metadata in regs ----
    const int er = l >> 2;          // edge row 0..15 within wave tile
    const int p  = l & 3;
    const int ge = perm[e0 + w*16 + er];
    const int s_ = src[ge];
    const int d_ = dst[ge];
    float dx = 0.f, dy = 0.f, dz = 0.f, invf = 0.f, r2 = 0.f;
    #pragma unroll
    for (int c = 0; c < 4; c++) {
        int node = (c < 2) ? s_ : d_;
        int c0 = (c & 1) * 64 + p * 16;
        const uint4* gp = (const uint4*)(hbf + (size_t)node*HID + c0);
        int k0 = c*64 + p*16;
        *(uint4*)(sW + a_addr(k0,     er)) = gp[0];
        *(uint4*)(sW + a_addr(k0 + 8, er)) = gp[1];
    }
    if (p < 2) {
        dx = ldg1<F32>(coords, (size_t)s_*3+0) - ldg1<F32>(coords, (size_t)d_*3+0);
        dy = ldg1<F32>(coords, (size_t)s_*3+1) - ldg1<F32>(coords, (size_t)d_*3+1);
        dz = ldg1<F32>(coords, (size_t)s_*3+2) - ldg1<F32>(coords, (size_t)d_*3+2);
        r2 = dx*dx + dy*dy + dz*dz;
        invf = 1.0f / (sqrtf(r2 + 1e-5f) + 1.0f);
        __align__(16) u16 tmp[16];
        #pragma unroll
        for (int j = 0; j < 16; j++) tmp[j] = 0;
        if (p == 0) {
            tmp[0] = f2bf(r2);                               // k=256 radial hi
            for (int j = 0; j < 15; j++)
                tmp[1+j] = f2bf(ldg1<F32>(a, (size_t)ge*EDGE_F + j));
        } else {
            tmp[0] = f2bf(ldg1<F32>(a, (size_t)ge*EDGE_F + 15));
            tmp[1] = f2bf(r2 - bf2f(f2bf(r2)));              // k=273 radial lo
        }
        int k0 = 256 + p*16;
        *(uint4*)(sW + a_addr(k0,     er)) = ((uint4*)tmp)[0];
        *(uint4*)(sW + a_addr(k0 + 8, er)) = ((uint4*)tmp)[1];
    }
    wave_lds_fence();                                   // F1: sF staged

    // ---- GEMM1: K=288, 9 LDS ksteps ----
    f32x4 acc1[10];
    #pragma unroll
    for (int nt = 0; nt < 10; nt++) {
        float v = bf2f(cbe1[nt*16 + col]);
        acc1[nt] = (f32x4){v, v, v, v};
    }
    #pragma unroll
    for (int kk = 0; kk < 9; kk++) {
        short8 af = *(const short8*)(sW + (kk << 9) + l8);
        const u16* B1 = We1P + ((kk*10) << 9) + l8;
        #pragma unroll
        for (int nt = 0; nt < 10; nt++) {
            short8 b = *(const short8*)(B1 + (nt << 9));
            acc1[nt] = __builtin_amdgcn_mfma_f32_16x16x32_bf16(af, b, acc1[nt], 0, 0, 0);
        }
    }
    wave_lds_fence();                                   // F2a: sF reads done (WAR)

    // sM1 -> [0,2560): paired u32 transpose writes via cvt_pk
    const bool lo = (col & 1) == 0;
    const int cb16 = col & ~1;
    #pragma unroll
    for (int nt = 0; nt < 10; nt++) {
        float m0 = silu(acc1[nt][0]);
        float m1 = silu(acc1[nt][1]);
        float m2 = silu(acc1[nt][2]);
        float m3 = silu(acc1[nt][3]);
        float p0 = __shfl_xor(m0, 1);
        float p1 = __shfl_xor(m1, 1);
        float p2 = __shfl_xor(m2, 1);
        float p3 = __shfl_xor(m3, 1);
        int k0 = nt*16 + cb16;
        if (lo) {
            *(u32*)(sW + a_addr(k0, q*4+0)) = cvt_pk(m0, p0);
            *(u32*)(sW + a_addr(k0, q*4+1)) = cvt_pk(m1, p1);
        } else {
            *(u32*)(sW + a_addr(k0, q*4+2)) = cvt_pk(p2, m2);
            *(u32*)(sW + a_addr(k0, q*4+3)) = cvt_pk(p3, m3);
        }
    }
    wave_lds_fence();                                   // F2: sM1 ready

    // ---- GEMM2: K=160 ----
    f32x4 acc2[10];
    #pragma unroll
    for (int nt = 0; nt < 10; nt++) {
        float v = bf2f(cbe2[nt*16 + col]);
        acc2[nt] = (f32x4){v, v, v, v};
    }
    #pragma unroll
    for (int k5 = 0; k5 < 5; k5++) {
        short8 af = *(const short8*)(sW + (k5 << 9) + l8);
        const u16* B2 = We2P + ((k5*10) << 9) + l8;
        #pragma unroll
        for (int nt = 0; nt < 10; nt++) {
            short8 b = *(const short8*)(B2 + (nt << 9));
            acc2[nt] = __builtin_amdgcn_mfma_f32_16x16x32_bf16(af, b, acc2[nt], 0, 0, 0);
        }
    }
    // sM2 -> [2560,5120): disjoint from sM1 reads; prior sF ops ordered by F2a/F2
    #pragma unroll
    for (int nt = 0; nt < 10; nt++) {
        float m0 = silu(acc2[nt][0]);
        float m1 = silu(acc2[nt][1]);
        float m2 = silu(acc2[nt][2]);
        float m3 = silu(acc2[nt][3]);
        float p0 = __shfl_xor(m0, 1);
        float p1 = __shfl_xor(m1, 1);
        float p2 = __shfl_xor(m2, 1);
        float p3 = __shfl_xor(m3, 1);
        int k0 = nt*16 + cb16;
        if (lo) {
            *(u32*)(sW + SM2_OFF + a_addr(k0, q*4+0)) = cvt_pk(m0, p0);
            *(u32*)(sW + SM2_OFF + a_addr(k0, q*4+1)) = cvt_pk(m1, p1);
        } else {
            *(u32*)(sW + SM2_OFF + a_addr(k0, q*4+2)) = cvt_pk(p2, m2);
            *(u32*)(sW + SM2_OFF + a_addr(k0, q*4+3)) = cvt_pk(p3, m3);
        }
    }
    wave_lds_fence();                                   // F3: sM2 ready

    // ---- GEMM3: N=144, K=160 ----
    f32x4 acc3[9];
    #pragma unroll
    for (int nt = 0; nt < 9; nt++) acc3[nt] = (f32x4){0.f, 0.f, 0.f, 0.f};
    #pragma unroll
    for (int k5 = 0; k5 < 5; k5++) {
        short8 af = *(const short8*)(sW + SM2_OFF + (k5 << 9) + l8);
        const u16* B3 = W3P + ((k5*9) << 9) + l8;
        #pragma unroll
        for (int nt = 0; nt < 9; nt++) {
            short8 b = *(const short8*)(B3 + (nt << 9));
            acc3[nt] = __builtin_amdgcn_mfma_f32_16x16x32_bf16(af, b, acc3[nt], 0, 0, 0);
        }
    }
    // scr -> [0,2336) bf16: aliases sM1 (dead, reads ordered by F3); GEMM3
    // reads [2560,5120) are disjoint -> no fence needed before scr writes.

    // ---- epilogue: bf16 scr transpose + segmented reduction over dst runs ----
    int dsts[16];
    #pragma unroll
    for (int row = 0; row < 16; row++) dsts[row] = __shfl(d_, row << 2);
    float dxv[4], dyv[4], dzv[4], ivv[4];
    #pragma unroll
    for (int rr = 0; rr < 4; rr++) {
        int sl = (q*4 + rr) << 2;
        dxv[rr] = __shfl(dx, sl); dyv[rr] = __shfl(dy, sl);
        dzv[rr] = __shfl(dz, sl); ivv[rr] = __shfl(invf, sl);
    }

    {
        float exv[4] = {0.f, 0.f, 0.f, 0.f};
        if (col < 8) {
            #pragma unroll
            for (int rr = 0; rr < 4; rr++)
                exv[rr] = __expf(fminf(fmaxf(acc3[8][rr], -30.f), 30.f));
        }
        #pragma unroll
        for (int nt = 0; nt < 8; nt++) {
            float ex0 = __shfl(exv[0], q*16 + nt);
            float ex1 = __shfl(exv[1], q*16 + nt);
            float ex2 = __shfl(exv[2], q*16 + nt);
            float ex3 = __shfl(exv[3], q*16 + nt);
            float v0 = acc3[nt][0] * ex0;
            float v1 = acc3[nt][1] * ex1;
            float v2 = acc3[nt][2] * ex2;
            float v3 = acc3[nt][3] * ex3;
            float p0 = __shfl_xor(v0, 1);
            float p1 = __shfl_xor(v1, 1);
            float p2 = __shfl_xor(v2, 1);
            float p3 = __shfl_xor(v3, 1);
            // even cols write rows q*4+{0,1}; odd cols rows q*4+{2,3}; packed u32
            int cb = nt*16 + cb16;
            int rowA = q*4 + (lo ? 0 : 2);
            u32 wA = lo ? cvt_pk(v0, p0) : cvt_pk(p2, v2);
            u32 wB = lo ? cvt_pk(v1, p1) : cvt_pk(p3, v3);
            *(u32*)(&sW[rowA*SCR_STRIDE + cb])       = wA;
            *(u32*)(&sW[(rowA+1)*SCR_STRIDE + cb])   = wB;
        }
        if (col < 8) {
            #pragma unroll
            for (int rr = 0; rr < 4; rr++)
                sW[(q*4 + rr)*SCR_STRIDE + 128 + col] = f2bf(exv[rr]);
        }
        if (col == 8) {
            #pragma unroll
            for (int rr = 0; rr < 4; rr++) {
                float lc = fminf(fmaxf(acc3[8][rr], -1e6f), 1e6f) * ivv[rr];
                sW[(q*4 + rr)*SCR_STRIDE + 136] = f2bf(lc * dxv[rr]);
                sW[(q*4 + rr)*SCR_STRIDE + 137] = f2bf(lc * dyv[rr]);
                sW[(q*4 + rr)*SCR_STRIDE + 138] = f2bf(lc * dzv[rr]);
            }
        }
    }
    wave_lds_fence();                                   // F4: scr ready

    #pragma unroll
    for (int pass = 0; pass < 3; pass++) {
        int c = pass*64 + l;
        bool act = c < 139;
        float accu = 0.f;
        int prevd = dsts[0];
        #pragma unroll
        for (int row = 0; row < 16; row++) {
            int d = dsts[row];
            if (d != prevd) {
                if (act) {
                    if (c < 128)      atomicAdd(&hagg[(size_t)prevd*HID + c], accu);
                    else if (c < 136) atomicAdd(&den[(size_t)prevd*8 + (c-128)], accu);
                    else              atomicAdd(&cacc[(size_t)prevd*3 + (c-136)], accu);
                }
                accu = 0.f; prevd = d;
            }
            if (act) accu += bf2f(sW[row*SCR_STRIDE + c]);
        }
        if (act) {
            if (c < 128)      atomicAdd(&hagg[(size_t)prevd*HID + c], accu);
            else if (c < 136) atomicAdd(&den[(size_t)prevd*8 + (c-128)], accu);
            else              atomicAdd(&cacc[(size_t)prevd*3 + (c-136)], accu);
        }
    }
}

__global__ __launch_bounds__(256, 4)
void edge_kernel(const int* __restrict__ flag,
                 const u16* __restrict__ hbf, const void* coords, const void* a,
                 const int* __restrict__ src, const int* __restrict__ dst,
                 const int* __restrict__ perm,
                 const u16* __restrict__ We1P, const u16* __restrict__ We2P,
                 const u16* __restrict__ W3P,
                 const u16* __restrict__ cbe1, const u16* __restrict__ cbe2,
                 float* __restrict__ den, float* __restrict__ hagg,
                 float* __restrict__ cacc)
{
    __shared__ __align__(16) u16 sPool[4 * WSLICE];   // 40960 B -> 4 blocks/CU
    if (*flag)
        edge_body<true>(hbf, coords, a, src, dst, perm, We1P, We2P, W3P,
                        cbe1, cbe2, den, hagg, cacc, sPool);
    else
        edge_body<false>(hbf, coords, a, src, dst, perm, We1P, We2P, W3P,
                         cbe1, cbe2, den, hagg, cacc, sPool);
}

// ---------------------------------------------------------------------------
// Barrier-free fused MFMA node kernel, fragment-linear B reads. (f32 den/hagg)
// ---------------------------------------------------------------------------
template<bool F32>   // applies to res / coords / out
__device__ __forceinline__ void node_body(
    const u16* __restrict__ hbf, const void* res, const void* coords,
    const u16* __restrict__ ybf,
    const float* __restrict__ den, const float* __restrict__ hagg,
    const float* __restrict__ cacc,
    const u16* __restrict__ WoP, const u16* __restrict__ Wn1P,
    const u16* __restrict__ Wn2P, const u16* __restrict__ Wf1P,
    const u16* __restrict__ Wf2P,
    const u16* __restrict__ cbn1, const u16* __restrict__ cbn2,
    const u16* __restrict__ cbf1, const u16* __restrict__ cbf2,
    void* out, u16* sScr)
{
    const int t = threadIdx.x;
    const int w = t >> 6, l = t & 63, col = l & 15, q = l >> 4;
    const int nodew = blockIdx.x * 64 + w * 16;
    const int mynode = nodew + col;
    const bool okA = mynode < N_NODES;
    const int l8 = l << 3;
    const bool lo = (col & 1) == 0;
    const int cb16 = col & ~1;
    u16* sc = sScr + w * 16 * 168;

    int gm[4]; bool okC[4];
    #pragma unroll
    for (int r = 0; r < 4; r++) { gm[r] = nodew + q*4 + r; okC[r] = gm[r] < N_NODES; }

    f32x4 aF2[8];
    #pragma unroll
    for (int nt = 0; nt < 8; nt++) aF2[nt] = (f32x4){0.f,0.f,0.f,0.f};
    #pragma unroll
    for (int c = 0; c < 2; c++) {
        #pragma unroll
        for (int ks = 0; ks < 2; ks++) {
            const int kbase = c*64 + ks*32 + q*8;
            union { u32 w[4]; short8 v; } u;
            if (okA) {
                float dd = den[(size_t)mynode*8 + (kbase >> 4)];
                float inv = dd > 0.f ? 1.f/dd : 0.f;
                const float4* gp = (const float4*)(hagg + (size_t)mynode*HID + kbase);
                float4 v0 = gp[0], v1 = gp[1];
                u.w[0] = cvt_pk(v0.x*inv, v0.y*inv);
                u.w[1] = cvt_pk(v0.z*inv, v0.w*inv);
                u.w[2] = cvt_pk(v1.x*inv, v1.y*inv);
                u.w[3] = cvt_pk(v1.z*inv, v1.w*inv);
            } else {
                #pragma unroll
                for (int j = 0; j < 4; j++) u.w[j] = 0;
            }
            const u16* B = WoP + (((c*2 + ks)*8) << 9) + l8;
            #pragma unroll
            for (int nt = 0; nt < 8; nt++) {
                short8 b = *(const short8*)(B + (nt << 9));
                aF2[nt] = __builtin_amdgcn_mfma_f32_16x16x32_bf16(u.v, b, aF2[nt], 0, 0, 0);
            }
        }
    }

    f32x4 aFl[16];
    #pragma unroll
    for (int nt = 0; nt < 16; nt++) {
        float v = bf2f(cbf1[nt*16 + col]);
        aFl[nt] = (f32x4){v,v,v,v};
    }
    #pragma unroll
    for (int ks = 0; ks < 2; ks++) {
        short8 af;
        if (okA) af = *(const short8*)(ybf + (size_t)mynode*ADY + ks*32 + q*8);
        else { union { u16 s[8]; short8 v; } z; for (int j=0;j<8;j++) z.s[j]=0; af = z.v; }
        const u16* B = Wf1P + ((ks*16) << 9) + l8;
        #pragma unroll
        for (int nt = 0; nt < 16; nt++) {
            short8 b = *(const short8*)(B + (nt << 9));
            aFl[nt] = __builtin_amdgcn_mfma_f32_16x16x32_bf16(af, b, aFl[nt], 0, 0, 0);
        }
    }

    float h1c[8][4], r1c[8][4];
    {
        float xv[8][4], s[4], ss[4];
        #pragma unroll
        for (int r = 0; r < 4; r++) { s[r] = 0.f; ss[r] = 0.f; }
        #pragma unroll
        for (int nt = 0; nt < 8; nt++)
            #pragma unroll
            for (int r = 0; r < 4; r++) {
                float hv = okC[r] ? bf2f(hbf[(size_t)gm[r]*HID + nt*16 + col]) : 0.f;
                float x = hv + aF2[nt][r];
                xv[nt][r] = x; s[r] += x; ss[r] += x*x;
            }
        #pragma unroll
        for (int r = 0; r < 4; r++)
            for (int off = 1; off <= 8; off <<= 1) {
                s[r]  += __shfl_xor(s[r], off);
                ss[r] += __shfl_xor(ss[r], off);
            }
        #pragma unroll
        for (int r = 0; r < 4; r++) {
            float mu = s[r] * (1.f/128.f);
            float var = ss[r] * (1.f/128.f) - mu*mu;
            float rs = rsqrtf(fmaxf(var, 0.f) + 1e-5f);
            #pragma unroll
            for (int nt = 0; nt < 8; nt++) {
                float h1 = (xv[nt][r]-mu)*rs*(1.f+aFl[nt][r]) + aFl[nt+8][r];
                h1c[nt][r] = h1;
                float rv = okC[r] ? ldg1<F32>(res, (size_t)gm[r]*HID + nt*16 + col) : 0.f;
                r1c[nt][r] = rv + aF2[nt][r];
            }
        }
        // paired-u32 transpose write of h1 into sc
        #pragma unroll
        for (int nt = 0; nt < 8; nt++) {
            float p0 = __shfl_xor(h1c[nt][0], 1);
            float p1 = __shfl_xor(h1c[nt][1], 1);
            float p2 = __shfl_xor(h1c[nt][2], 1);
            float p3 = __shfl_xor(h1c[nt][3], 1);
            int cb = nt*16 + cb16;
            if (lo) {
                *(u32*)(&sc[(q*4 + 0)*168 + cb]) = cvt_pk(h1c[nt][0], p0);
                *(u32*)(&sc[(q*4 + 1)*168 + cb]) = cvt_pk(h1c[nt][1], p1);
            } else {
                *(u32*)(&sc[(q*4 + 2)*168 + cb]) = cvt_pk(p2, h1c[nt][2]);
                *(u32*)(&sc[(q*4 + 3)*168 + cb]) = cvt_pk(p3, h1c[nt][3]);
            }
        }
    }
    wave_lds_fence();

    f32x4 aT[10];
    #pragma unroll
    for (int nt = 0; nt < 10; nt++) {
        float v = bf2f(cbn1[nt*16 + col]);
        aT[nt] = (f32x4){v,v,v,v};
    }
    #pragma unroll
    for (int c = 0; c < 2; c++) {
        #pragma unroll
        for (int ks = 0; ks < 2; ks++) {
            short8 af = *(const short8*)(sc + col*168 + c*64 + ks*32 + q*8);
            const u16* B = Wn1P + (((c*2 + ks)*10) << 9) + l8;
            #pragma unroll
            for (int nt = 0; nt < 10; nt++) {
                short8 b = *(const short8*)(B + (nt << 9));
                aT[nt] = __builtin_amdgcn_mfma_f32_16x16x32_bf16(af, b, aT[nt], 0, 0, 0);
            }
        }
    }
    wave_lds_fence();
    #pragma unroll
    for (int nt = 0; nt < 10; nt++) {
        float m0 = silu(aT[nt][0]);
        float m1 = silu(aT[nt][1]);
        float m2 = silu(aT[nt][2]);
        float m3 = silu(aT[nt][3]);
        float p0 = __shfl_xor(m0, 1);
        float p1 = __shfl_xor(m1, 1);
        float p2 = __shfl_xor(m2, 1);
        float p3 = __shfl_xor(m3, 1);
        int cb = nt*16 + cb16;
        if (lo) {
            *(u32*)(&sc[(q*4 + 0)*168 + cb]) = cvt_pk(m0, p0);
            *(u32*)(&sc[(q*4 + 1)*168 + cb]) = cvt_pk(m1, p1);
        } else {
            *(u32*)(&sc[(q*4 + 2)*168 + cb]) = cvt_pk(p2, m2);
            *(u32*)(&sc[(q*4 + 3)*168 + cb]) = cvt_pk(p3, m3);
        }
    }
    wave_lds_fence();

    f32x4 aF3[8];
    #pragma unroll
    for (int nt = 0; nt < 8; nt++) {
        float v = bf2f(cbn2[nt*16 + col]);
        aF3[nt] = (f32x4){v,v,v,v};
    }
    #pragma unroll
    for (int k5 = 0; k5 < 5; k5++) {
        short8 af = *(const short8*)(sc + col*168 + k5*32 + q*8);
        const u16* B = Wn2P + ((k5*8) << 9) + l8;
        #pragma unroll
        for (int nt = 0; nt < 8; nt++) {
            short8 b = *(const short8*)(B + (nt << 9));
            aF3[nt] = __builtin_amdgcn_mfma_f32_16x16x32_bf16(af, b, aF3[nt], 0, 0, 0);
        }
    }

    #pragma unroll
    for (int nt = 0; nt < 16; nt++) {
        float v = bf2f(cbf2[nt*16 + col]);
        aFl[nt] = (f32x4){v,v,v,v};
    }
    #pragma unroll
    for (int ks = 0; ks < 2; ks++) {
        short8 af;
        if (okA) af = *(const short8*)(ybf + (size_t)mynode*ADY + ks*32 + q*8);
        else { union { u16 s[8]; short8 v; } z; for (int j=0;j<8;j++) z.s[j]=0; af = z.v; }
        const u16* B = Wf2P + ((ks*16) << 9) + l8;
        #pragma unroll
        for (int nt = 0; nt < 16; nt++) {
            short8 b = *(const short8*)(B + (nt << 9));
            aFl[nt] = __builtin_amdgcn_mfma_f32_16x16x32_bf16(af, b, aFl[nt], 0, 0, 0);
        }
    }

    {
        float xv[8][4], s[4], ss[4];
        #pragma unroll
        for (int r = 0; r < 4; r++) { s[r] = 0.f; ss[r] = 0.f; }
        #pragma unroll
        for (int nt = 0; nt < 8; nt++)
            #pragma unroll
            for (int r = 0; r < 4; r++) {
                float x = h1c[nt][r] + aF3[nt][r];
                xv[nt][r] = x; s[r] += x; ss[r] += x*x;
            }
        #pragma unroll
        for (int r = 0; r < 4; r++)
            for (int off = 1; off <= 8; off <<= 1) {
                s[r]  += __shfl_xor(s[r], off);
                ss[r] += __shfl_xor(ss[r], off);
            }
        #pragma unroll
        for (int r = 0; r < 4; r++) {
            float mu = s[r] * (1.f/128.f);
            float var = ss[r] * (1.f/128.f) - mu*mu;
            float rs = rsqrtf(fmaxf(var, 0.f) + 1e-5f);
            if (okC[r]) {
                #pragma unroll
                for (int nt = 0; nt < 8; nt++) {
                    int n = nt*16 + col;
                    float h2 = (xv[nt][r]-mu)*rs*(1.f+aFl[nt][r]) + aFl[nt+8][r];
                    stg1<F32>(out, (size_t)gm[r]*HID + n, h2);
                    stg1<F32>(out, (size_t)OUT_RES + (size_t)gm[r]*HID + n,
                              r1c[nt][r] + aF3[nt][r]);
                }
            }
        }
    }

    if (q == 0 && okA) {
        #pragma unroll
        for (int j = 0; j < 3; j++)
            stg1<F32>(out, (size_t)OUT_CRD + (size_t)mynode*3 + j,
                      ldg1<F32>(coords, (size_t)mynode*3 + j) + cacc[(size_t)mynode*3 + j]);
    }
}

__global__ __launch_bounds__(256, 2)
void node_kernel(const int* __restrict__ flag,
                 const u16* __restrict__ hbf, const void* res, const void* coords,
                 const u16* __restrict__ ybf,
                 const float* __restrict__ den, const float* __restrict__ hagg,
                 const float* __restrict__ cacc,
                 const u16* __restrict__ WoP, const u16* __restrict__ Wn1P,
                 const u16* __restrict__ Wn2P, const u16* __restrict__ Wf1P,
                 const u16* __restrict__ Wf2P,
                 const u16* __restrict__ cbn1, const u16* __restrict__ cbn2,
                 const u16* __restrict__ cbf1, const u16* __restrict__ cbf2,
                 void* out)
{
    __shared__ __align__(16) u16 sScr[4 * 16 * 168];
    if (*flag)
        node_body<true>(hbf, res, coords, ybf, den, hagg, cacc, WoP, Wn1P, Wn2P,
                        Wf1P, Wf2P, cbn1, cbn2, cbf1, cbf2, out, sScr);
    else
        node_body<false>(hbf, res, coords, ybf, den, hagg, cacc, WoP, Wn1P, Wn2P,
                         Wf1P, Wf2P, cbn1, cbn2, cbf1, cbf2, out, sScr);
}

// ---------------------------------------------------------------------------
extern "C" void kernel_launch(void* const* d_in, const int* in_sizes, int n_in,
                              void* d_out, int out_size, void* d_ws, size_t ws_size,
                              hipStream_t stream)
{
    const void* h      = d_in[0];
    const void* coords = d_in[1];
    const void* a      = d_in[2];
    const void* y      = d_in[3];
    const void* res    = d_in[4];
    const int* src     = (const int*)d_in[5];
    const int* dst     = (const int*)d_in[6];

    char* ws = (char*)d_ws;
    int*   flag   = (int*)(ws + FLAG_OFF);
    float* den    = (float*)(ws + DEN_OFF);
    float* cacc   = (float*)(ws + CACC_OFF);
    float* hagg   = (float*)(ws + HAGG_OFF);
    int*   cnt    = (int*)(ws + CNT_OFF);
    int*   cursor = (int*)(ws + CUR_OFF);
    int*   perm   = (int*)(ws + PERM_OFF);
    u16*   hbf    = (u16*)(ws + HBF_OFF);
    u16*   ybf    = (u16*)(ws + YBF_OFF);

    // convert list: 6 biases + h + y
    CvtArgs args;
    const int cvtn[8]   = {160, 160, 160, 128, 256, 256, N_NODES*HID, N_NODES*ADY};
    const int cvtsrc[8] = {8, 10, 16, 18, 20, 22, 0, 3};
    u64 boff[8];
    u64 bo = BIAS_OFF;
    for (int i = 0; i < 6; i++) {
        boff[i] = bo;
        bo += ((u64)cvtn[i] * 2 + 15) & ~(u64)15;
    }
    boff[6] = HBF_OFF;
    boff[7] = YBF_OFF;
    for (int i = 0; i < 8; i++) {
        args.src[i] = d_in[cvtsrc[i]];
        args.dstoff[i] = boff[i];
        args.n[i] = cvtn[i];
    }
    const u16* cbe1 = (const u16*)(ws + boff[0]);
    const u16* cbe2 = (const u16*)(ws + boff[1]);
    const u16* cbn1 = (const u16*)(ws + boff[2]);
    const u16* cbn2 = (const u16*)(ws + boff[3]);
    const u16* cbf1 = (const u16*)(ws + boff[4]);
    const u16* cbf2 = (const u16*)(ws + boff[5]);

    // fragment-linear blocked weights
    BwArgs bwa;
    bwa.We1 = d_in[7];  bwa.We2 = d_in[9];  bwa.Wv = d_in[12]; bwa.Wa = d_in[13];
    bwa.Wc  = d_in[11]; bwa.Wo  = d_in[14]; bwa.Wn1 = d_in[15]; bwa.Wn2 = d_in[17];
    bwa.Wf1 = d_in[19]; bwa.Wf2 = d_in[21];
    bwa.b1 = BW_OFF;
    bwa.b2 = bwa.b1 + (u64)5*2*10*512*2;   // 102400 B
    bwa.b3 = bwa.b2 + (u64)5*10*512*2;     //  51200 B
    bwa.b4 = bwa.b3 + (u64)5*9*512*2;      //  46080 B
    bwa.b5 = bwa.b4 + (u64)4*8*512*2;      //  32768 B
    bwa.b6 = bwa.b5 + (u64)4*10*512*2;     //  40960 B
    bwa.b7 = bwa.b6 + (u64)5*8*512*2;      //  40960 B
    bwa.b8 = bwa.b7 + (u64)2*16*512*2;     //  32768 B
    const u16* We1P = (const u16*)(ws + bwa.b1);
    const u16* We2P = (const u16*)(ws + bwa.b2);
    const u16* W3P  = (const u16*)(ws + bwa.b3);
    const u16* WoP  = (const u16*)(ws + bwa.b4);
    const u16* Wn1P = (const u16*)(ws + bwa.b5);
    const u16* Wn2P = (const u16*)(ws + bwa.b6);
    const u16* Wf1P = (const u16*)(ws + bwa.b7);
    const u16* Wf2P = (const u16*)(ws + bwa.b8);

    hipMemsetAsync(d_ws, 0, MEMSET_BYTES, stream);

    preproc_kernel<<<256, 256, 0, stream>>>(h, flag, ws, args, bwa, dst, cnt);

    scan_kernel<<<1, 1024, 0, stream>>>(cnt, cursor);

    scatter_kernel<<<(N_EDGES + 255)/256, 256, 0, stream>>>(dst, cursor, perm);

    edge_kernel<<<N_EDGES/64, 256, 0, stream>>>(flag, hbf, coords, a, src, dst, perm,
                                                We1P, We2P, W3P, cbe1, cbe2,
                                                den, hagg, cacc);

    node_kernel<<<(N_NODES + 63)/64, 256, 0, stream>>>(
        flag, hbf, res, coords, ybf, den, hagg, cacc,
        WoP, Wn1P, Wn2P, Wf1P, Wf2P, cbn1, cbn2, cbf1, cbf2, d_out);
}

// Round 16
// 480.547 us; speedup vs baseline: 1.2870x; 1.0095x over previous
//
#include <hip/hip_runtime.h>
#include <math.h>

#define N_NODES 25000
#define N_EDGES 400000
#define HID 128
#define EDGE_F 16
#define ADY 64
#define INNER 160
#define MSG_F 273
#define HEADS 8

// element offsets inside d_out (h2 | coords | res2)
#define OUT_CRD (N_NODES * HID)
#define OUT_RES (N_NODES * (HID + 3))

// ws byte offsets (16-aligned)
#define FLAG_OFF 0
#define DEN_OFF  256                    // f32 [25000][8]   = 800000
#define CACC_OFF 800256                 // f32 [25000][3]   = 300000
#define HAGG_OFF 1100256                // f32 [25000][128] = 12800000
#define CNT_OFF  13900256               // int [25000] histogram
#define CUR_OFF  14000256               // int [25000] scan/cursor
#define PERM_OFF 14100256               // int [400000] dst-sorted edge ids
#define MEMSET_BYTES 14000256           // zero flag..cnt (cursor/perm overwritten)
#define HBF_OFF  15700256               // h as bf16: 6.4 MB
#define YBF_OFF  22100256               // y as bf16: 3.2 MB
#define BIAS_OFF 25300256               // 6 bias tensors, bf16
#define BW_OFF   25302560               // blocked (fragment-linear) weights

// per-wave LDS slice (u16 units), R12 = R4 structure:
//   sF  [0,4608)     9 frag-linear ksteps (h_src 4, h_dst 4, kc 1)
//   sM1 [0,2560)     GEMM2 input (aliases sF after GEMM1)
//   sM2 [2560,5120)  GEMM3 input (aliases sF tail, dead after GEMM1)
//   scr [0,2336)     bf16 [16][SCR_STRIDE] epilogue (aliases sM1)
// slice = 5120 u16 = 10240 B -> 40960 B/block -> 4 blocks/CU, no extra arrays.
#define WSLICE 5120
#define SM2_OFF 2560
#define SCR_STRIDE 146

typedef unsigned short u16;
typedef unsigned int u32;
typedef unsigned long long u64;
typedef __attribute__((ext_vector_type(8))) short short8;
typedef __attribute__((ext_vector_type(4))) float f32x4;

__device__ __forceinline__ float bf2f(u16 v) {
    union { u32 u; float f; } x; x.u = ((u32)v) << 16; return x.f;
}
__device__ __forceinline__ u16 f2bf(float f) {
    union { float ff; u32 u; } x; x.ff = f;
    u32 u = x.u;
    u32 rounding = 0x7FFFu + ((u >> 16) & 1u);
    u += rounding;
    return (u16)(u >> 16);
}
// HW packed bf16 convert: one instruction for 2 floats (guide T12, m240).
__device__ __forceinline__ u32 cvt_pk(float lo, float hi) {
    u32 r;
    asm("v_cvt_pk_bf16_f32 %0, %1, %2" : "=v"(r) : "v"(lo), "v"(hi));
    return r;
}
__device__ __forceinline__ float silu(float z) {
    z = fminf(fmaxf(z, -30000.f), 30000.f);
    return z / (1.0f + __expf(-z));
}

template<bool F32> __device__ __forceinline__ float ldg1(const void* p, size_t i) {
    if (F32) return ((const float*)p)[i];
    return bf2f(((const u16*)p)[i]);
}
template<bool F32> __device__ __forceinline__ void stg1(void* p, size_t i, float v) {
    if (F32) ((float*)p)[i] = v;
    else     ((u16*)p)[i] = f2bf(v);
}
__device__ __forceinline__ float ldany(const void* p, size_t i, bool f32) {
    return f32 ? ((const float*)p)[i] : bf2f(((const u16*)p)[i]);
}
// wave-level LDS fence (all LDS regions are wave-private)
__device__ __forceinline__ void wave_lds_fence() {
    __builtin_amdgcn_wave_barrier();
    __builtin_amdgcn_s_waitcnt(0xc07f);   // lgkmcnt(0) only
    __builtin_amdgcn_wave_barrier();
}

// A-fragment address for 16x16x32 bf16 (K-major frag-linear LDS layout)
__device__ __forceinline__ int a_addr(int k, int lr) {
    return ((k >> 5) << 9) + (((((k & 31) >> 3) << 4) | lr) << 3) + (k & 7);
}

// ---------------------------------------------------------------------------
// Fused preprocessing: dtype detect + cvt + fragment-linear blockw + dst hist.
// ---------------------------------------------------------------------------
struct CvtArgs {
    const void* src[8];
    u64 dstoff[8];
    int n[8];
};
struct BwArgs {
    const void* We1; const void* We2; const void* Wv; const void* Wa;
    const void* Wc;  const void* Wo;  const void* Wn1; const void* Wn2;
    const void* Wf1; const void* Wf2;
    u64 b1, b2, b3, b4, b5, b6, b7, b8;
};

__global__ __launch_bounds__(256)
void preproc_kernel(const void* hsrc, int* flag, char* ws, CvtArgs args, BwArgs bwa,
                    const int* __restrict__ dstp, int* __restrict__ cnt)
{
    __shared__ float red[256];
    __shared__ int sflag;
    const int t = threadIdx.x;
    {
        const u16* p = (const u16*)hsrc;
        float mx = 0.f;
        for (int i = 0; i < 8; i++) {
            int idx = (t * 8 + i) * 97;
            float v = fabsf(bf2f(p[idx * 2]));
            mx = fmaxf(mx, v);
        }
        red[t] = mx;
        __syncthreads();
        for (int s = 128; s > 0; s >>= 1) {
            if (t < s) red[t] = fmaxf(red[t], red[t + s]);
            __syncthreads();
        }
        if (t == 0) {
            sflag = (red[0] > 1e10f || red[0] == 0.f) ? 1 : 0;
            if (blockIdx.x == 0) flag[0] = sflag;
        }
        __syncthreads();
    }
    const bool f32 = (sflag != 0);
    const int g = blockIdx.x * 256 + t;
    const int stride = gridDim.x * 256;

    // ---- dst histogram for counting sort ----
    for (int i = g; i < N_EDGES; i += stride)
        atomicAdd(&cnt[dstp[i]], 1);

    // ---- cvt: biases + h + y ----
    for (int ten = 0; ten < 8; ten++) {
        const void* s = args.src[ten];
        u16* d = (u16*)(ws + args.dstoff[ten]);
        const int n = args.n[ten];
        if (f32) {
            const float* sf = (const float*)s;
            for (int i = g; i < n; i += stride) d[i] = f2bf(sf[i]);
        } else {
            const u16* su = (const u16*)s;
            for (int i = g; i < n; i += stride) d[i] = su[i];
        }
    }

    // ---- fragment-linear blocked weights ----
    u16* b1 = (u16*)(ws + bwa.b1);
    u16* b2 = (u16*)(ws + bwa.b2);
    u16* b3 = (u16*)(ws + bwa.b3);
    u16* b4 = (u16*)(ws + bwa.b4);
    u16* b5 = (u16*)(ws + bwa.b5);
    u16* b6 = (u16*)(ws + bwa.b6);
    u16* b7 = (u16*)(ws + bwa.b7);
    u16* b8 = (u16*)(ws + bwa.b8);
    // We1P: [5c][2ks][10nt] tiles, K=320 logical (k==273 -> dup row 256)
    for (int i = g; i < 5*2*10*512; i += stride) {
        int tt = i >> 9, r = i & 511, l = r >> 3, j = r & 7;
        int c = tt / 20, ks = (tt / 10) % 2, nt = tt % 10;
        int k = c*64 + ks*32 + (l >> 4)*8 + j;
        int n = nt*16 + (l & 15);
        float v = 0.f;
        if (k < MSG_F)      v = ldany(bwa.We1, (size_t)k*INNER + n, f32);
        else if (k == 273)  v = ldany(bwa.We1, (size_t)256*INNER + n, f32);
        b1[i] = f2bf(v);
    }
    // We2P: [5 k5][10 nt], K=160
    for (int i = g; i < 5*10*512; i += stride) {
        int tt = i >> 9, r = i & 511, l = r >> 3, j = r & 7;
        int k5 = tt / 10, nt = tt % 10;
        int k = k5*32 + (l >> 4)*8 + j;
        int n = nt*16 + (l & 15);
        b2[i] = f2bf(ldany(bwa.We2, (size_t)k*INNER + n, f32));
    }
    // W3P: [5 k5][9 nt], K=160; n<128 Wv | n<136 Wa | n==136 Wc | else 0
    for (int i = g; i < 5*9*512; i += stride) {
        int tt = i >> 9, r = i & 511, l = r >> 3, j = r & 7;
        int k5 = tt / 9, nt = tt % 9;
        int k = k5*32 + (l >> 4)*8 + j;
        int n = nt*16 + (l & 15);
        float v = 0.f;
        if (n < 128)       v = ldany(bwa.Wv, (size_t)k*HID + n, f32);
        else if (n < 136)  v = ldany(bwa.Wa, (size_t)k*HEADS + (n-128), f32);
        else if (n == 136) v = ldany(bwa.Wc, (size_t)k, f32);
        b3[i] = f2bf(v);
    }
    // WoP: [4 cks][8 nt], K=128
    for (int i = g; i < 4*8*512; i += stride) {
        int tt = i >> 9, r = i & 511, l = r >> 3, j = r & 7;
        int cks = tt / 8, nt = tt % 8;
        int k = cks*32 + (l >> 4)*8 + j;
        int n = nt*16 + (l & 15);
        b4[i] = f2bf(ldany(bwa.Wo, (size_t)k*HID + n, f32));
    }
    // Wn1P: [4 cks][10 nt], K=128
    for (int i = g; i < 4*10*512; i += stride) {
        int tt = i >> 9, r = i & 511, l = r >> 3, j = r & 7;
        int cks = tt / 10, nt = tt % 10;
        int k = cks*32 + (l >> 4)*8 + j;
        int n = nt*16 + (l & 15);
        b5[i] = f2bf(ldany(bwa.Wn1, (size_t)k*INNER + n, f32));
    }
    // Wn2P: [5 k5][8 nt], K=160
    for (int i = g; i < 5*8*512; i += stride) {
        int tt = i >> 9, r = i & 511, l = r >> 3, j = r & 7;
        int k5 = tt / 8, nt = tt % 8;
        int k = k5*32 + (l >> 4)*8 + j;
        int n = nt*16 + (l & 15);
        b6[i] = f2bf(ldany(bwa.Wn2, (size_t)k*HID + n, f32));
    }
    // Wf1P / Wf2P: [2 ks][16 nt], K=64
    for (int i = g; i < 2*16*512; i += stride) {
        int tt = i >> 9, r = i & 511, l = r >> 3, j = r & 7;
        int ks = tt / 16, nt = tt % 16;
        int k = ks*32 + (l >> 4)*8 + j;
        int n = nt*16 + (l & 15);
        b7[i] = f2bf(ldany(bwa.Wf1, (size_t)k*256 + n, f32));
        b8[i] = f2bf(ldany(bwa.Wf2, (size_t)k*256 + n, f32));
    }
}

// ---------------------------------------------------------------------------
// Counting-sort: exclusive scan of the 25000-bin histogram (single block).
// ---------------------------------------------------------------------------
__global__ __launch_bounds__(1024)
void scan_kernel(const int* __restrict__ cnt, int* __restrict__ cursor)
{
    __shared__ int ssum[1024];
    const int t = threadIdx.x;
    const int base = t * 25;
    int loc[25];
    int s = 0;
    #pragma unroll
    for (int j = 0; j < 25; j++) {
        int i = base + j;
        int v = (i < N_NODES) ? cnt[i] : 0;
        loc[j] = s; s += v;
    }
    ssum[t] = s;
    __syncthreads();
    for (int off = 1; off < 1024; off <<= 1) {
        int v = (t >= off) ? ssum[t - off] : 0;
        __syncthreads();
        ssum[t] += v;
        __syncthreads();
    }
    int offs = (t > 0) ? ssum[t - 1] : 0;
    #pragma unroll
    for (int j = 0; j < 25; j++) {
        int i = base + j;
        if (i < N_NODES) cursor[i] = offs + loc[j];
    }
}

__global__ __launch_bounds__(256)
void scatter_kernel(const int* __restrict__ dstp, int* __restrict__ cursor,
                    int* __restrict__ perm)
{
    int i = blockIdx.x * 256 + threadIdx.x;
    if (i < N_EDGES) {
        int pos = atomicAdd(&cursor[dstp[i]], 1);
        perm[pos] = i;
    }
}

// ---------------------------------------------------------------------------
// Barrier-free MFMA edge kernel, dst-sorted. (= R12, measured 239us steady;
// at the 16-edge/wave latency floor.)
// ---------------------------------------------------------------------------
template<bool F32>   // applies to coords / a only
__device__ __forceinline__ void edge_body(
    const u16* __restrict__ hbf, const void* coords, const void* a,
    const int* __restrict__ src, const int* __restrict__ dst,
    const int* __restrict__ perm,
    const u16* __restrict__ We1P, const u16* __restrict__ We2P,
    const u16* __restrict__ W3P,
    const u16* __restrict__ cbe1, const u16* __restrict__ cbe2,
    float* __restrict__ den, float* __restrict__ hagg, float* __restrict__ cacc,
    u16* sPool)
{
    const int t   = threadIdx.x;
    const int w   = t >> 6;
    const int l   = t & 63;
    const int col = l & 15;
    const int q   = l >> 4;
    const int e0  = blockIdx.x * 64;
    const int l8  = l << 3;

    u16* sW = sPool + w * WSLICE;

    // ---- staging: 4 lanes per edge, h -> frag-linear LDS; metadata in regs ----
    const int er = l >> 2;          // edge row 0..15 within wave tile
    const int p  = l & 3;
    const int ge = perm[e0 + w*16 + er];
    const int s_ = src[ge];
    const int d_ = dst[ge];
    float dx = 0.f, dy = 0.f, dz = 0.f, invf = 0.f, r2 = 0.f;
    #pragma unroll
    for (int c = 0; c < 4; c++) {
        int node = (c < 2) ? s_ : d_;
        int c0 = (c & 1) * 64 + p * 16;
        const uint4* gp = (const uint4*)(hbf + (size_t)node*HID + c0);
        int k0 = c*64 + p*16;
        *(uint4*)(sW + a_addr(k0,     er)) = gp[0];
        *(uint4*)(sW + a_addr(k0 + 8, er)) = gp[1];
    }
    if (p < 2) {
        dx = ldg1<F32>(coords, (size_t)s_*3+0) - ldg1<F32>(coords, (size_t)d_*3+0);
        dy = ldg1<F32>(coords, (size_t)s_*3+1) - ldg1<F32>(coords, (size_t)d_*3+1);
        dz = ldg1<F32>(coords, (size_t)s_*3+2) - ldg1<F32>(coords, (size_t)d_*3+2);
        r2 = dx*dx + dy*dy + dz*dz;
        invf = 1.0f / (sqrtf(r2 + 1e-5f) + 1.0f);
        __align__(16) u16 tmp[16];
        #pragma unroll
        for (int j = 0; j < 16; j++) tmp[j] = 0;
        if (p == 0) {
            tmp[0] = f2bf(r2);                               // k=256 radial hi
            for (int j = 0; j < 15; j++)
                tmp[1+j] = f2bf(ldg1<F32>(a, (size_t)ge*EDGE_F + j));
        } else {
            tmp[0] = f2bf(ldg1<F32>(a, (size_t)ge*EDGE_F + 15));
            tmp[1] = f2bf(r2 - bf2f(f2bf(r2)));              // k=273 radial lo
        }
        int k0 = 256 + p*16;
        *(uint4*)(sW + a_addr(k0,     er)) = ((uint4*)tmp)[0];
        *(uint4*)(sW + a_addr(k0 + 8, er)) = ((uint4*)tmp)[1];
    }
    wave_lds_fence();                                   // F1: sF staged

    // ---- GEMM1: K=288, 9 LDS ksteps ----
    f32x4 acc1[10];
    #pragma unroll
    for (int nt = 0; nt < 10; nt++) {
        float v = bf2f(cbe1[nt*16 + col]);
        acc1[nt] = (f32x4){v, v, v, v};
    }
    #pragma unroll
    for (int kk = 0; kk < 9; kk++) {
        short8 af = *(const short8*)(sW + (kk << 9) + l8);
        const u16* B1 = We1P + ((kk*10) << 9) + l8;
        #pragma unroll
        for (int nt = 0; nt < 10; nt++) {
            short8 b = *(const short8*)(B1 + (nt << 9));
            acc1[nt] = __builtin_amdgcn_mfma_f32_16x16x32_bf16(af, b, acc1[nt], 0, 0, 0);
        }
    }
    wave_lds_fence();                                   // F2a: sF reads done (WAR)

    // sM1 -> [0,2560): paired u32 transpose writes via cvt_pk
    const bool lo = (col & 1) == 0;
    const int cb16 = col & ~1;
    #pragma unroll
    for (int nt = 0; nt < 10; nt++) {
        float m0 = silu(acc1[nt][0]);
        float m1 = silu(acc1[nt][1]);
        float m2 = silu(acc1[nt][2]);
        float m3 = silu(acc1[nt][3]);
        float p0 = __shfl_xor(m0, 1);
        float p1 = __shfl_xor(m1, 1);
        float p2 = __shfl_xor(m2, 1);
        float p3 = __shfl_xor(m3, 1);
        int k0 = nt*16 + cb16;
        if (lo) {
            *(u32*)(sW + a_addr(k0, q*4+0)) = cvt_pk(m0, p0);
            *(u32*)(sW + a_addr(k0, q*4+1)) = cvt_pk(m1, p1);
        } else {
            *(u32*)(sW + a_addr(k0, q*4+2)) = cvt_pk(p2, m2);
            *(u32*)(sW + a_addr(k0, q*4+3)) = cvt_pk(p3, m3);
        }
    }
    wave_lds_fence();                                   // F2: sM1 ready

    // ---- GEMM2: K=160 ----
    f32x4 acc2[10];
    #pragma unroll
    for (int nt = 0; nt < 10; nt++) {
        float v = bf2f(cbe2[nt*16 + col]);
        acc2[nt] = (f32x4){v, v, v, v};
    }
    #pragma unroll
    for (int k5 = 0; k5 < 5; k5++) {
        short8 af = *(const short8*)(sW + (k5 << 9) + l8);
        const u16* B2 = We2P + ((k5*10) << 9) + l8;
        #pragma unroll
        for (int nt = 0; nt < 10; nt++) {
            short8 b = *(const short8*)(B2 + (nt << 9));
            acc2[nt] = __builtin_amdgcn_mfma_f32_16x16x32_bf16(af, b, acc2[nt], 0, 0, 0);
        }
    }
    // sM2 -> [2560,5120): disjoint from sM1 reads; prior sF ops ordered by F2a/F2
    #pragma unroll
    for (int nt = 0; nt < 10; nt++) {
        float m0 = silu(acc2[nt][0]);
        float m1 = silu(acc2[nt][1]);
        float m2 = silu(acc2[nt][2]);
        float m3 = silu(acc2[nt][3]);
        float p0 = __shfl_xor(m0, 1);
        float p1 = __shfl_xor(m1, 1);
        float p2 = __shfl_xor(m2, 1);
        float p3 = __shfl_xor(m3, 1);
        int k0 = nt*16 + cb16;
        if (lo) {
            *(u32*)(sW + SM2_OFF + a_addr(k0, q*4+0)) = cvt_pk(m0, p0);
            *(u32*)(sW + SM2_OFF + a_addr(k0, q*4+1)) = cvt_pk(m1, p1);
        } else {
            *(u32*)(sW + SM2_OFF + a_addr(k0, q*4+2)) = cvt_pk(p2, m2);
            *(u32*)(sW + SM2_OFF + a_addr(k0, q*4+3)) = cvt_pk(p3, m3);
        }
    }
    wave_lds_fence();                                   // F3: sM2 ready

    // ---- GEMM3: N=144, K=160 ----
    f32x4 acc3[9];
    #pragma unroll
    for (int nt = 0; nt < 9; nt++) acc3[nt] = (f32x4){0.f, 0.f, 0.f, 0.f};
    #pragma unroll
    for (int k5 = 0; k5 < 5; k5++) {
        short8 af = *(const short8*)(sW + SM2_OFF + (k5 << 9) + l8);
        const u16* B3 = W3P + ((k5*9) << 9) + l8;
        #pragma unroll
        for (int nt = 0; nt < 9; nt++) {
            short8 b = *(const short8*)(B3 + (nt << 9));
            acc3[nt] = __builtin_amdgcn_mfma_f32_16x16x32_bf16(af, b, acc3[nt], 0, 0, 0);
        }
    }
    // scr -> [0,2336) bf16: aliases sM1 (dead, reads ordered by F3); GEMM3
    // reads [2560,5120) are disjoint -> no fence needed before scr writes.

    // ---- epilogue: bf16 scr transpose + segmented reduction over dst runs ----
    int dsts[16];
    #pragma unroll
    for (int row = 0; row < 16; row++) dsts[row] = __shfl(d_, row << 2);
    float dxv[4], dyv[4], dzv[4], ivv[4];
    #pragma unroll
    for (int rr = 0; rr < 4; rr++) {
        int sl = (q*4 + rr) << 2;
        dxv[rr] = __shfl(dx, sl); dyv[rr] = __shfl(dy, sl);
        dzv[rr] = __shfl(dz, sl); ivv[rr] = __shfl(invf, sl);
    }

    {
        float exv[4] = {0.f, 0.f, 0.f, 0.f};
        if (col < 8) {
            #pragma unroll
            for (int rr = 0; rr < 4; rr++)
                exv[rr] = __expf(fminf(fmaxf(acc3[8][rr], -30.f), 30.f));
        }
        #pragma unroll
        for (int nt = 0; nt < 8; nt++) {
            float ex0 = __shfl(exv[0], q*16 + nt);
            float ex1 = __shfl(exv[1], q*16 + nt);
            float ex2 = __shfl(exv[2], q*16 + nt);
            float ex3 = __shfl(exv[3], q*16 + nt);
            float v0 = acc3[nt][0] * ex0;
            float v1 = acc3[nt][1] * ex1;
            float v2 = acc3[nt][2] * ex2;
            float v3 = acc3[nt][3] * ex3;
            float p0 = __shfl_xor(v0, 1);
            float p1 = __shfl_xor(v1, 1);
            float p2 = __shfl_xor(v2, 1);
            float p3 = __shfl_xor(v3, 1);
            // even cols write rows q*4+{0,1}; odd cols rows q*4+{2,3}; packed u32
            int cb = nt*16 + cb16;
            int rowA = q*4 + (lo ? 0 : 2);
            u32 wA = lo ? cvt_pk(v0, p0) : cvt_pk(p2, v2);
            u32 wB = lo ? cvt_pk(v1, p1) : cvt_pk(p3, v3);
            *(u32*)(&sW[rowA*SCR_STRIDE + cb])       = wA;
            *(u32*)(&sW[(rowA+1)*SCR_STRIDE + cb])   = wB;
        }
        if (col < 8) {
            #pragma unroll
            for (int rr = 0; rr < 4; rr++)
                sW[(q*4 + rr)*SCR_STRIDE + 128 + col] = f2bf(exv[rr]);
        }
        if (col == 8) {
            #pragma unroll
            for (int rr = 0; rr < 4; rr++) {
                float lc = fminf(fmaxf(acc3[8][rr], -1e6f), 1e6f) * ivv[rr];
                sW[(q*4 + rr)*SCR_STRIDE + 136] = f2bf(lc * dxv[rr]);
                sW[(q*4 + rr)*SCR_STRIDE + 137] = f2bf(lc * dyv[rr]);
                sW[(q*4 + rr)*SCR_STRIDE + 138] = f2bf(lc * dzv[rr]);
            }
        }
    }
    wave_lds_fence();                                   // F4: scr ready

    #pragma unroll
    for (int pass = 0; pass < 3; pass++) {
        int c = pass*64 + l;
        bool act = c < 139;
        float accu = 0.f;
        int prevd = dsts[0];
        #pragma unroll
        for (int row = 0; row < 16; row++) {
            int d = dsts[row];
            if (d != prevd) {
                if (act) {
                    if (c < 128)      atomicAdd(&hagg[(size_t)prevd*HID + c], accu);
                    else if (c < 136) atomicAdd(&den[(size_t)prevd*8 + (c-128)], accu);
                    else              atomicAdd(&cacc[(size_t)prevd*3 + (c-136)], accu);
                }
                accu = 0.f; prevd = d;
            }
            if (act) accu += bf2f(sW[row*SCR_STRIDE + c]);
        }
        if (act) {
            if (c < 128)      atomicAdd(&hagg[(size_t)prevd*HID + c], accu);
            else if (c < 136) atomicAdd(&den[(size_t)prevd*8 + (c-128)], accu);
            else              atomicAdd(&cacc[(size_t)prevd*3 + (c-136)], accu);
        }
    }
}

__global__ __launch_bounds__(256, 4)
void edge_kernel(const int* __restrict__ flag,
                 const u16* __restrict__ hbf, const void* coords, const void* a,
                 const int* __restrict__ src, const int* __restrict__ dst,
                 const int* __restrict__ perm,
                 const u16* __restrict__ We1P, const u16* __restrict__ We2P,
                 const u16* __restrict__ W3P,
                 const u16* __restrict__ cbe1, const u16* __restrict__ cbe2,
                 float* __restrict__ den, float* __restrict__ hagg,
                 float* __restrict__ cacc)
{
    __shared__ __align__(16) u16 sPool[4 * WSLICE];   // 40960 B -> 4 blocks/CU
    if (*flag)
        edge_body<true>(hbf, coords, a, src, dst, perm, We1P, We2P, W3P,
                        cbe1, cbe2, den, hagg, cacc, sPool);
    else
        edge_body<false>(hbf, coords, a, src, dst, perm, We1P, We2P, W3P,
                         cbe1, cbe2, den, hagg, cacc, sPool);
}

// ---------------------------------------------------------------------------
// Barrier-free fused MFMA node kernel. R16: latency fixes (node kernel runs
// at ~1.5 waves/SIMD so every serial VMEM chain is exposed):
//  (1) hagg/den loads batched into ONE vmcnt window before the Wo GEMM;
//  (2) all 32 res loads batched upfront into registers (in flight under
//      Wo+Wf1's 64 MFMA);
//  (3) h-tile staged into sc via 4 coalesced uint4 loads/lane (replaces 32
//      scattered global u16 loads/lane), read back via LDS.
// ---------------------------------------------------------------------------
template<bool F32>   // applies to res / coords / out
__device__ __forceinline__ void node_body(
    const u16* __restrict__ hbf, const void* res, const void* coords,
    const u16* __restrict__ ybf,
    const float* __restrict__ den, const float* __restrict__ hagg,
    const float* __restrict__ cacc,
    const u16* __restrict__ WoP, const u16* __restrict__ Wn1P,
    const u16* __restrict__ Wn2P, const u16* __restrict__ Wf1P,
    const u16* __restrict__ Wf2P,
    const u16* __restrict__ cbn1, const u16* __restrict__ cbn2,
    const u16* __restrict__ cbf1, const u16* __restrict__ cbf2,
    void* out, u16* sScr)
{
    const int t = threadIdx.x;
    const int w = t >> 6, l = t & 63, col = l & 15, q = l >> 4;
    const int nodew = blockIdx.x * 64 + w * 16;
    const int mynode = nodew + col;
    const bool okA = mynode < N_NODES;
    const int l8 = l << 3;
    const bool lo = (col & 1) == 0;
    const int cb16 = col & ~1;
    u16* sc = sScr + w * 16 * 168;

    int gm[4]; bool okC[4];
    #pragma unroll
    for (int r = 0; r < 4; r++) { gm[r] = nodew + q*4 + r; okC[r] = gm[r] < N_NODES; }

    // ---- (3) stage h-tile into sc: lane covers row=l>>2, cols (l&3)*32..+31 ----
    {
        const int hrow = l >> 2;            // 0..15
        const int hp   = l & 3;             // 0..3
        const int hnode = nodew + hrow;
        uint4 hv0, hv1, hv2, hv3;
        if (hnode < N_NODES) {
            const uint4* gp = (const uint4*)(hbf + (size_t)hnode*HID + hp*32);
            hv0 = gp[0]; hv1 = gp[1]; hv2 = gp[2]; hv3 = gp[3];
        } else {
            hv0 = hv1 = hv2 = hv3 = (uint4){0,0,0,0};
        }
        *(uint4*)(&sc[hrow*168 + hp*32 +  0]) = hv0;
        *(uint4*)(&sc[hrow*168 + hp*32 +  8]) = hv1;
        *(uint4*)(&sc[hrow*168 + hp*32 + 16]) = hv2;
        *(uint4*)(&sc[hrow*168 + hp*32 + 24]) = hv3;
    }

    // ---- (2) batch ALL res loads upfront (in flight under Wo+Wf1 GEMMs) ----
    float rvv[8][4];
    #pragma unroll
    for (int nt = 0; nt < 8; nt++)
        #pragma unroll
        for (int r = 0; r < 4; r++)
            rvv[nt][r] = okC[r] ? ldg1<F32>(res, (size_t)gm[r]*HID + nt*16 + col) : 0.f;

    // ---- (1) batch hagg/den loads into one window ----
    float4 hga[4], hgb[4];
    float  ddv[4];
    #pragma unroll
    for (int i = 0; i < 4; i++) {
        const int c = i >> 1, ks = i & 1;
        const int kbase = c*64 + ks*32 + q*8;
        if (okA) {
            ddv[i] = den[(size_t)mynode*8 + (kbase >> 4)];
            const float4* gp = (const float4*)(hagg + (size_t)mynode*HID + kbase);
            hga[i] = gp[0]; hgb[i] = gp[1];
        } else {
            ddv[i] = 0.f;
            hga[i] = (float4){0.f,0.f,0.f,0.f};
            hgb[i] = (float4){0.f,0.f,0.f,0.f};
        }
    }

    f32x4 aF2[8];
    #pragma unroll
    for (int nt = 0; nt < 8; nt++) aF2[nt] = (f32x4){0.f,0.f,0.f,0.f};
    #pragma unroll
    for (int i = 0; i < 4; i++) {
        union { u32 w[4]; short8 v; } u;
        float inv = ddv[i] > 0.f ? 1.f/ddv[i] : 0.f;
        u.w[0] = cvt_pk(hga[i].x*inv, hga[i].y*inv);
        u.w[1] = cvt_pk(hga[i].z*inv, hga[i].w*inv);
        u.w[2] = cvt_pk(hgb[i].x*inv, hgb[i].y*inv);
        u.w[3] = cvt_pk(hgb[i].z*inv, hgb[i].w*inv);
        const u16* B = WoP + ((i*8) << 9) + l8;
        #pragma unroll
        for (int nt = 0; nt < 8; nt++) {
            short8 b = *(const short8*)(B + (nt << 9));
            aF2[nt] = __builtin_amdgcn_mfma_f32_16x16x32_bf16(u.v, b, aF2[nt], 0, 0, 0);
        }
    }

    f32x4 aFl[16];
    #pragma unroll
    for (int nt = 0; nt < 16; nt++) {
        float v = bf2f(cbf1[nt*16 + col]);
        aFl[nt] = (f32x4){v,v,v,v};
    }
    #pragma unroll
    for (int ks = 0; ks < 2; ks++) {
        short8 af;
        if (okA) af = *(const short8*)(ybf + (size_t)mynode*ADY + ks*32 + q*8);
        else { union { u16 s[8]; short8 v; } z; for (int j=0;j<8;j++) z.s[j]=0; af = z.v; }
        const u16* B = Wf1P + ((ks*16) << 9) + l8;
        #pragma unroll
        for (int nt = 0; nt < 16; nt++) {
            short8 b = *(const short8*)(B + (nt << 9));
            aFl[nt] = __builtin_amdgcn_mfma_f32_16x16x32_bf16(af, b, aFl[nt], 0, 0, 0);
        }
    }
    wave_lds_fence();                         // h-tile staged (cross-lane)

    float h1c[8][4], r1c[8][4];
    {
        float xv[8][4], s[4], ss[4];
        #pragma unroll
        for (int r = 0; r < 4; r++) { s[r] = 0.f; ss[r] = 0.f; }
        #pragma unroll
        for (int nt = 0; nt < 8; nt++)
            #pragma unroll
            for (int r = 0; r < 4; r++) {
                float hv = bf2f(sc[(q*4 + r)*168 + nt*16 + col]);
                float x = hv + aF2[nt][r];
                xv[nt][r] = x; s[r] += x; ss[r] += x*x;
            }
        #pragma unroll
        for (int r = 0; r < 4; r++)
            for (int off = 1; off <= 8; off <<= 1) {
                s[r]  += __shfl_xor(s[r], off);
                ss[r] += __shfl_xor(ss[r], off);
            }
        #pragma unroll
        for (int r = 0; r < 4; r++) {
            float mu = s[r] * (1.f/128.f);
            float var = ss[r] * (1.f/128.f) - mu*mu;
            float rs = rsqrtf(fmaxf(var, 0.f) + 1e-5f);
            #pragma unroll
            for (int nt = 0; nt < 8; nt++) {
                float h1 = (xv[nt][r]-mu)*rs*(1.f+aFl[nt][r]) + aFl[nt+8][r];
                h1c[nt][r] = h1;
                r1c[nt][r] = rvv[nt][r] + aF2[nt][r];
            }
        }
        wave_lds_fence();                     // all h reads done (cross-lane WAR)
        // paired-u32 transpose write of h1 into sc
        #pragma unroll
        for (int nt = 0; nt < 8; nt++) {
            float p0 = __shfl_xor(h1c[nt][0], 1);
            float p1 = __shfl_xor(h1c[nt][1], 1);
            float p2 = __shfl_xor(h1c[nt][2], 1);
            float p3 = __shfl_xor(h1c[nt][3], 1);
            int cb = nt*16 + cb16;
            if (lo) {
                *(u32*)(&sc[(q*4 + 0)*168 + cb]) = cvt_pk(h1c[nt][0], p0);
                *(u32*)(&sc[(q*4 + 1)*168 + cb]) = cvt_pk(h1c[nt][1], p1);
            } else {
                *(u32*)(&sc[(q*4 + 2)*168 + cb]) = cvt_pk(p2, h1c[nt][2]);
                *(u32*)(&sc[(q*4 + 3)*168 + cb]) = cvt_pk(p3, h1c[nt][3]);
            }
        }
    }
    wave_lds_fence();

    f32x4 aT[10];
    #pragma unroll
    for (int nt = 0; nt < 10; nt++) {
        float v = bf2f(cbn1[nt*16 + col]);
        aT[nt] = (f32x4){v,v,v,v};
    }
    #pragma unroll
    for (int c = 0; c < 2; c++) {
        #pragma unroll
        for (int ks = 0; ks < 2; ks++) {
            short8 af = *(const short8*)(sc + col*168 + c*64 + ks*32 + q*8);
            const u16* B = Wn1P + (((c*2 + ks)*10) << 9) + l8;
            #pragma unroll
            for (int nt = 0; nt < 10; nt++) {
                short8 b = *(const short8*)(B + (nt << 9));
                aT[nt] = __builtin_amdgcn_mfma_f32_16x16x32_bf16(af, b, aT[nt], 0, 0, 0);
            }
        }
    }
    wave_lds_fence();
    #pragma unroll
    for (int nt = 0; nt < 10; nt++) {
        float m0 = silu(aT[nt][0]);
        float m1 = silu(aT[nt][1]);
        float m2 = silu(aT[nt][2]);
        float m3 = silu(aT[nt][3]);
        float p0 = __shfl_xor(m0, 1);
        float p1 = __shfl_xor(m1, 1);
        float p2 = __shfl_xor(m2, 1);
        float p3 = __shfl_xor(m3, 1);
        int cb = nt*16 + cb16;
        if (lo) {
            *(u32*)(&sc[(q*4 + 0)*168 + cb]) = cvt_pk(m0, p0);
            *(u32*)(&sc[(q*4 + 1)*168 + cb]) = cvt_pk(m1, p1);
        } else {
            *(u32*)(&sc[(q*4 + 2)*168 + cb]) = cvt_pk(p2, m2);
            *(u32*)(&sc[(q*4 + 3)*168 + cb]) = cvt_pk(p3, m3);
        }
    }
    wave_lds_fence();

    f32x4 aF3[8];
    #pragma unroll
    for (int nt = 0; nt < 8; nt++) {
        float v = bf2f(cbn2[nt*16 + col]);
        aF3[nt] = (f32x4){v,v,v,v};
    }
    #pragma unroll
    for (int k5 = 0; k5 < 5; k5++) {
        short8 af = *(const short8*)(sc + col*168 + k5*32 + q*8);
        const u16* B = Wn2P + ((k5*8) << 9) + l8;
        #pragma unroll
        for (int nt = 0; nt < 8; nt++) {
            short8 b = *(const short8*)(B + (nt << 9));
            aF3[nt] = __builtin_amdgcn_mfma_f32_16x16x32_bf16(af, b, aF3[nt], 0, 0, 0);
        }
    }

    #pragma unroll
    for (int nt = 0; nt < 16; nt++) {
        float v = bf2f(cbf2[nt*16 + col]);
        aFl[nt] = (f32x4){v,v,v,v};
    }
    #pragma unroll
    for (int ks = 0; ks < 2; ks++) {
        short8 af;
        if (okA) af = *(const short8*)(ybf + (size_t)mynode*ADY + ks*32 + q*8);
        else { union { u16 s[8]; short8 v; } z; for (int j=0;j<8;j++) z.s[j]=0; af = z.v; }
        const u16* B = Wf2P + ((ks*16) << 9) + l8;
        #pragma unroll
        for (int nt = 0; nt < 16; nt++) {
            short8 b = *(const short8*)(B + (nt << 9));
            aFl[nt] = __builtin_amdgcn_mfma_f32_16x16x32_bf16(af, b, aFl[nt], 0, 0, 0);
        }
    }

    {
        float xv[8][4], s[4], ss[4];
        #pragma unroll
        for (int r = 0; r < 4; r++) { s[r] = 0.f; ss[r] = 0.f; }
        #pragma unroll
        for (int nt = 0; nt < 8; nt++)
            #pragma unroll
            for (int r = 0; r < 4; r++) {
                float x = h1c[nt][r] + aF3[nt][r];
                xv[nt][r] = x; s[r] += x; ss[r] += x*x;
            }
        #pragma unroll
        for (int r = 0; r < 4; r++)
            for (int off = 1; off <= 8; off <<= 1) {
                s[r]  += __shfl_xor(s[r], off);
                ss[r] += __shfl_xor(ss[r], off);
            }
        #pragma unroll
        for (int r = 0; r < 4; r++) {
            float mu = s[r] * (1.f/128.f);
            float var = ss[r] * (1.f/128.f) - mu*mu;
            float rs = rsqrtf(fmaxf(var, 0.f) + 1e-5f);
            if (okC[r]) {
                #pragma unroll
                for (int nt = 0; nt < 8; nt++) {
                    int n = nt*16 + col;
                    float h2 = (xv[nt][r]-mu)*rs*(1.f+aFl[nt][r]) + aFl[nt+8][r];
                    stg1<F32>(out, (size_t)gm[r]*HID + n, h2);
                    stg1<F32>(out, (size_t)OUT_RES + (size_t)gm[r]*HID + n,
                              r1c[nt][r] + aF3[nt][r]);
                }
            }
        }
    }

    if (q == 0 && okA) {
        #pragma unroll
        for (int j = 0; j < 3; j++)
            stg1<F32>(out, (size_t)OUT_CRD + (size_t)mynode*3 + j,
                      ldg1<F32>(coords, (size_t)mynode*3 + j) + cacc[(size_t)mynode*3 + j]);
    }
}

__global__ __launch_bounds__(256, 2)
void node_kernel(const int* __restrict__ flag,
                 const u16* __restrict__ hbf, const void* res, const void* coords,
                 const u16* __restrict__ ybf,
                 const float* __restrict__ den, const float* __restrict__ hagg,
                 const float* __restrict__ cacc,
                 const u16* __restrict__ WoP, const u16* __restrict__ Wn1P,
                 const u16* __restrict__ Wn2P, const u16* __restrict__ Wf1P,
                 const u16* __restrict__ Wf2P,
                 const u16* __restrict__ cbn1, const u16* __restrict__ cbn2,
                 const u16* __restrict__ cbf1, const u16* __restrict__ cbf2,
                 void* out)
{
    __shared__ __align__(16) u16 sScr[4 * 16 * 168];
    if (*flag)
        node_body<true>(hbf, res, coords, ybf, den, hagg, cacc, WoP, Wn1P, Wn2P,
                        Wf1P, Wf2P, cbn1, cbn2, cbf1, cbf2, out, sScr);
    else
        node_body<false>(hbf, res, coords, ybf, den, hagg, cacc, WoP, Wn1P, Wn2P,
                         Wf1P, Wf2P, cbn1, cbn2, cbf1, cbf2, out, sScr);
}

// ---------------------------------------------------------------------------
extern "C" void kernel_launch(void* const* d_in, const int* in_sizes, int n_in,
                              void* d_out, int out_size, void* d_ws, size_t ws_size,
                              hipStream_t stream)
{
    const void* h      = d_in[0];
    const void* coords = d_in[1];
    const void* a      = d_in[2];
    const void* y      = d_in[3];
    const void* res    = d_in[4];
    const int* src     = (const int*)d_in[5];
    const int* dst     = (const int*)d_in[6];

    char* ws = (char*)d_ws;
    int*   flag   = (int*)(ws + FLAG_OFF);
    float* den    = (float*)(ws + DEN_OFF);
    float* cacc   = (float*)(ws + CACC_OFF);
    float* hagg   = (float*)(ws + HAGG_OFF);
    int*   cnt    = (int*)(ws + CNT_OFF);
    int*   cursor = (int*)(ws + CUR_OFF);
    int*   perm   = (int*)(ws + PERM_OFF);
    u16*   hbf    = (u16*)(ws + HBF_OFF);
    u16*   ybf    = (u16*)(ws + YBF_OFF);

    // convert list: 6 biases + h + y
    CvtArgs args;
    const int cvtn[8]   = {160, 160, 160, 128, 256, 256, N_NODES*HID, N_NODES*ADY};
    const int cvtsrc[8] = {8, 10, 16, 18, 20, 22, 0, 3};
    u64 boff[8];
    u64 bo = BIAS_OFF;
    for (int i = 0; i < 6; i++) {
        boff[i] = bo;
        bo += ((u64)cvtn[i] * 2 + 15) & ~(u64)15;
    }
    boff[6] = HBF_OFF;
    boff[7] = YBF_OFF;
    for (int i = 0; i < 8; i++) {
        args.src[i] = d_in[cvtsrc[i]];
        args.dstoff[i] = boff[i];
        args.n[i] = cvtn[i];
    }
    const u16* cbe1 = (const u16*)(ws + boff[0]);
    const u16* cbe2 = (const u16*)(ws + boff[1]);
    const u16* cbn1 = (const u16*)(ws + boff[2]);
    const u16* cbn2 = (const u16*)(ws + boff[3]);
    const u16* cbf1 = (const u16*)(ws + boff[4]);
    const u16* cbf2 = (const u16*)(ws + boff[5]);

    // fragment-linear blocked weights
    BwArgs bwa;
    bwa.We1 = d_in[7];  bwa.We2 = d_in[9];  bwa.Wv = d_in[12]; bwa.Wa = d_in[13];
    bwa.Wc  = d_in[11]; bwa.Wo  = d_in[14]; bwa.Wn1 = d_in[15]; bwa.Wn2 = d_in[17];
    bwa.Wf1 = d_in[19]; bwa.Wf2 = d_in[21];
    bwa.b1 = BW_OFF;
    bwa.b2 = bwa.b1 + (u64)5*2*10*512*2;   // 102400 B
    bwa.b3 = bwa.b2 + (u64)5*10*512*2;     //  51200 B
    bwa.b4 = bwa.b3 + (u64)5*9*512*2;      //  46080 B
    bwa.b5 = bwa.b4 + (u64)4*8*512*2;      //  32768 B
    bwa.b6 = bwa.b5 + (u64)4*10*512*2;     //  40960 B
    bwa.b7 = bwa.b6 + (u64)5*8*512*2;      //  40960 B
    bwa.b8 = bwa.b7 + (u64)2*16*512*2;     //  32768 B
    const u16* We1P = (const u16*)(ws + bwa.b1);
    const u16* We2P = (const u16*)(ws + bwa.b2);
    const u16* W3P  = (const u16*)(ws + bwa.b3);
    const u16* WoP  = (const u16*)(ws + bwa.b4);
    const u16* Wn1P = (const u16*)(ws + bwa.b5);
    const u16* Wn2P = (const u16*)(ws + bwa.b6);
    const u16* Wf1P = (const u16*)(ws + bwa.b7);
    const u16* Wf2P = (const u16*)(ws + bwa.b8);

    hipMemsetAsync(d_ws, 0, MEMSET_BYTES, stream);

    preproc_kernel<<<256, 256, 0, stream>>>(h, flag, ws, args, bwa, dst, cnt);

    scan_kernel<<<1, 1024, 0, stream>>>(cnt, cursor);

    scatter_kernel<<<(N_EDGES + 255)/256, 256, 0, stream>>>(dst, cursor, perm);

    edge_kernel<<<N_EDGES/64, 256, 0, stream>>>(flag, hbf, coords, a, src, dst, perm,
                                                We1P, We2P, W3P, cbe1, cbe2,
                                                den, hagg, cacc);

    node_kernel<<<(N_NODES + 63)/64, 256, 0, stream>>>(
        flag, hbf, res, coords, ybf, den, hagg, cacc,
        WoP, Wn1P, Wn2P, Wf1P, Wf2P, cbn1, cbn2, cbf1, cbf2, d_out);
}

// Round 17
// 460.936 us; speedup vs baseline: 1.3418x; 1.0425x over previous
//
#include <hip/hip_runtime.h>
#include <math.h>

#define N_NODES 25000
#define N_EDGES 400000
#define HID 128
#define EDGE_F 16
#define ADY 64
#define INNER 160
#define MSG_F 273
#define HEADS 8

// element offsets inside d_out (h2 | coords | res2)
#define OUT_CRD (N_NODES * HID)
#define OUT_RES (N_NODES * (HID + 3))

// ws byte offsets (16-aligned)
#define FLAG_OFF 0
#define DEN_OFF  256                    // f32 [25000][8]   = 800000
#define CACC_OFF 800256                 // f32 [25000][3]   = 300000
#define HAGG_OFF 1100256                // f32 [25000][128] = 12800000
#define CNT_OFF  13900256               // int [25000] histogram
#define CUR_OFF  14000256               // int [25000] scan/cursor
#define PERM_OFF 14100256               // int [400000] dst-sorted edge ids
#define MEMSET_BYTES 14000256           // zero flag..cnt (cursor/perm overwritten)
#define HBF_OFF  15700256               // h as bf16: 6.4 MB
#define YBF_OFF  22100256               // y as bf16: 3.2 MB
#define BIAS_OFF 25300256               // 6 bias tensors, bf16
#define BW_OFF   25302560               // blocked (fragment-linear) weights

// per-wave LDS slice (u16 units), R12 = R4 structure:
//   sF  [0,4608)     9 frag-linear ksteps (h_src 4, h_dst 4, kc 1)
//   sM1 [0,2560)     GEMM2 input (aliases sF after GEMM1)
//   sM2 [2560,5120)  GEMM3 input (aliases sF tail, dead after GEMM1)
//   scr [0,2336)     bf16 [16][SCR_STRIDE] epilogue (aliases sM1)
// slice = 5120 u16 = 10240 B -> 40960 B/block -> 4 blocks/CU, no extra arrays.
#define WSLICE 5120
#define SM2_OFF 2560
#define SCR_STRIDE 146

typedef unsigned short u16;
typedef unsigned int u32;
typedef unsigned long long u64;
typedef __attribute__((ext_vector_type(8))) short short8;
typedef __attribute__((ext_vector_type(4))) float f32x4;

__device__ __forceinline__ float bf2f(u16 v) {
    union { u32 u; float f; } x; x.u = ((u32)v) << 16; return x.f;
}
__device__ __forceinline__ u16 f2bf(float f) {
    union { float ff; u32 u; } x; x.ff = f;
    u32 u = x.u;
    u32 rounding = 0x7FFFu + ((u >> 16) & 1u);
    u += rounding;
    return (u16)(u >> 16);
}
// HW packed bf16 convert: one instruction for 2 floats (guide T12, m240).
__device__ __forceinline__ u32 cvt_pk(float lo, float hi) {
    u32 r;
    asm("v_cvt_pk_bf16_f32 %0, %1, %2" : "=v"(r) : "v"(lo), "v"(hi));
    return r;
}
__device__ __forceinline__ float silu(float z) {
    z = fminf(fmaxf(z, -30000.f), 30000.f);
    return z / (1.0f + __expf(-z));
}

template<bool F32> __device__ __forceinline__ float ldg1(const void* p, size_t i) {
    if (F32) return ((const float*)p)[i];
    return bf2f(((const u16*)p)[i]);
}
template<bool F32> __device__ __forceinline__ void stg1(void* p, size_t i, float v) {
    if (F32) ((float*)p)[i] = v;
    else     ((u16*)p)[i] = f2bf(v);
}
__device__ __forceinline__ float ldany(const void* p, size_t i, bool f32) {
    return f32 ? ((const float*)p)[i] : bf2f(((const u16*)p)[i]);
}
// wave-level LDS fence (all LDS regions are wave-private)
__device__ __forceinline__ void wave_lds_fence() {
    __builtin_amdgcn_wave_barrier();
    __builtin_amdgcn_s_waitcnt(0xc07f);   // lgkmcnt(0) only
    __builtin_amdgcn_wave_barrier();
}

// A-fragment address for 16x16x32 bf16 (K-major frag-linear LDS layout)
__device__ __forceinline__ int a_addr(int k, int lr) {
    return ((k >> 5) << 9) + (((((k & 31) >> 3) << 4) | lr) << 3) + (k & 7);
}

// ---------------------------------------------------------------------------
// Fused preprocessing: dtype detect + cvt + fragment-linear blockw + dst hist.
// R17: grid 256 -> 2048 blocks (1 -> 8 blocks/CU: preproc was the worst
// latency-hiding config on the chip) + h/y conversion vectorized 8-wide
// (uint4 copy on bf16 path, float4 x2 + cvt_pk on f32 path).
// ---------------------------------------------------------------------------
struct CvtArgs {
    const void* src[8];
    u64 dstoff[8];
    int n[8];
};
struct BwArgs {
    const void* We1; const void* We2; const void* Wv; const void* Wa;
    const void* Wc;  const void* Wo;  const void* Wn1; const void* Wn2;
    const void* Wf1; const void* Wf2;
    u64 b1, b2, b3, b4, b5, b6, b7, b8;
};

__global__ __launch_bounds__(256)
void preproc_kernel(const void* hsrc, int* flag, char* ws, CvtArgs args, BwArgs bwa,
                    const int* __restrict__ dstp, int* __restrict__ cnt)
{
    __shared__ float red[256];
    __shared__ int sflag;
    const int t = threadIdx.x;
    {
        const u16* p = (const u16*)hsrc;
        float mx = 0.f;
        for (int i = 0; i < 8; i++) {
            int idx = (t * 8 + i) * 97;
            float v = fabsf(bf2f(p[idx * 2]));
            mx = fmaxf(mx, v);
        }
        red[t] = mx;
        __syncthreads();
        for (int s = 128; s > 0; s >>= 1) {
            if (t < s) red[t] = fmaxf(red[t], red[t + s]);
            __syncthreads();
        }
        if (t == 0) {
            sflag = (red[0] > 1e10f || red[0] == 0.f) ? 1 : 0;
            if (blockIdx.x == 0) flag[0] = sflag;
        }
        __syncthreads();
    }
    const bool f32 = (sflag != 0);
    const int g = blockIdx.x * 256 + t;
    const int stride = gridDim.x * 256;

    // ---- dst histogram for counting sort ----
    for (int i = g; i < N_EDGES; i += stride)
        atomicAdd(&cnt[dstp[i]], 1);

    // ---- cvt: biases (small, scalar) ----
    for (int ten = 0; ten < 6; ten++) {
        const void* s = args.src[ten];
        u16* d = (u16*)(ws + args.dstoff[ten]);
        const int n = args.n[ten];
        if (f32) {
            const float* sf = (const float*)s;
            for (int i = g; i < n; i += stride) d[i] = f2bf(sf[i]);
        } else {
            const u16* su = (const u16*)s;
            for (int i = g; i < n; i += stride) d[i] = su[i];
        }
    }
    // ---- cvt: h + y, 8-wide vectorized ----
    for (int ten = 6; ten < 8; ten++) {
        const void* s = args.src[ten];
        u16* d = (u16*)(ws + args.dstoff[ten]);
        const int n8 = args.n[ten] >> 3;
        if (f32) {
            const float4* sf = (const float4*)s;
            uint4* du = (uint4*)d;
            for (int i = g; i < n8; i += stride) {
                float4 a0 = sf[i*2], a1 = sf[i*2+1];
                uint4 o;
                o.x = cvt_pk(a0.x, a0.y);
                o.y = cvt_pk(a0.z, a0.w);
                o.z = cvt_pk(a1.x, a1.y);
                o.w = cvt_pk(a1.z, a1.w);
                du[i] = o;
            }
        } else {
            const uint4* su = (const uint4*)s;
            uint4* du = (uint4*)d;
            for (int i = g; i < n8; i += stride) du[i] = su[i];
        }
    }

    // ---- fragment-linear blocked weights ----
    u16* b1 = (u16*)(ws + bwa.b1);
    u16* b2 = (u16*)(ws + bwa.b2);
    u16* b3 = (u16*)(ws + bwa.b3);
    u16* b4 = (u16*)(ws + bwa.b4);
    u16* b5 = (u16*)(ws + bwa.b5);
    u16* b6 = (u16*)(ws + bwa.b6);
    u16* b7 = (u16*)(ws + bwa.b7);
    u16* b8 = (u16*)(ws + bwa.b8);
    // We1P: [5c][2ks][10nt] tiles, K=320 logical (k==273 -> dup row 256)
    for (int i = g; i < 5*2*10*512; i += stride) {
        int tt = i >> 9, r = i & 511, l = r >> 3, j = r & 7;
        int c = tt / 20, ks = (tt / 10) % 2, nt = tt % 10;
        int k = c*64 + ks*32 + (l >> 4)*8 + j;
        int n = nt*16 + (l & 15);
        float v = 0.f;
        if (k < MSG_F)      v = ldany(bwa.We1, (size_t)k*INNER + n, f32);
        else if (k == 273)  v = ldany(bwa.We1, (size_t)256*INNER + n, f32);
        b1[i] = f2bf(v);
    }
    // We2P: [5 k5][10 nt], K=160
    for (int i = g; i < 5*10*512; i += stride) {
        int tt = i >> 9, r = i & 511, l = r >> 3, j = r & 7;
        int k5 = tt / 10, nt = tt % 10;
        int k = k5*32 + (l >> 4)*8 + j;
        int n = nt*16 + (l & 15);
        b2[i] = f2bf(ldany(bwa.We2, (size_t)k*INNER + n, f32));
    }
    // W3P: [5 k5][9 nt], K=160; n<128 Wv | n<136 Wa | n==136 Wc | else 0
    for (int i = g; i < 5*9*512; i += stride) {
        int tt = i >> 9, r = i & 511, l = r >> 3, j = r & 7;
        int k5 = tt / 9, nt = tt % 9;
        int k = k5*32 + (l >> 4)*8 + j;
        int n = nt*16 + (l & 15);
        float v = 0.f;
        if (n < 128)       v = ldany(bwa.Wv, (size_t)k*HID + n, f32);
        else if (n < 136)  v = ldany(bwa.Wa, (size_t)k*HEADS + (n-128), f32);
        else if (n == 136) v = ldany(bwa.Wc, (size_t)k, f32);
        b3[i] = f2bf(v);
    }
    // WoP: [4 cks][8 nt], K=128
    for (int i = g; i < 4*8*512; i += stride) {
        int tt = i >> 9, r = i & 511, l = r >> 3, j = r & 7;
        int cks = tt / 8, nt = tt % 8;
        int k = cks*32 + (l >> 4)*8 + j;
        int n = nt*16 + (l & 15);
        b4[i] = f2bf(ldany(bwa.Wo, (size_t)k*HID + n, f32));
    }
    // Wn1P: [4 cks][10 nt], K=128
    for (int i = g; i < 4*10*512; i += stride) {
        int tt = i >> 9, r = i & 511, l = r >> 3, j = r & 7;
        int cks = tt / 10, nt = tt % 10;
        int k = cks*32 + (l >> 4)*8 + j;
        int n = nt*16 + (l & 15);
        b5[i] = f2bf(ldany(bwa.Wn1, (size_t)k*INNER + n, f32));
    }
    // Wn2P: [5 k5][8 nt], K=160
    for (int i = g; i < 5*8*512; i += stride) {
        int tt = i >> 9, r = i & 511, l = r >> 3, j = r & 7;
        int k5 = tt / 8, nt = tt % 8;
        int k = k5*32 + (l >> 4)*8 + j;
        int n = nt*16 + (l & 15);
        b6[i] = f2bf(ldany(bwa.Wn2, (size_t)k*HID + n, f32));
    }
    // Wf1P / Wf2P: [2 ks][16 nt], K=64
    for (int i = g; i < 2*16*512; i += stride) {
        int tt = i >> 9, r = i & 511, l = r >> 3, j = r & 7;
        int ks = tt / 16, nt = tt % 16;
        int k = ks*32 + (l >> 4)*8 + j;
        int n = nt*16 + (l & 15);
        b7[i] = f2bf(ldany(bwa.Wf1, (size_t)k*256 + n, f32));
        b8[i] = f2bf(ldany(bwa.Wf2, (size_t)k*256 + n, f32));
    }
}

// ---------------------------------------------------------------------------
// Counting-sort: exclusive scan of the 25000-bin histogram (single block).
// ---------------------------------------------------------------------------
__global__ __launch_bounds__(1024)
void scan_kernel(const int* __restrict__ cnt, int* __restrict__ cursor)
{
    __shared__ int ssum[1024];
    const int t = threadIdx.x;
    const int base = t * 25;
    int loc[25];
    int s = 0;
    #pragma unroll
    for (int j = 0; j < 25; j++) {
        int i = base + j;
        int v = (i < N_NODES) ? cnt[i] : 0;
        loc[j] = s; s += v;
    }
    ssum[t] = s;
    __syncthreads();
    for (int off = 1; off < 1024; off <<= 1) {
        int v = (t >= off) ? ssum[t - off] : 0;
        __syncthreads();
        ssum[t] += v;
        __syncthreads();
    }
    int offs = (t > 0) ? ssum[t - 1] : 0;
    #pragma unroll
    for (int j = 0; j < 25; j++) {
        int i = base + j;
        if (i < N_NODES) cursor[i] = offs + loc[j];
    }
}

__global__ __launch_bounds__(256)
void scatter_kernel(const int* __restrict__ dstp, int* __restrict__ cursor,
                    int* __restrict__ perm)
{
    int i = blockIdx.x * 256 + threadIdx.x;
    if (i < N_EDGES) {
        int pos = atomicAdd(&cursor[dstp[i]], 1);
        perm[pos] = i;
    }
}

// ---------------------------------------------------------------------------
// Barrier-free MFMA edge kernel, dst-sorted. (= R12, measured 239-242us
// steady; at the 16-edge/wave latency floor.)
// ---------------------------------------------------------------------------
template<bool F32>   // applies to coords / a only
__device__ __forceinline__ void edge_body(
    const u16* __restrict__ hbf, const void* coords, const void* a,
    const int* __restrict__ src, const int* __restrict__ dst,
    const int* __restrict__ perm,
    const u16* __restrict__ We1P, const u16* __restrict__ We2P,
    const u16* __restrict__ W3P,
    const u16* __restrict__ cbe1, const u16* __restrict__ cbe2,
    float* __restrict__ den, float* __restrict__ hagg, float* __restrict__ cacc,
    u16* sPool)
{
    const int t   = threadIdx.x;
    const int w   = t >> 6;
    const int l   = t & 63;
    const int col = l & 15;
    const int q   = l >> 4;
    const int e0  = blockIdx.x * 64;
    const int l8  = l << 3;

    u16* sW = sPool + w * WSLICE;

    // ---- staging: 4 lanes per edge, h -> frag-linear LDS; metadata in regs ----
    const int er = l >> 2;          // edge row 0..15 within wave tile
    const int p  = l & 3;
    const int ge = perm[e0 + w*16 + er];
    const int s_ = src[ge];
    const int d_ = dst[ge];
    float dx = 0.f, dy = 0.f, dz = 0.f, invf = 0.f, r2 = 0.f;
    #pragma unroll
    for (int c = 0; c < 4; c++) {
        int node = (c < 2) ? s_ : d_;
        int c0 = (c & 1) * 64 + p * 16;
        const uint4* gp = (const uint4*)(hbf + (size_t)node*HID + c0);
        int k0 = c*64 + p*16;
        *(uint4*)(sW + a_addr(k0,     er)) = gp[0];
        *(uint4*)(sW + a_addr(k0 + 8, er)) = gp[1];
    }
    if (p < 2) {
        dx = ldg1<F32>(coords, (size_t)s_*3+0) - ldg1<F32>(coords, (size_t)d_*3+0);
        dy = ldg1<F32>(coords, (size_t)s_*3+1) - ldg1<F32>(coords, (size_t)d_*3+1);
        dz = ldg1<F32>(coords, (size_t)s_*3+2) - ldg1<F32>(coords, (size_t)d_*3+2);
        r2 = dx*dx + dy*dy + dz*dz;
        invf = 1.0f / (sqrtf(r2 + 1e-5f) + 1.0f);
        __align__(16) u16 tmp[16];
        #pragma unroll
        for (int j = 0; j < 16; j++) tmp[j] = 0;
        if (p == 0) {
            tmp[0] = f2bf(r2);                               // k=256 radial hi
            for (int j = 0; j < 15; j++)
                tmp[1+j] = f2bf(ldg1<F32>(a, (size_t)ge*EDGE_F + j));
        } else {
            tmp[0] = f2bf(ldg1<F32>(a, (size_t)ge*EDGE_F + 15));
            tmp[1] = f2bf(r2 - bf2f(f2bf(r2)));              // k=273 radial lo
        }
        int k0 = 256 + p*16;
        *(uint4*)(sW + a_addr(k0,     er)) = ((uint4*)tmp)[0];
        *(uint4*)(sW + a_addr(k0 + 8, er)) = ((uint4*)tmp)[1];
    }
    wave_lds_fence();                                   // F1: sF staged

    // ---- GEMM1: K=288, 9 LDS ksteps ----
    f32x4 acc1[10];
    #pragma unroll
    for (int nt = 0; nt < 10; nt++) {
        float v = bf2f(cbe1[nt*16 + col]);
        acc1[nt] = (f32x4){v, v, v, v};
    }
    #pragma unroll
    for (int kk = 0; kk < 9; kk++) {
        short8 af = *(const short8*)(sW + (kk << 9) + l8);
        const u16* B1 = We1P + ((kk*10) << 9) + l8;
        #pragma unroll
        for (int nt = 0; nt < 10; nt++) {
            short8 b = *(const short8*)(B1 + (nt << 9));
            acc1[nt] = __builtin_amdgcn_mfma_f32_16x16x32_bf16(af, b, acc1[nt], 0, 0, 0);
        }
    }
    wave_lds_fence();                                   // F2a: sF reads done (WAR)

    // sM1 -> [0,2560): paired u32 transpose writes via cvt_pk
    const bool lo = (col & 1) == 0;
    const int cb16 = col & ~1;
    #pragma unroll
    for (int nt = 0; nt < 10; nt++) {
        float m0 = silu(acc1[nt][0]);
        float m1 = silu(acc1[nt][1]);
        float m2 = silu(acc1[nt][2]);
        float m3 = silu(acc1[nt][3]);
        float p0 = __shfl_xor(m0, 1);
        float p1 = __shfl_xor(m1, 1);
        float p2 = __shfl_xor(m2, 1);
        float p3 = __shfl_xor(m3, 1);
        int k0 = nt*16 + cb16;
        if (lo) {
            *(u32*)(sW + a_addr(k0, q*4+0)) = cvt_pk(m0, p0);
            *(u32*)(sW + a_addr(k0, q*4+1)) = cvt_pk(m1, p1);
        } else {
            *(u32*)(sW + a_addr(k0, q*4+2)) = cvt_pk(p2, m2);
            *(u32*)(sW + a_addr(k0, q*4+3)) = cvt_pk(p3, m3);
        }
    }
    wave_lds_fence();                                   // F2: sM1 ready

    // ---- GEMM2: K=160 ----
    f32x4 acc2[10];
    #pragma unroll
    for (int nt = 0; nt < 10; nt++) {
        float v = bf2f(cbe2[nt*16 + col]);
        acc2[nt] = (f32x4){v, v, v, v};
    }
    #pragma unroll
    for (int k5 = 0; k5 < 5; k5++) {
        short8 af = *(const short8*)(sW + (k5 << 9) + l8);
        const u16* B2 = We2P + ((k5*10) << 9) + l8;
        #pragma unroll
        for (int nt = 0; nt < 10; nt++) {
            short8 b = *(const short8*)(B2 + (nt << 9));
            acc2[nt] = __builtin_amdgcn_mfma_f32_16x16x32_bf16(af, b, acc2[nt], 0, 0, 0);
        }
    }
    // sM2 -> [2560,5120): disjoint from sM1 reads; prior sF ops ordered by F2a/F2
    #pragma unroll
    for (int nt = 0; nt < 10; nt++) {
        float m0 = silu(acc2[nt][0]);
        float m1 = silu(acc2[nt][1]);
        float m2 = silu(acc2[nt][2]);
        float m3 = silu(acc2[nt][3]);
        float p0 = __shfl_xor(m0, 1);
        float p1 = __shfl_xor(m1, 1);
        float p2 = __shfl_xor(m2, 1);
        float p3 = __shfl_xor(m3, 1);
        int k0 = nt*16 + cb16;
        if (lo) {
            *(u32*)(sW + SM2_OFF + a_addr(k0, q*4+0)) = cvt_pk(m0, p0);
            *(u32*)(sW + SM2_OFF + a_addr(k0, q*4+1)) = cvt_pk(m1, p1);
        } else {
            *(u32*)(sW + SM2_OFF + a_addr(k0, q*4+2)) = cvt_pk(p2, m2);
            *(u32*)(sW + SM2_OFF + a_addr(k0, q*4+3)) = cvt_pk(p3, m3);
        }
    }
    wave_lds_fence();                                   // F3: sM2 ready

    // ---- GEMM3: N=144, K=160 ----
    f32x4 acc3[9];
    #pragma unroll
    for (int nt = 0; nt < 9; nt++) acc3[nt] = (f32x4){0.f, 0.f, 0.f, 0.f};
    #pragma unroll
    for (int k5 = 0; k5 < 5; k5++) {
        short8 af = *(const short8*)(sW + SM2_OFF + (k5 << 9) + l8);
        const u16* B3 = W3P + ((k5*9) << 9) + l8;
        #pragma unroll
        for (int nt = 0; nt < 9; nt++) {
            short8 b = *(const short8*)(B3 + (nt << 9));
            acc3[nt] = __builtin_amdgcn_mfma_f32_16x16x32_bf16(af, b, acc3[nt], 0, 0, 0);
        }
    }
    // scr -> [0,2336) bf16: aliases sM1 (dead, reads ordered by F3); GEMM3
    // reads [2560,5120) are disjoint -> no fence needed before scr writes.

    // ---- epilogue: bf16 scr transpose + segmented reduction over dst runs ----
    int dsts[16];
    #pragma unroll
    for (int row = 0; row < 16; row++) dsts[row] = __shfl(d_, row << 2);
    float dxv[4], dyv[4], dzv[4], ivv[4];
    #pragma unroll
    for (int rr = 0; rr < 4; rr++) {
        int sl = (q*4 + rr) << 2;
        dxv[rr] = __shfl(dx, sl); dyv[rr] = __shfl(dy, sl);
        dzv[rr] = __shfl(dz, sl); ivv[rr] = __shfl(invf, sl);
    }

    {
        float exv[4] = {0.f, 0.f, 0.f, 0.f};
        if (col < 8) {
            #pragma unroll
            for (int rr = 0; rr < 4; rr++)
                exv[rr] = __expf(fminf(fmaxf(acc3[8][rr], -30.f), 30.f));
        }
        #pragma unroll
        for (int nt = 0; nt < 8; nt++) {
            float ex0 = __shfl(exv[0], q*16 + nt);
            float ex1 = __shfl(exv[1], q*16 + nt);
            float ex2 = __shfl(exv[2], q*16 + nt);
            float ex3 = __shfl(exv[3], q*16 + nt);
            float v0 = acc3[nt][0] * ex0;
            float v1 = acc3[nt][1] * ex1;
            float v2 = acc3[nt][2] * ex2;
            float v3 = acc3[nt][3] * ex3;
            float p0 = __shfl_xor(v0, 1);
            float p1 = __shfl_xor(v1, 1);
            float p2 = __shfl_xor(v2, 1);
            float p3 = __shfl_xor(v3, 1);
            // even cols write rows q*4+{0,1}; odd cols rows q*4+{2,3}; packed u32
            int cb = nt*16 + cb16;
            int rowA = q*4 + (lo ? 0 : 2);
            u32 wA = lo ? cvt_pk(v0, p0) : cvt_pk(p2, v2);
            u32 wB = lo ? cvt_pk(v1, p1) : cvt_pk(p3, v3);
            *(u32*)(&sW[rowA*SCR_STRIDE + cb])       = wA;
            *(u32*)(&sW[(rowA+1)*SCR_STRIDE + cb])   = wB;
        }
        if (col < 8) {
            #pragma unroll
            for (int rr = 0; rr < 4; rr++)
                sW[(q*4 + rr)*SCR_STRIDE + 128 + col] = f2bf(exv[rr]);
        }
        if (col == 8) {
            #pragma unroll
            for (int rr = 0; rr < 4; rr++) {
                float lc = fminf(fmaxf(acc3[8][rr], -1e6f), 1e6f) * ivv[rr];
                sW[(q*4 + rr)*SCR_STRIDE + 136] = f2bf(lc * dxv[rr]);
                sW[(q*4 + rr)*SCR_STRIDE + 137] = f2bf(lc * dyv[rr]);
                sW[(q*4 + rr)*SCR_STRIDE + 138] = f2bf(lc * dzv[rr]);
            }
        }
    }
    wave_lds_fence();                                   // F4: scr ready

    #pragma unroll
    for (int pass = 0; pass < 3; pass++) {
        int c = pass*64 + l;
        bool act = c < 139;
        float accu = 0.f;
        int prevd = dsts[0];
        #pragma unroll
        for (int row = 0; row < 16; row++) {
            int d = dsts[row];
            if (d != prevd) {
                if (act) {
                    if (c < 128)      atomicAdd(&hagg[(size_t)prevd*HID + c], accu);
                    else if (c < 136) atomicAdd(&den[(size_t)prevd*8 + (c-128)], accu);
                    else              atomicAdd(&cacc[(size_t)prevd*3 + (c-136)], accu);
                }
                accu = 0.f; prevd = d;
            }
            if (act) accu += bf2f(sW[row*SCR_STRIDE + c]);
        }
        if (act) {
            if (c < 128)      atomicAdd(&hagg[(size_t)prevd*HID + c], accu);
            else if (c < 136) atomicAdd(&den[(size_t)prevd*8 + (c-128)], accu);
            else              atomicAdd(&cacc[(size_t)prevd*3 + (c-136)], accu);
        }
    }
}

__global__ __launch_bounds__(256, 4)
void edge_kernel(const int* __restrict__ flag,
                 const u16* __restrict__ hbf, const void* coords, const void* a,
                 const int* __restrict__ src, const int* __restrict__ dst,
                 const int* __restrict__ perm,
                 const u16* __restrict__ We1P, const u16* __restrict__ We2P,
                 const u16* __restrict__ W3P,
                 const u16* __restrict__ cbe1, const u16* __restrict__ cbe2,
                 float* __restrict__ den, float* __restrict__ hagg,
                 float* __restrict__ cacc)
{
    __shared__ __align__(16) u16 sPool[4 * WSLICE];   // 40960 B -> 4 blocks/CU
    if (*flag)
        edge_body<true>(hbf, coords, a, src, dst, perm, We1P, We2P, W3P,
                        cbe1, cbe2, den, hagg, cacc, sPool);
    else
        edge_body<false>(hbf, coords, a, src, dst, perm, We1P, We2P, W3P,
                         cbe1, cbe2, den, hagg, cacc, sPool);
}

// ---------------------------------------------------------------------------
// Barrier-free fused MFMA node kernel. (= R16: batched hagg/den window,
// batched res loads, coalesced h-tile staging via LDS.)
// ---------------------------------------------------------------------------
template<bool F32>   // applies to res / coords / out
__device__ __forceinline__ void node_body(
    const u16* __restrict__ hbf, const void* res, const void* coords,
    const u16* __restrict__ ybf,
    const float* __restrict__ den, const float* __restrict__ hagg,
    const float* __restrict__ cacc,
    const u16* __restrict__ WoP, const u16* __restrict__ Wn1P,
    const u16* __restrict__ Wn2P, const u16* __restrict__ Wf1P,
    const u16* __restrict__ Wf2P,
    const u16* __restrict__ cbn1, const u16* __restrict__ cbn2,
    const u16* __restrict__ cbf1, const u16* __restrict__ cbf2,
    void* out, u16* sScr)
{
    const int t = threadIdx.x;
    const int w = t >> 6, l = t & 63, col = l & 15, q = l >> 4;
    const int nodew = blockIdx.x * 64 + w * 16;
    const int mynode = nodew + col;
    const bool okA = mynode < N_NODES;
    const int l8 = l << 3;
    const bool lo = (col & 1) == 0;
    const int cb16 = col & ~1;
    u16* sc = sScr + w * 16 * 168;

    int gm[4]; bool okC[4];
    #pragma unroll
    for (int r = 0; r < 4; r++) { gm[r] = nodew + q*4 + r; okC[r] = gm[r] < N_NODES; }

    // ---- stage h-tile into sc: lane covers row=l>>2, cols (l&3)*32..+31 ----
    {
        const int hrow = l >> 2;            // 0..15
        const int hp   = l & 3;             // 0..3
        const int hnode = nodew + hrow;
        uint4 hv0, hv1, hv2, hv3;
        if (hnode < N_NODES) {
            const uint4* gp = (const uint4*)(hbf + (size_t)hnode*HID + hp*32);
            hv0 = gp[0]; hv1 = gp[1]; hv2 = gp[2]; hv3 = gp[3];
        } else {
            hv0 = hv1 = hv2 = hv3 = (uint4){0,0,0,0};
        }
        *(uint4*)(&sc[hrow*168 + hp*32 +  0]) = hv0;
        *(uint4*)(&sc[hrow*168 + hp*32 +  8]) = hv1;
        *(uint4*)(&sc[hrow*168 + hp*32 + 16]) = hv2;
        *(uint4*)(&sc[hrow*168 + hp*32 + 24]) = hv3;
    }

    // ---- batch ALL res loads upfront (in flight under Wo+Wf1 GEMMs) ----
    float rvv[8][4];
    #pragma unroll
    for (int nt = 0; nt < 8; nt++)
        #pragma unroll
        for (int r = 0; r < 4; r++)
            rvv[nt][r] = okC[r] ? ldg1<F32>(res, (size_t)gm[r]*HID + nt*16 + col) : 0.f;

    // ---- batch hagg/den loads into one window ----
    float4 hga[4], hgb[4];
    float  ddv[4];
    #pragma unroll
    for (int i = 0; i < 4; i++) {
        const int c = i >> 1, ks = i & 1;
        const int kbase = c*64 + ks*32 + q*8;
        if (okA) {
            ddv[i] = den[(size_t)mynode*8 + (kbase >> 4)];
            const float4* gp = (const float4*)(hagg + (size_t)mynode*HID + kbase);
            hga[i] = gp[0]; hgb[i] = gp[1];
        } else {
            ddv[i] = 0.f;
            hga[i] = (float4){0.f,0.f,0.f,0.f};
            hgb[i] = (float4){0.f,0.f,0.f,0.f};
        }
    }

    f32x4 aF2[8];
    #pragma unroll
    for (int nt = 0; nt < 8; nt++) aF2[nt] = (f32x4){0.f,0.f,0.f,0.f};
    #pragma unroll
    for (int i = 0; i < 4; i++) {
        union { u32 w[4]; short8 v; } u;
        float inv = ddv[i] > 0.f ? 1.f/ddv[i] : 0.f;
        u.w[0] = cvt_pk(hga[i].x*inv, hga[i].y*inv);
        u.w[1] = cvt_pk(hga[i].z*inv, hga[i].w*inv);
        u.w[2] = cvt_pk(hgb[i].x*inv, hgb[i].y*inv);
        u.w[3] = cvt_pk(hgb[i].z*inv, hgb[i].w*inv);
        const u16* B = WoP + ((i*8) << 9) + l8;
        #pragma unroll
        for (int nt = 0; nt < 8; nt++) {
            short8 b = *(const short8*)(B + (nt << 9));
            aF2[nt] = __builtin_amdgcn_mfma_f32_16x16x32_bf16(u.v, b, aF2[nt], 0, 0, 0);
        }
    }

    f32x4 aFl[16];
    #pragma unroll
    for (int nt = 0; nt < 16; nt++) {
        float v = bf2f(cbf1[nt*16 + col]);
        aFl[nt] = (f32x4){v,v,v,v};
    }
    #pragma unroll
    for (int ks = 0; ks < 2; ks++) {
        short8 af;
        if (okA) af = *(const short8*)(ybf + (size_t)mynode*ADY + ks*32 + q*8);
        else { union { u16 s[8]; short8 v; } z; for (int j=0;j<8;j++) z.s[j]=0; af = z.v; }
        const u16* B = Wf1P + ((ks*16) << 9) + l8;
        #pragma unroll
        for (int nt = 0; nt < 16; nt++) {
            short8 b = *(const short8*)(B + (nt << 9));
            aFl[nt] = __builtin_amdgcn_mfma_f32_16x16x32_bf16(af, b, aFl[nt], 0, 0, 0);
        }
    }
    wave_lds_fence();                         // h-tile staged (cross-lane)

    float h1c[8][4], r1c[8][4];
    {
        float xv[8][4], s[4], ss[4];
        #pragma unroll
        for (int r = 0; r < 4; r++) { s[r] = 0.f; ss[r] = 0.f; }
        #pragma unroll
        for (int nt = 0; nt < 8; nt++)
            #pragma unroll
            for (int r = 0; r < 4; r++) {
                float hv = bf2f(sc[(q*4 + r)*168 + nt*16 + col]);
                float x = hv + aF2[nt][r];
                xv[nt][r] = x; s[r] += x; ss[r] += x*x;
            }
        #pragma unroll
        for (int r = 0; r < 4; r++)
            for (int off = 1; off <= 8; off <<= 1) {
                s[r]  += __shfl_xor(s[r], off);
                ss[r] += __shfl_xor(ss[r], off);
            }
        #pragma unroll
        for (int r = 0; r < 4; r++) {
            float mu = s[r] * (1.f/128.f);
            float var = ss[r] * (1.f/128.f) - mu*mu;
            float rs = rsqrtf(fmaxf(var, 0.f) + 1e-5f);
            #pragma unroll
            for (int nt = 0; nt < 8; nt++) {
                float h1 = (xv[nt][r]-mu)*rs*(1.f+aFl[nt][r]) + aFl[nt+8][r];
                h1c[nt][r] = h1;
                r1c[nt][r] = rvv[nt][r] + aF2[nt][r];
            }
        }
        wave_lds_fence();                     // all h reads done (cross-lane WAR)
        // paired-u32 transpose write of h1 into sc
        #pragma unroll
        for (int nt = 0; nt < 8; nt++) {
            float p0 = __shfl_xor(h1c[nt][0], 1);
            float p1 = __shfl_xor(h1c[nt][1], 1);
            float p2 = __shfl_xor(h1c[nt][2], 1);
            float p3 = __shfl_xor(h1c[nt][3], 1);
            int cb = nt*16 + cb16;
            if (lo) {
                *(u32*)(&sc[(q*4 + 0)*168 + cb]) = cvt_pk(h1c[nt][0], p0);
                *(u32*)(&sc[(q*4 + 1)*168 + cb]) = cvt_pk(h1c[nt][1], p1);
            } else {
                *(u32*)(&sc[(q*4 + 2)*168 + cb]) = cvt_pk(p2, h1c[nt][2]);
                *(u32*)(&sc[(q*4 + 3)*168 + cb]) = cvt_pk(p3, h1c[nt][3]);
            }
        }
    }
    wave_lds_fence();

    f32x4 aT[10];
    #pragma unroll
    for (int nt = 0; nt < 10; nt++) {
        float v = bf2f(cbn1[nt*16 + col]);
        aT[nt] = (f32x4){v,v,v,v};
    }
    #pragma unroll
    for (int c = 0; c < 2; c++) {
        #pragma unroll
        for (int ks = 0; ks < 2; ks++) {
            short8 af = *(const short8*)(sc + col*168 + c*64 + ks*32 + q*8);
            const u16* B = Wn1P + (((c*2 + ks)*10) << 9) + l8;
            #pragma unroll
            for (int nt = 0; nt < 10; nt++) {
                short8 b = *(const short8*)(B + (nt << 9));
                aT[nt] = __builtin_amdgcn_mfma_f32_16x16x32_bf16(af, b, aT[nt], 0, 0, 0);
            }
        }
    }
    wave_lds_fence();
    #pragma unroll
    for (int nt = 0; nt < 10; nt++) {
        float m0 = silu(aT[nt][0]);
        float m1 = silu(aT[nt][1]);
        float m2 = silu(aT[nt][2]);
        float m3 = silu(aT[nt][3]);
        float p0 = __shfl_xor(m0, 1);
        float p1 = __shfl_xor(m1, 1);
        float p2 = __shfl_xor(m2, 1);
        float p3 = __shfl_xor(m3, 1);
        int cb = nt*16 + cb16;
        if (lo) {
            *(u32*)(&sc[(q*4 + 0)*168 + cb]) = cvt_pk(m0, p0);
            *(u32*)(&sc[(q*4 + 1)*168 + cb]) = cvt_pk(m1, p1);
        } else {
            *(u32*)(&sc[(q*4 + 2)*168 + cb]) = cvt_pk(p2, m2);
            *(u32*)(&sc[(q*4 + 3)*168 + cb]) = cvt_pk(p3, m3);
        }
    }
    wave_lds_fence();

    f32x4 aF3[8];
    #pragma unroll
    for (int nt = 0; nt < 8; nt++) {
        float v = bf2f(cbn2[nt*16 + col]);
        aF3[nt] = (f32x4){v,v,v,v};
    }
    #pragma unroll
    for (int k5 = 0; k5 < 5; k5++) {
        short8 af = *(const short8*)(sc + col*168 + k5*32 + q*8);
        const u16* B = Wn2P + ((k5*8) << 9) + l8;
        #pragma unroll
        for (int nt = 0; nt < 8; nt++) {
            short8 b = *(const short8*)(B + (nt << 9));
            aF3[nt] = __builtin_amdgcn_mfma_f32_16x16x32_bf16(af, b, aF3[nt], 0, 0, 0);
        }
    }

    #pragma unroll
    for (int nt = 0; nt < 16; nt++) {
        float v = bf2f(cbf2[nt*16 + col]);
        aFl[nt] = (f32x4){v,v,v,v};
    }
    #pragma unroll
    for (int ks = 0; ks < 2; ks++) {
        short8 af;
        if (okA) af = *(const short8*)(ybf + (size_t)mynode*ADY + ks*32 + q*8);
        else { union { u16 s[8]; short8 v; } z; for (int j=0;j<8;j++) z.s[j]=0; af = z.v; }
        const u16* B = Wf2P + ((ks*16) << 9) + l8;
        #pragma unroll
        for (int nt = 0; nt < 16; nt++) {
            short8 b = *(const short8*)(B + (nt << 9));
            aFl[nt] = __builtin_amdgcn_mfma_f32_16x16x32_bf16(af, b, aFl[nt], 0, 0, 0);
        }
    }

    {
        float xv[8][4], s[4], ss[4];
        #pragma unroll
        for (int r = 0; r < 4; r++) { s[r] = 0.f; ss[r] = 0.f; }
        #pragma unroll
        for (int nt = 0; nt < 8; nt++)
            #pragma unroll
            for (int r = 0; r < 4; r++) {
                float x = h1c[nt][r] + aF3[nt][r];
                xv[nt][r] = x; s[r] += x; ss[r] += x*x;
            }
        #pragma unroll
        for (int r = 0; r < 4; r++)
            for (int off = 1; off <= 8; off <<= 1) {
                s[r]  += __shfl_xor(s[r], off);
                ss[r] += __shfl_xor(ss[r], off);
            }
        #pragma unroll
        for (int r = 0; r < 4; r++) {
            float mu = s[r] * (1.f/128.f);
            float var = ss[r] * (1.f/128.f) - mu*mu;
            float rs = rsqrtf(fmaxf(var, 0.f) + 1e-5f);
            if (okC[r]) {
                #pragma unroll
                for (int nt = 0; nt < 8; nt++) {
                    int n = nt*16 + col;
                    float h2 = (xv[nt][r]-mu)*rs*(1.f+aFl[nt][r]) + aFl[nt+8][r];
                    stg1<F32>(out, (size_t)gm[r]*HID + n, h2);
                    stg1<F32>(out, (size_t)OUT_RES + (size_t)gm[r]*HID + n,
                              r1c[nt][r] + aF3[nt][r]);
                }
            }
        }
    }

    if (q == 0 && okA) {
        #pragma unroll
        for (int j = 0; j < 3; j++)
            stg1<F32>(out, (size_t)OUT_CRD + (size_t)mynode*3 + j,
                      ldg1<F32>(coords, (size_t)mynode*3 + j) + cacc[(size_t)mynode*3 + j]);
    }
}

__global__ __launch_bounds__(256, 2)
void node_kernel(const int* __restrict__ flag,
                 const u16* __restrict__ hbf, const void* res, const void* coords,
                 const u16* __restrict__ ybf,
                 const float* __restrict__ den, const float* __restrict__ hagg,
                 const float* __restrict__ cacc,
                 const u16* __restrict__ WoP, const u16* __restrict__ Wn1P,
                 const u16* __restrict__ Wn2P, const u16* __restrict__ Wf1P,
                 const u16* __restrict__ Wf2P,
                 const u16* __restrict__ cbn1, const u16* __restrict__ cbn2,
                 const u16* __restrict__ cbf1, const u16* __restrict__ cbf2,
                 void* out)
{
    __shared__ __align__(16) u16 sScr[4 * 16 * 168];
    if (*flag)
        node_body<true>(hbf, res, coords, ybf, den, hagg, cacc, WoP, Wn1P, Wn2P,
                        Wf1P, Wf2P, cbn1, cbn2, cbf1, cbf2, out, sScr);
    else
        node_body<false>(hbf, res, coords, ybf, den, hagg, cacc, WoP, Wn1P, Wn2P,
                         Wf1P, Wf2P, cbn1, cbn2, cbf1, cbf2, out, sScr);
}

// ---------------------------------------------------------------------------
extern "C" void kernel_launch(void* const* d_in, const int* in_sizes, int n_in,
                              void* d_out, int out_size, void* d_ws, size_t ws_size,
                              hipStream_t stream)
{
    const void* h      = d_in[0];
    const void* coords = d_in[1];
    const void* a      = d_in[2];
    const void* y      = d_in[3];
    const void* res    = d_in[4];
    const int* src     = (const int*)d_in[5];
    const int* dst     = (const int*)d_in[6];

    char* ws = (char*)d_ws;
    int*   flag   = (int*)(ws + FLAG_OFF);
    float* den    = (float*)(ws + DEN_OFF);
    float* cacc   = (float*)(ws + CACC_OFF);
    float* hagg   = (float*)(ws + HAGG_OFF);
    int*   cnt    = (int*)(ws + CNT_OFF);
    int*   cursor = (int*)(ws + CUR_OFF);
    int*   perm   = (int*)(ws + PERM_OFF);
    u16*   hbf    = (u16*)(ws + HBF_OFF);
    u16*   ybf    = (u16*)(ws + YBF_OFF);

    // convert list: 6 biases + h + y
    CvtArgs args;
    const int cvtn[8]   = {160, 160, 160, 128, 256, 256, N_NODES*HID, N_NODES*ADY};
    const int cvtsrc[8] = {8, 10, 16, 18, 20, 22, 0, 3};
    u64 boff[8];
    u64 bo = BIAS_OFF;
    for (int i = 0; i < 6; i++) {
        boff[i] = bo;
        bo += ((u64)cvtn[i] * 2 + 15) & ~(u64)15;
    }
    boff[6] = HBF_OFF;
    boff[7] = YBF_OFF;
    for (int i = 0; i < 8; i++) {
        args.src[i] = d_in[cvtsrc[i]];
        args.dstoff[i] = boff[i];
        args.n[i] = cvtn[i];
    }
    const u16* cbe1 = (const u16*)(ws + boff[0]);
    const u16* cbe2 = (const u16*)(ws + boff[1]);
    const u16* cbn1 = (const u16*)(ws + boff[2]);
    const u16* cbn2 = (const u16*)(ws + boff[3]);
    const u16* cbf1 = (const u16*)(ws + boff[4]);
    const u16* cbf2 = (const u16*)(ws + boff[5]);

    // fragment-linear blocked weights
    BwArgs bwa;
    bwa.We1 = d_in[7];  bwa.We2 = d_in[9];  bwa.Wv = d_in[12]; bwa.Wa = d_in[13];
    bwa.Wc  = d_in[11]; bwa.Wo  = d_in[14]; bwa.Wn1 = d_in[15]; bwa.Wn2 = d_in[17];
    bwa.Wf1 = d_in[19]; bwa.Wf2 = d_in[21];
    bwa.b1 = BW_OFF;
    bwa.b2 = bwa.b1 + (u64)5*2*10*512*2;   // 102400 B
    bwa.b3 = bwa.b2 + (u64)5*10*512*2;     //  51200 B
    bwa.b4 = bwa.b3 + (u64)5*9*512*2;      //  46080 B
    bwa.b5 = bwa.b4 + (u64)4*8*512*2;      //  32768 B
    bwa.b6 = bwa.b5 + (u64)4*10*512*2;     //  40960 B
    bwa.b7 = bwa.b6 + (u64)5*8*512*2;      //  40960 B
    bwa.b8 = bwa.b7 + (u64)2*16*512*2;     //  32768 B
    const u16* We1P = (const u16*)(ws + bwa.b1);
    const u16* We2P = (const u16*)(ws + bwa.b2);
    const u16* W3P  = (const u16*)(ws + bwa.b3);
    const u16* WoP  = (const u16*)(ws + bwa.b4);
    const u16* Wn1P = (const u16*)(ws + bwa.b5);
    const u16* Wn2P = (const u16*)(ws + bwa.b6);
    const u16* Wf1P = (const u16*)(ws + bwa.b7);
    const u16* Wf2P = (const u16*)(ws + bwa.b8);

    hipMemsetAsync(d_ws, 0, MEMSET_BYTES, stream);

    preproc_kernel<<<2048, 256, 0, stream>>>(h, flag, ws, args, bwa, dst, cnt);

    scan_kernel<<<1, 1024, 0, stream>>>(cnt, cursor);

    scatter_kernel<<<(N_EDGES + 255)/256, 256, 0, stream>>>(dst, cursor, perm);

    edge_kernel<<<N_EDGES/64, 256, 0, stream>>>(flag, hbf, coords, a, src, dst, perm,
                                                We1P, We2P, W3P, cbe1, cbe2,
                                                den, hagg, cacc);

    node_kernel<<<(N_NODES + 63)/64, 256, 0, stream>>>(
        flag, hbf, res, coords, ybf, den, hagg, cacc,
        WoP, Wn1P, Wn2P, Wf1P, Wf2P, cbn1, cbn2, cbf1, cbf2, d_out);
}